// Round 5
// baseline (1047.453 us; speedup 1.0000x reference)
//
#include <hip/hip_runtime.h>
#include <hip/hip_bf16.h>
#include <math.h>

using bf16 = __hip_bfloat16;

typedef short s16x8 __attribute__((ext_vector_type(8)));
typedef short s16x4 __attribute__((ext_vector_type(4)));
typedef float f32x4 __attribute__((ext_vector_type(4)));

// Problem dims (fixed by setup_inputs)
constexpr int Bc = 8, Tc = 1024, Dc = 1024, Hc = 8;
constexpr int NTc = 77, LTc = 768, KRc = 1024, Nc = 2125, Ec = 2048;
constexpr float NEGC = -1000000.0f;

// Transposed K/V layout: [b][feature(1024)][token], row stride NP (16B-aligned)
constexpr int NP = 2128;  // 2125 tokens + 3 pad (zeroed in vT; guarded in kT reads)
constexpr long SKT = (long)Dc * NP;

// ---- Workspace layout ----
constexpr long F_STATS1 = 0;                    // 16,384
constexpr long F_STATS2 = F_STATS1 + 16384;     // 16,384
constexpr long F_KEYADD = F_STATS2 + 16384;     // 17,000
constexpr long F_VALMUL = F_KEYADD + 17000;     // 17,000
constexpr long F_SILU   = F_VALMUL + 17000;     // 16,384 (cs_m[8192] + cs_inv[8192])
constexpr long F_EO     = F_SILU + 16384;       // 16,384
constexpr long F_ATT    = F_EO + 16384;         // 1,048,576 (holds attT bf16 2MB)
constexpr long F_END    = F_ATT + 1048576;
// bf16 region
constexpr long KT_SZ   = (long)Bc * Dc * NP;    // 17,432,576
constexpr long B_NORMX = 0;                     // 8,388,608 (reused: att_part fp32, then y16)
constexpr long B_Q     = B_NORMX + 8388608;     // 8,388,608 (ren2 first, then q16, then s16)
constexpr long B_KT    = B_Q + 8388608;         // kT  [b][d][n]
constexpr long B_VT    = B_KT + KT_SZ;          // vT  [b][l][n] (reused: eo_part fp32 after att)
constexpr long B_NXF   = B_VT + KT_SZ;          // 473,088
// Weights: Q, KM, VM contiguous (fused QKVM B-operand = 3072 rows x 1024)
constexpr long B_WQ    = B_NXF + 473088;
constexpr long B_WKM   = B_WQ + 1048576;
constexpr long B_WVM   = B_WKM + 1048576;
constexpr long B_WKT   = B_WVM + 1048576;       // WtKT + WtVT contiguous (text B-operand)
constexpr long B_WVT   = B_WKT + 786432;
constexpr long B_WKR   = B_WVT + 786432;
constexpr long B_WVR   = B_WKR + 2097152;
constexpr long B_WO    = B_WVR + 1048576;
constexpr long B_END   = B_WO + 1048576;
constexpr size_t WS_NEED = (size_t)F_END * 4 + (size_t)B_END * 2;

__device__ __forceinline__ float b2f(bf16 v) { return __bfloat162float(v); }
__device__ __forceinline__ bf16 f2b(float v) { return __float2bfloat16(v); }
__device__ __forceinline__ short f2s(float v) {
    bf16 h = __float2bfloat16(v);
    return *reinterpret_cast<short*>(&h);
}
__device__ __forceinline__ float us2f(unsigned short u) {
    bf16 h = *reinterpret_cast<bf16*>(&u);
    return __bfloat162float(h);
}
__device__ __forceinline__ void storef(float* p, float v) { *p = v; }
__device__ __forceinline__ void storef(bf16* p, float v) { *p = __float2bfloat16(v); }

// async global->LDS, 16B per lane. LDS dest must be wave-uniform base + lane*16.
typedef __attribute__((address_space(1))) const unsigned int gu32;
typedef __attribute__((address_space(3))) unsigned int lu32;
__device__ __forceinline__ void gl_lds16(const void* g, void* l) {
    __builtin_amdgcn_global_load_lds((gu32*)g, (lu32*)l, 16, 0, 0);
}

__device__ __forceinline__ float2 block_sum2(float s, float s2) {
    #pragma unroll
    for (int off = 32; off > 0; off >>= 1) {
        s  += __shfl_down(s, off, 64);
        s2 += __shfl_down(s2, off, 64);
    }
    __shared__ float sh[4], sh2[4];
    int w = threadIdx.x >> 6, lane = threadIdx.x & 63;
    if (lane == 0) { sh[w] = s; sh2[w] = s2; }
    __syncthreads();
    s = sh[0] + sh[1] + sh[2] + sh[3];
    s2 = sh2[0] + sh2[1] + sh2[2] + sh2[3];
    return make_float2(s, s2);
}

// Row LayerNorm: one block (256 thr) per row
template <typename TO>
__global__ __launch_bounds__(256) void ln_rows(const float* __restrict__ in,
                                               const float* __restrict__ g,
                                               const float* __restrict__ b,
                                               TO* __restrict__ out, int C) {
    long row = blockIdx.x;
    const float* x = in + row * (long)C;
    TO* o = out + row * (long)C;
    float s = 0.f, s2 = 0.f;
    for (int c = threadIdx.x; c < C; c += 256) { float v = x[c]; s += v; s2 += v * v; }
    float2 r = block_sum2(s, s2);
    float mean = r.x / C;
    float var = r.y / C - mean * mean;
    float inv = rsqrtf(var + 1e-5f);
    for (int c = threadIdx.x; c < C; c += 256)
        storef(&o[c], (x[c] - mean) * inv * g[c] + b[c]);
}

// Both retrieval LN stats in one pass over re_motion
__global__ __launch_bounds__(256) void ln_stats_both(const float* __restrict__ motion,
                                                     const float* __restrict__ text,
                                                     float* __restrict__ stats1,
                                                     float* __restrict__ stats2) {
    long row = blockIdx.x;  // b*1024 + k*512 + r
    const float* m = motion + row * 1024;
    const float* tx = text + (row >> 9) * 1024;
    float s = 0.f, s2 = 0.f;
    for (int c = threadIdx.x; c < 1024; c += 256) { float v = m[c]; s += v; s2 += v * v; }
    float2 rm = block_sum2(s, s2);
    __syncthreads();
    float st = 0.f, st2 = 0.f;
    for (int c = threadIdx.x; c < 1024; c += 256) { float v = tx[c]; st += v; st2 += v * v; }
    float2 rt = block_sum2(st, st2);
    if (threadIdx.x == 0) {
        float mean2 = rm.x / 1024.f;
        float var2 = rm.y / 1024.f - mean2 * mean2;
        stats2[2 * row] = mean2;
        stats2[2 * row + 1] = rsqrtf(var2 + 1e-5f);
        float mean1 = (rm.x + rt.x) / 2048.f;
        float var1 = (rm.y + rt.y) / 2048.f - mean1 * mean1;
        stats1[2 * row] = mean1;
        stats1[2 * row + 1] = rsqrtf(var1 + 1e-5f);
    }
}

// Materialize normalized retrieval operands as bf16 (once):
// ren1[row][0:1024] = LN1(motion), ren1[row][1024:2048] = LN1(text); ren2 = LN2(motion)
__device__ __forceinline__ s16x4 pack4(float4 v, float mean, float rstd, float4 g, float4 b) {
    s16x4 o;
    o[0] = f2s((v.x - mean) * rstd * g.x + b.x);
    o[1] = f2s((v.y - mean) * rstd * g.y + b.y);
    o[2] = f2s((v.z - mean) * rstd * g.z + b.z);
    o[3] = f2s((v.w - mean) * rstd * g.w + b.w);
    return o;
}
__global__ __launch_bounds__(256) void materialize_ren(
    const float* __restrict__ motion, const float* __restrict__ text,
    const float* __restrict__ stats1, const float* __restrict__ stats2,
    const float* __restrict__ g1, const float* __restrict__ b1,
    const float* __restrict__ g2, const float* __restrict__ b2,
    bf16* __restrict__ ren1, bf16* __restrict__ ren2) {
    long row = blockIdx.x;  // b*1024 + kr
    int c = threadIdx.x * 4;
    const float* mrow = motion + row * 1024;
    const float* trow = text + (row >> 9) * 1024;
    float m1 = stats1[2 * row], r1 = stats1[2 * row + 1];
    float m2 = stats2[2 * row], r2 = stats2[2 * row + 1];
    float4 mv = *(const float4*)(mrow + c);
    float4 tv = *(const float4*)(trow + c);
    float4 g1m = *(const float4*)(g1 + c),        b1m = *(const float4*)(b1 + c);
    float4 g1t = *(const float4*)(g1 + 1024 + c), b1t = *(const float4*)(b1 + 1024 + c);
    float4 g2m = *(const float4*)(g2 + c),        b2m = *(const float4*)(b2 + c);
    *(s16x4*)((short*)ren1 + row * 2048 + c)        = pack4(mv, m1, r1, g1m, b1m);
    *(s16x4*)((short*)ren1 + row * 2048 + 1024 + c) = pack4(tv, m1, r1, g1t, b1t);
    *(s16x4*)((short*)ren2 + row * 1024 + c)        = pack4(mv, m2, r2, g2m, b2m);
}

// Per-(b, n) key additive mask and value multiplicative mask
__global__ __launch_bounds__(256) void prep_masks(const int* __restrict__ cond_type,
                                                  const float* __restrict__ src_mask,
                                                  const float* __restrict__ re_mask,
                                                  float* __restrict__ key_add,
                                                  float* __restrict__ val_mul) {
    int idx = blockIdx.x * 256 + threadIdx.x;
    if (idx >= Bc * Nc) return;
    int b = idx / Nc, n = idx % Nc;
    int ct = cond_type[b];
    float text_ct = ((ct % 10) > 0) ? 1.f : 0.f;
    float retr_ct = ((ct / 10) > 0) ? 1.f : 0.f;
    float add, mul;
    if (n < NTc) {
        add = (1.f - text_ct) * NEGC; mul = text_ct;
    } else if (n < NTc + KRc) {
        float rm = re_mask[b * KRc + (n - NTc)];
        add = (1.f - retr_ct) * NEGC + (1.f - rm) * NEGC;
        mul = retr_ct * rm;
    } else {
        float sm = src_mask[b * Tc + (n - NTc - KRc)];
        add = (1.f - sm) * NEGC; mul = sm;
    }
    key_add[idx] = add;
    val_mul[idx] = mul;
}

// Zero the 3 pad columns of vT (keeps MFMA tail reads finite; kT pad is guarded)
__global__ __launch_bounds__(256) void zero_tail(bf16* __restrict__ vT) {
    int row = blockIdx.x * 256 + threadIdx.x;
    if (row >= Bc * Dc) return;
    bf16* p = vT + (long)row * NP + Nc;
    p[0] = f2b(0.f); p[1] = f2b(0.f); p[2] = f2b(0.f);
}

// All 8 weight transposes in ONE launch: W[K][1024] fp32 -> Wt[1024][K] bf16
__global__ __launch_bounds__(256) void transpose_all(
    const float* __restrict__ Wq,  const float* __restrict__ Wkt,
    const float* __restrict__ Wvt, const float* __restrict__ Wkm,
    const float* __restrict__ Wvm, const float* __restrict__ Wkr,
    const float* __restrict__ Wvr, const float* __restrict__ Wo,
    short* __restrict__ WtQ,  short* __restrict__ WtKT,
    short* __restrict__ WtVT, short* __restrict__ WtKM,
    short* __restrict__ WtVM, short* __restrict__ WtKR,
    short* __restrict__ WtVR, short* __restrict__ WtO) {
    __shared__ float t[32][33];
    int sy = blockIdx.y;
    const float* W; short* Wt; int K; int ky;
    if (sy < 32)       { W = Wq;  Wt = WtQ;  K = 1024; ky = sy; }
    else if (sy < 56)  { W = Wkt; Wt = WtKT; K = 768;  ky = sy - 32; }
    else if (sy < 80)  { W = Wvt; Wt = WtVT; K = 768;  ky = sy - 56; }
    else if (sy < 112) { W = Wkm; Wt = WtKM; K = 1024; ky = sy - 80; }
    else if (sy < 144) { W = Wvm; Wt = WtVM; K = 1024; ky = sy - 112; }
    else if (sy < 208) { W = Wkr; Wt = WtKR; K = 2048; ky = sy - 144; }
    else if (sy < 240) { W = Wvr; Wt = WtVR; K = 1024; ky = sy - 208; }
    else               { W = Wo;  Wt = WtO;  K = 1024; ky = sy - 240; }
    int n0 = blockIdx.x * 32, k0 = ky * 32;
    int tx = threadIdx.x & 31, ty = threadIdx.x >> 5;
    #pragma unroll
    for (int i = 0; i < 4; ++i)
        t[ty + i * 8][tx] = W[(long)(k0 + ty + i * 8) * 1024 + n0 + tx];
    __syncthreads();
    #pragma unroll
    for (int i = 0; i < 4; ++i)
        Wt[(long)(n0 + ty + i * 8) * K + k0 + tx] = f2s(t[tx][ty + i * 8]);
}

constexpr int LDK = 64;

// ====== Fused text key+value GEMM (128^2 template, M=77, B=[WtKT|WtVT]) =====
// grid (16, 1, Bc): tn = bx*128, sec = tn>>10 (0 -> kT +key_add, 1 -> vT *val_mul)
__global__ __launch_bounds__(256) void gemm_text(
    const short* __restrict__ A,           // nxf16, per-b stride NTc*LTc
    const short* __restrict__ Bt,          // WtKT base (WtVT contiguous), ldb=768
    const float* __restrict__ bkt, const float* __restrict__ bvt,
    const float* __restrict__ key_add, const float* __restrict__ val_mul,
    bf16* __restrict__ kT, bf16* __restrict__ vT) {
    int b = blockIdx.z;
    A += (long)b * NTc * LTc;
    const int tn = blockIdx.x * 128;
    const int sec = tn >> 10;
    const int fn0 = tn & 1023;

    __shared__ __align__(16) short As[128 * LDK];
    __shared__ __align__(16) short Bs[128 * LDK];

    int tid = threadIdx.x;
    int lane = tid & 63, wid = tid >> 6;
    int wi = wid >> 1, wj = wid & 1;
    int l16 = lane & 15, quad = lane >> 4;

    f32x4 acc[4][4];
    #pragma unroll
    for (int i = 0; i < 4; ++i)
        #pragma unroll
        for (int j = 0; j < 4; ++j)
            acc[i][j] = (f32x4){0.f, 0.f, 0.f, 0.f};

    auto issue = [&](int k0) {
        #pragma unroll
        for (int p = 0; p < 4; ++p) {
            int e = p * 256 + tid;
            int row = e >> 3, c8 = e & 7;
            int gm = row;
            if (gm >= NTc) gm = NTc - 1;  // clamp: garbage rows never stored
            gl_lds16(A + (long)gm * LTc + k0 + c8 * 8, &As[row * LDK + c8 * 8]);
            gl_lds16(Bt + (long)(tn + row) * LTc + k0 + c8 * 8, &Bs[row * LDK + c8 * 8]);
        }
    };

    issue(0);
    int kt = 0;
    while (true) {
        __syncthreads();
        #pragma unroll
        for (int kk = 0; kk < 2; ++kk) {
            s16x8 af[4], bfr[4];
            #pragma unroll
            for (int i = 0; i < 4; ++i)
                af[i] = *(const s16x8*)&As[(wi * 64 + i * 16 + l16) * LDK + kk * 32 + quad * 8];
            #pragma unroll
            for (int j = 0; j < 4; ++j)
                bfr[j] = *(const s16x8*)&Bs[(wj * 64 + j * 16 + l16) * LDK + kk * 32 + quad * 8];
            #pragma unroll
            for (int i = 0; i < 4; ++i)
                #pragma unroll
                for (int j = 0; j < 4; ++j)
                    acc[i][j] = __builtin_amdgcn_mfma_f32_16x16x32_bf16(bfr[j], af[i], acc[i][j], 0, 0, 0);
        }
        int nxt = kt + 64;
        if (nxt >= 768) break;
        __syncthreads();
        issue(nxt);
        kt = nxt;
    }

    const float* bias = sec ? bvt : bkt;
    const float* rmask = (sec ? val_mul : key_add) + b * Nc;
    bf16* C = (sec ? vT : kT) + (long)b * SKT;
    #pragma unroll
    for (int j = 0; j < 4; ++j) {
        #pragma unroll
        for (int r = 0; r < 4; ++r) {
            int feat = fn0 + wj * 64 + j * 16 + quad * 4 + r;
            float bf_ = bias[feat];
            #pragma unroll
            for (int i = 0; i < 4; ++i) {
                int tok = wi * 64 + i * 16 + l16;
                if (tok >= NTc) continue;
                float v = acc[i][j][r] + bf_;
                if (sec) v *= rmask[tok];
                else     v += rmask[tok];
                C[(long)feat * NP + tok] = f2b(v);
            }
        }
    }
}

// ========== 256^2 2-phase double-buffered MFMA GEMM (8 waves, BK=64) ========
// One barrier per K-tile; staging for tile t+1 issued BEFORE MFMA of tile t,
// drained by the barrier's implicit vmcnt(0) -> HBM latency hides under MFMA.
// NOTE: NO min-waves clause in __launch_bounds__ — acc[8][4] needs ~200+ VGPRs;
// capping at 128 (512,2) spilled the accumulator to scratch (1 GB/dispatch, R4).
constexpr int BK2 = 64;

// Generic (final out GEMM): C = A @ Bt^T + bias (+addC), M,N multiples of 256.
template <typename TC>
__global__ __launch_bounds__(512) void gemm_bt2(
    const short* __restrict__ A, int lda,
    const short* __restrict__ Bt, int ldb,
    const float* __restrict__ bias,
    const float* __restrict__ addC, int ldac,
    TC* __restrict__ C, int ldc, int K) {
    const int tm = blockIdx.y * 256;
    const int tn = blockIdx.x * 256;

    __shared__ __align__(16) short As[2][256 * BK2];
    __shared__ __align__(16) short Bs[2][256 * BK2];

    int tid = threadIdx.x;
    int lane = tid & 63, wid = tid >> 6;
    int wr = wid >> 2, wc = wid & 3;
    int l16 = lane & 15, quad = lane >> 4;

    f32x4 acc[8][4];
    #pragma unroll
    for (int i = 0; i < 8; ++i)
        #pragma unroll
        for (int j = 0; j < 4; ++j)
            acc[i][j] = (f32x4){0.f, 0.f, 0.f, 0.f};

    auto stage = [&](int k0, int buf) {
        #pragma unroll
        for (int p = 0; p < 4; ++p) {
            int e = p * 512 + tid;
            int row = e >> 3, c8 = (e & 7) * 8;
            gl_lds16(A + (long)(tm + row) * lda + k0 + c8, &As[buf][row * BK2 + c8]);
            gl_lds16(Bt + (long)(tn + row) * ldb + k0 + c8, &Bs[buf][row * BK2 + c8]);
        }
    };
    auto compute = [&](int buf) {
        const short* as = As[buf];
        const short* bs = Bs[buf];
        #pragma unroll
        for (int kk = 0; kk < 2; ++kk) {
            s16x8 af[8], bfr[4];
            #pragma unroll
            for (int i = 0; i < 8; ++i)
                af[i] = *(const s16x8*)&as[(wr * 128 + i * 16 + l16) * BK2 + kk * 32 + quad * 8];
            #pragma unroll
            for (int j = 0; j < 4; ++j)
                bfr[j] = *(const s16x8*)&bs[(wc * 64 + j * 16 + l16) * BK2 + kk * 32 + quad * 8];
            #pragma unroll
            for (int i = 0; i < 8; ++i)
                #pragma unroll
                for (int j = 0; j < 4; ++j)
                    acc[i][j] = __builtin_amdgcn_mfma_f32_16x16x32_bf16(af[i], bfr[j], acc[i][j], 0, 0, 0);
        }
    };

    stage(0, 0);
    __syncthreads();
    int cur = 0, kt = 0;
    while (true) {
        int nxt = kt + BK2;
        if (nxt < K) stage(nxt, cur ^ 1);
        compute(cur);
        if (nxt >= K) break;
        __syncthreads();
        cur ^= 1;
        kt = nxt;
    }

    #pragma unroll
    for (int i = 0; i < 8; ++i) {
        #pragma unroll
        for (int r = 0; r < 4; ++r) {
            int gm = tm + wr * 128 + i * 16 + quad * 4 + r;
            #pragma unroll
            for (int j = 0; j < 4; ++j) {
                int gn = tn + wc * 64 + j * 16 + l16;
                float v = acc[i][j][r] + bias[gn];
                if (addC) v += addC[(long)gm * ldac + gn];
                storef(&C[(long)gm * ldc + gn], v);
            }
        }
    }
}

// Fused Q + key_motion + value_motion on the 256^2 2-phase template.
// A = norm_x16 (8192x1024), B = [WtQ|WtKM|WtVM] (3072x1024). grid (12, 32).
__global__ __launch_bounds__(512) void gemm_qkvm2(
    const short* __restrict__ A, const short* __restrict__ Bt,
    const float* __restrict__ bq, const float* __restrict__ bkm,
    const float* __restrict__ bvm,
    const float* __restrict__ key_add, const float* __restrict__ val_mul,
    bf16* __restrict__ q16, bf16* __restrict__ kT, bf16* __restrict__ vT) {
    const int tm = blockIdx.y * 256;
    const int tn = blockIdx.x * 256;
    const int sec = tn >> 10;
    const int fn0 = tn & 1023;

    __shared__ __align__(16) short As[2][256 * BK2];
    __shared__ __align__(16) short Bs[2][256 * BK2];

    int tid = threadIdx.x;
    int lane = tid & 63, wid = tid >> 6;
    int wr = wid >> 2, wc = wid & 3;
    int l16 = lane & 15, quad = lane >> 4;

    f32x4 acc[8][4];
    #pragma unroll
    for (int i = 0; i < 8; ++i)
        #pragma unroll
        for (int j = 0; j < 4; ++j)
            acc[i][j] = (f32x4){0.f, 0.f, 0.f, 0.f};

    auto stage = [&](int k0, int buf) {
        #pragma unroll
        for (int p = 0; p < 4; ++p) {
            int e = p * 512 + tid;
            int row = e >> 3, c8 = (e & 7) * 8;
            gl_lds16(A + (long)(tm + row) * 1024 + k0 + c8, &As[buf][row * BK2 + c8]);
            gl_lds16(Bt + (long)(tn + row) * 1024 + k0 + c8, &Bs[buf][row * BK2 + c8]);
        }
    };
    auto compute = [&](int buf) {
        const short* as = As[buf];
        const short* bs = Bs[buf];
        #pragma unroll
        for (int kk = 0; kk < 2; ++kk) {
            s16x8 af[8], bfr[4];
            #pragma unroll
            for (int i = 0; i < 8; ++i)
                af[i] = *(const s16x8*)&as[(wr * 128 + i * 16 + l16) * BK2 + kk * 32 + quad * 8];
            #pragma unroll
            for (int j = 0; j < 4; ++j)
                bfr[j] = *(const s16x8*)&bs[(wc * 64 + j * 16 + l16) * BK2 + kk * 32 + quad * 8];
            if (sec == 0) {
                #pragma unroll
                for (int i = 0; i < 8; ++i)
                    #pragma unroll
                    for (int j = 0; j < 4; ++j)
                        acc[i][j] = __builtin_amdgcn_mfma_f32_16x16x32_bf16(af[i], bfr[j], acc[i][j], 0, 0, 0);
            } else {
                #pragma unroll
                for (int i = 0; i < 8; ++i)
                    #pragma unroll
                    for (int j = 0; j < 4; ++j)
                        acc[i][j] = __builtin_amdgcn_mfma_f32_16x16x32_bf16(bfr[j], af[i], acc[i][j], 0, 0, 0);
            }
        }
    };

    stage(0, 0);
    __syncthreads();
    int cur = 0, kt = 0;
    while (true) {
        int nxt = kt + BK2;
        if (nxt < 1024) stage(nxt, cur ^ 1);
        compute(cur);
        if (nxt >= 1024) break;
        __syncthreads();
        cur ^= 1;
        kt = nxt;
    }

    if (sec == 0) {
        #pragma unroll
        for (int i = 0; i < 8; ++i) {
            #pragma unroll
            for (int r = 0; r < 4; ++r) {
                int gm = tm + wr * 128 + i * 16 + quad * 4 + r;
                #pragma unroll
                for (int j = 0; j < 4; ++j) {
                    int gn = fn0 + wc * 64 + j * 16 + l16;
                    q16[(long)gm * Dc + gn] = f2b(acc[i][j][r] + bq[gn]);
                }
            }
        }
    } else {
        const float* bias = (sec == 1) ? bkm : bvm;
        bf16* C = (sec == 1) ? kT : vT;
        #pragma unroll
        for (int j = 0; j < 4; ++j) {
            #pragma unroll
            for (int r = 0; r < 4; ++r) {
                int feat = fn0 + wc * 64 + j * 16 + quad * 4 + r;
                float bf_ = bias[feat];
                #pragma unroll
                for (int i = 0; i < 8; ++i) {
                    int gm = tm + wr * 128 + i * 16 + l16;
                    int b = gm >> 10, tok = gm & 1023;
                    int mi = b * Nc + NTc + KRc + tok;
                    float v = acc[i][j][r] + bf_;
                    if (sec == 1) v += key_add[mi];
                    else          v *= val_mul[mi];
                    C[(long)b * SKT + (long)feat * NP + NTc + KRc + tok] = f2b(v);
                }
            }
        }
    }
}

// Fused retrieval GEMMs on 256^2 2-phase: z<8 -> key_retr (K=2048), else value_retr
// (K=1024). grid (4, 4, 16).
__global__ __launch_bounds__(512) void gemm_retr2(
    const short* __restrict__ ren1, const short* __restrict__ ren2,
    const short* __restrict__ WtKR, const short* __restrict__ WtVR,
    const float* __restrict__ bkr, const float* __restrict__ bvr,
    const float* __restrict__ key_add, const float* __restrict__ val_mul,
    bf16* __restrict__ kT, bf16* __restrict__ vT) {
    int z = blockIdx.z;
    bool isK = z < 8;
    int b = isK ? z : z - 8;
    const short* A  = isK ? ren1 + (long)b * KRc * 2048 : ren2 + (long)b * KRc * 1024;
    const short* Bt = isK ? WtKR : WtVR;
    int K = isK ? 2048 : 1024;
    const float* bias = isK ? bkr : bvr;
    const float* rmask = (isK ? key_add : val_mul) + b * Nc + NTc;
    bf16* C = (isK ? kT : vT) + (long)b * SKT + NTc;

    const int tm = blockIdx.y * 256;
    const int tn = blockIdx.x * 256;

    __shared__ __align__(16) short As[2][256 * BK2];
    __shared__ __align__(16) short Bs[2][256 * BK2];

    int tid = threadIdx.x;
    int lane = tid & 63, wid = tid >> 6;
    int wr = wid >> 2, wc = wid & 3;
    int l16 = lane & 15, quad = lane >> 4;

    f32x4 acc[8][4];
    #pragma unroll
    for (int i = 0; i < 8; ++i)
        #pragma unroll
        for (int j = 0; j < 4; ++j)
            acc[i][j] = (f32x4){0.f, 0.f, 0.f, 0.f};

    auto stage = [&](int k0, int buf) {
        #pragma unroll
        for (int p = 0; p < 4; ++p) {
            int e = p * 512 + tid;
            int row = e >> 3, c8 = (e & 7) * 8;
            gl_lds16(A + (long)(tm + row) * K + k0 + c8, &As[buf][row * BK2 + c8]);
            gl_lds16(Bt + (long)(tn + row) * K + k0 + c8, &Bs[buf][row * BK2 + c8]);
        }
    };
    auto compute = [&](int buf) {
        const short* as = As[buf];
        const short* bs = Bs[buf];
        #pragma unroll
        for (int kk = 0; kk < 2; ++kk) {
            s16x8 af[8], bfr[4];
            #pragma unroll
            for (int i = 0; i < 8; ++i)
                af[i] = *(const s16x8*)&as[(wr * 128 + i * 16 + l16) * BK2 + kk * 32 + quad * 8];
            #pragma unroll
            for (int j = 0; j < 4; ++j)
                bfr[j] = *(const s16x8*)&bs[(wc * 64 + j * 16 + l16) * BK2 + kk * 32 + quad * 8];
            #pragma unroll
            for (int i = 0; i < 8; ++i)
                #pragma unroll
                for (int j = 0; j < 4; ++j)
                    acc[i][j] = __builtin_amdgcn_mfma_f32_16x16x32_bf16(bfr[j], af[i], acc[i][j], 0, 0, 0);
        }
    };

    stage(0, 0);
    __syncthreads();
    int cur = 0, kt = 0;
    while (true) {
        int nxt = kt + BK2;
        if (nxt < K) stage(nxt, cur ^ 1);
        compute(cur);
        if (nxt >= K) break;
        __syncthreads();
        cur ^= 1;
        kt = nxt;
    }

    #pragma unroll
    for (int j = 0; j < 4; ++j) {
        #pragma unroll
        for (int r = 0; r < 4; ++r) {
            int feat = tn + wc * 64 + j * 16 + quad * 4 + r;
            float bf_ = bias[feat];
            #pragma unroll
            for (int i = 0; i < 8; ++i) {
                int tok = tm + wr * 128 + i * 16 + l16;
                float v = acc[i][j][r] + bf_;
                if (isK) v += rmask[tok];
                else     v *= rmask[tok];
                C[(long)feat * NP + tok] = f2b(v);
            }
        }
    }
}

// eo split-K
__global__ __launch_bounds__(256) void eo_partial(const float* __restrict__ emb,
                                                  const float* __restrict__ We,
                                                  float* __restrict__ part) {
    int nb = blockIdx.x;
    int ks = blockIdx.y;
    int n = nb * 256 + threadIdx.x;
    int k0 = ks * 64;
    __shared__ float a_s[8][64];
    for (int idx = threadIdx.x; idx < 512; idx += 256) {
        int b = idx >> 6, kk = idx & 63;
        float v = emb[b * 2048 + k0 + kk];
        a_s[b][kk] = v / (1.f + expf(-v));
    }
    __syncthreads();
    float acc[8] = {};
    for (int kk = 0; kk < 64; ++kk) {
        float w = We[(long)(k0 + kk) * 2048 + n];
        #pragma unroll
        for (int b = 0; b < 8; ++b) acc[b] = fmaf(a_s[b][kk], w, acc[b]);
    }
    #pragma unroll
    for (int b = 0; b < 8; ++b) part[((long)ks * 8 + b) * 2048 + n] = acc[b];
}

__global__ __launch_bounds__(256) void eo_reduce(const float* __restrict__ part,
                                                 const float* __restrict__ be,
                                                 float* __restrict__ eo) {
    int idx = blockIdx.x * 256 + threadIdx.x;
    int n = idx & 2047, b = idx >> 11;
    float s = be[n];
    #pragma unroll 8
    for (int ks = 0; ks < 32; ++ks) s += part[((long)ks * 8 + b) * 2048 + n];
    eo[idx] = s;
}

// q softmax over head dim (128): one wave per row, 2 elems/lane.
__global__ __launch_bounds__(256) void softmax_head(bf16* __restrict__ q) {
    long row = (long)blockIdx.x * 4 + (threadIdx.x >> 6);
    int lane = threadIdx.x & 63;
    bf16* p = q + row * 128 + lane * 2;
    float v0 = b2f(p[0]), v1 = b2f(p[1]);
    float mx = fmaxf(v0, v1);
    #pragma unroll
    for (int off = 32; off > 0; off >>= 1) mx = fmaxf(mx, __shfl_xor(mx, off, 64));
    float e0 = expf(v0 - mx), e1 = expf(v1 - mx);
    float s = e0 + e1;
    #pragma unroll
    for (int off = 32; off > 0; off >>= 1) s += __shfl_xor(s, off, 64);
    float inv = 1.f / s;
    p[0] = f2b(e0 * inv);
    p[1] = f2b(e1 * inv);
}

// key softmax column stats over tokens — ROW reduction on kT[b][d][n].
__global__ __launch_bounds__(256) void ksm_rows(const bf16* __restrict__ kT,
                                                float* __restrict__ cs_m,
                                                float* __restrict__ cs_inv) {
    int row = blockIdx.x * 4 + (threadIdx.x >> 6);  // b*1024 + feature
    int lane = threadIdx.x & 63;
    const s16x8* p8 = (const s16x8*)(kT + (long)row * NP);
    float m = -3.0e38f;
    for (int c = lane; c < NP / 8; c += 64) {
        s16x8 raw = p8[c];
        int n0 = c * 8;
        #pragma unroll
        for (int j = 0; j < 8; ++j)
            if (n0 + j < Nc) m = fmaxf(m, us2f((unsigned short)raw[j]));
    }
    #pragma unroll
    for (int off = 32; off > 0; off >>= 1) m = fmaxf(m, __shfl_xor(m, off, 64));
    float s = 0.f;
    for (int c = lane; c < NP / 8; c += 64) {
        s16x8 raw = p8[c];
        int n0 = c * 8;
        #pragma unroll
        for (int j = 0; j < 8; ++j)
            if (n0 + j < Nc) s += __expf(us2f((unsigned short)raw[j]) - m);
    }
    #pragma unroll
    for (int off = 32; off > 0; off >>= 1) s += __shfl_xor(s, off, 64);
    if (lane == 0) { cs_m[row] = m; cs_inv[row] = 1.f / s; }
}

// att_part[split][bh][l][d] = sum_{n in split} exp(kT[bd][n]-m_d) * vT[bl][n]  (C^T store)
constexpr int ATT_SPLIT = 4;
__global__ __launch_bounds__(256) void att_gemm(const bf16* __restrict__ kTb,
                                                const bf16* __restrict__ vTb,
                                                const float* __restrict__ cs_m,
                                                float* __restrict__ att_part) {
    int bh = blockIdx.x;
    int split = blockIdx.y;
    int b = bh >> 3, h = bh & 7;
    const short* A  = (const short*)kTb + ((long)b * 1024 + h * 128) * NP;
    const short* Bt = (const short*)vTb + ((long)b * 1024 + h * 128) * NP;
    float* ap = att_part + ((long)split * 64 + bh) * 16384;

    __shared__ __align__(16) short As[128 * LDK];
    __shared__ __align__(16) short Bs[128 * LDK];
    __shared__ float ms[128];

    int tid = threadIdx.x;
    if (tid < 128) ms[tid] = cs_m[(long)b * 1024 + h * 128 + tid];

    int lane = tid & 63, wid = tid >> 6;
    int wi = wid >> 1, wj = wid & 1;
    int l16 = lane & 15, quad = lane >> 4;

    f32x4 acc[4][4];
    #pragma unroll
    for (int i = 0; i < 4; ++i)
        #pragma unroll
        for (int j = 0; j < 4; ++j)
            acc[i][j] = (f32x4){0.f, 0.f, 0.f, 0.f};

    uint4 pa[4];
    auto computeA = [&](int k0) {
        #pragma unroll
        for (int p = 0; p < 4; ++p) {
            int e = p * 256 + tid;
            int row = e >> 3, c8 = e & 7;
            int n0 = k0 + c8 * 8;
            union { short s[8]; uint4 u; } pk;
            if (n0 >= Nc) {
                pk.u = (uint4){0u, 0u, 0u, 0u};
            } else {
                float m = ms[row];
                s16x8 raw = *(const s16x8*)(A + (long)row * NP + n0);
                #pragma unroll
                for (int j = 0; j < 8; ++j) {
                    float v = (n0 + j < Nc) ? __expf(us2f((unsigned short)raw[j]) - m) : 0.f;
                    pk.s[j] = f2s(v);
                }
            }
            pa[p] = pk.u;
        }
    };
    auto issueB = [&](int k0) {
        #pragma unroll
        for (int p = 0; p < 4; ++p) {
            int e = p * 256 + tid;
            int row = e >> 3, c8 = e & 7;
            int n0 = k0 + c8 * 8;
            if (n0 > NP - 8) n0 = NP - 8;  // clamp: A is zero there, values just must be finite
            gl_lds16(Bt + (long)row * NP + n0, &Bs[row * LDK + c8 * 8]);
        }
    };
    auto storeA = [&]() {
        #pragma unroll
        for (int p = 0; p < 4; ++p) {
            int e = p * 256 + tid;
            int row = e >> 3, c8 = e & 7;
            *(uint4*)&As[row * LDK + c8 * 8] = pa[p];
        }
    };

    // 34 K-steps total, split {9,9,8,8}
    int st = (split < 2) ? split * 9 : 18 + (split - 2) * 8;
    int cnt = (split < 2) ? 9 : 8;
    int kt = st * 64;
    int kend = kt + cnt * 64;

    __syncthreads();  // ms ready
    issueB(kt);
    computeA(kt);
    storeA();
    while (true) {
        __syncthreads();
        #pragma unroll
        for (int kk = 0; kk < 2; ++kk) {
            s16x8 af[4], bfr[4];
            #pragma unroll
            for (int i = 0; i < 4; ++i)
                af[i] = *(const s16x8*)&As[(wi * 64 + i * 16 + l16) * LDK + kk * 32 + quad * 8];
            #pragma unroll
            for (int j = 0; j < 4; ++j)
                bfr[j] = *(const s16x8*)&Bs[(wj * 64 + j * 16 + l16) * LDK + kk * 32 + quad * 8];
            #pragma unroll
            for (int i = 0; i < 4; ++i)
                #pragma unroll
                for (int j = 0; j < 4; ++j)
                    acc[i][j] = __builtin_amdgcn_mfma_f32_16x16x32_bf16(bfr[j], af[i], acc[i][j], 0, 0, 0);
        }
        int nxt = kt + 64;
        if (nxt >= kend) break;
        computeA(nxt);
        __syncthreads();
        issueB(nxt);
        storeA();
        kt = nxt;
    }

    // C^T: acc rows = value-feature l (tile j), cols = key-feature d (tile i)
    #pragma unroll
    for (int j = 0; j < 4; ++j) {
        #pragma unroll
        for (int r = 0; r < 4; ++r) {
            int l = wj * 64 + j * 16 + quad * 4 + r;
            #pragma unroll
            for (int i = 0; i < 4; ++i) {
                int d = wi * 64 + i * 16 + l16;
                ap[l * 128 + d] = acc[i][j][r];
            }
        }
    }
}

// reduce splits + apply per-d 1/sum -> bf16 attT[bh][l][d] (ready B^T operand for y)
__global__ __launch_bounds__(256) void reduce_att_t(const float* __restrict__ att_part,
                                                    const float* __restrict__ cs_inv,
                                                    bf16* __restrict__ attT) {
    long idx = (long)blockIdx.x * 256 + threadIdx.x;
    if (idx >= (long)64 * 16384) return;
    float s = 0.f;
    #pragma unroll
    for (int sp = 0; sp < ATT_SPLIT; ++sp) s += att_part[(long)sp * 64 * 16384 + idx];
    int bh = (int)(idx >> 14);
    int d = (int)(idx & 127);
    int b = bh >> 3, h = bh & 7;
    attT[idx] = f2b(s * cs_inv[b * Dc + h * 128 + d]);
}

// y[b,t,h*128+l] = sum_d q[b,t,h*128+d] * att[bh][d][l] — MFMA, K=128 single stage.
__global__ __launch_bounds__(256) void y_gemm(const bf16* __restrict__ q,
                                              const bf16* __restrict__ attT,
                                              bf16* __restrict__ y) {
    int bh = blockIdx.y;
    int b = bh >> 3, h = bh & 7;
    const short* A  = (const short*)q + (long)b * Tc * Dc + h * 128;   // row stride Dc
    const short* Bt = (const short*)attT + (long)bh * 16384;           // [l][d] stride 128
    bf16* yb = y + (long)b * Tc * Dc + h * 128;
    int tm = blockIdx.x * 128;

    __shared__ __align__(16) short As[128 * 128];
    __shared__ __align__(16) short Bs[128 * 128];
    int tid = threadIdx.x;
    #pragma unroll
    for (int p = 0; p < 8; ++p) {
        int e = p * 256 + tid;
        int row = e >> 4, c8 = e & 15;
        gl_lds16(A + (long)(tm + row) * Dc + c8 * 8, &As[row * 128 + c8 * 8]);
        gl_lds16(Bt + row * 128 + c8 * 8, &Bs[row * 128 + c8 * 8]);
    }
    int lane = tid & 63, wid = tid >> 6;
    int wi = wid >> 1, wj = wid & 1;
    int l16 = lane & 15, quad = lane >> 4;
    f32x4 acc[4][4];
    #pragma unroll
    for (int i = 0; i < 4; ++i)
        #pragma unroll
        for (int j = 0; j < 4; ++j)
            acc[i][j] = (f32x4){0.f, 0.f, 0.f, 0.f};
    __syncthreads();
    #pragma unroll
    for (int kk = 0; kk < 4; ++kk) {
        s16x8 af[4], bfr[4];
        #pragma unroll
        for (int i = 0; i < 4; ++i)
            af[i] = *(const s16x8*)&As[(wi * 64 + i * 16 + l16) * 128 + kk * 32 + quad * 8];
        #pragma unroll
        for (int j = 0; j < 4; ++j)
            bfr[j] = *(const s16x8*)&Bs[(wj * 64 + j * 16 + l16) * 128 + kk * 32 + quad * 8];
        #pragma unroll
        for (int i = 0; i < 4; ++i)
            #pragma unroll
            for (int j = 0; j < 4; ++j)
                acc[i][j] = __builtin_amdgcn_mfma_f32_16x16x32_bf16(af[i], bfr[j], acc[i][j], 0, 0, 0);
    }
    #pragma unroll
    for (int i = 0; i < 4; ++i) {
        #pragma unroll
        for (int r = 0; r < 4; ++r) {
            int gm = tm + wi * 64 + i * 16 + quad * 4 + r;
            #pragma unroll
            for (int j = 0; j < 4; ++j) {
                int gn = wj * 64 + j * 16 + l16;
                yb[(long)gm * Dc + gn] = f2b(acc[i][j][r]);
            }
        }
    }
}

// s = silu( LN(y)*(1+scale) + shift )
__global__ __launch_bounds__(256) void film_kernel(const bf16* __restrict__ y,
                                                   const float* __restrict__ eo,
                                                   const float* __restrict__ g,
                                                   const float* __restrict__ bta,
                                                   bf16* __restrict__ s) {
    long row = blockIdx.x;
    int b = (int)(row >> 10);
    const bf16* yr = y + row * Dc;
    float sum = 0.f, sum2 = 0.f;
    for (int c = threadIdx.x; c < Dc; c += 256) { float v = b2f(yr[c]); sum += v; sum2 += v * v; }
    float2 r = block_sum2(sum, sum2);
    float mean = r.x / Dc;
    float var = r.y / Dc - mean * mean;
    float inv = rsqrtf(var + 1e-5f);
    const float* sc = eo + (long)b * 2048;
    const float* sf = sc + 1024;
    bf16* so = s + row * Dc;
    for (int c = threadIdx.x; c < Dc; c += 256) {
        float v = (b2f(yr[c]) - mean) * inv * g[c] + bta[c];
        v = v * (1.f + sc[c]) + sf[c];
        so[c] = f2b(v / (1.f + expf(-v)));
    }
}

extern "C" void kernel_launch(void* const* d_in, const int* in_sizes, int n_in,
                              void* d_out, int out_size, void* d_ws, size_t ws_size,
                              hipStream_t stream) {
    if (ws_size < WS_NEED) return;

    const float* x         = (const float*)d_in[0];
    const float* xf        = (const float*)d_in[1];
    const float* emb       = (const float*)d_in[2];
    const float* src_mask  = (const float*)d_in[3];
    const int*   cond_type = (const int*)d_in[4];
    const float* re_motion = (const float*)d_in[5];
    const float* re_text   = (const float*)d_in[6];
    const float* re_mask   = (const float*)d_in[7];
    const float* ln_g  = (const float*)d_in[8];
    const float* ln_b  = (const float*)d_in[9];
    const float* tln_g = (const float*)d_in[10];
    const float* tln_b = (const float*)d_in[11];
    const float* rn1_g = (const float*)d_in[12];
    const float* rn1_b = (const float*)d_in[13];
    const float* rn2_g = (const float*)d_in[14];
    const float* rn2_b = (const float*)d_in[15];
    const float* Wq  = (const float*)d_in[16];
    const float* bq  = (const float*)d_in[17];
    const float* Wkt = (const float*)d_in[18];
    const float* bkt = (const float*)d_in[19];
    const float* Wvt = (const float*)d_in[20];
    const float* bvt = (const float*)d_in[21];
    const float* Wkm = (const float*)d_in[22];
    const float* bkm = (const float*)d_in[23];
    const float* Wvm = (const float*)d_in[24];
    const float* bvm = (const float*)d_in[25];
    const float* Wkr = (const float*)d_in[26];
    const float* bkr = (const float*)d_in[27];
    const float* Wvr = (const float*)d_in[28];
    const float* bvr = (const float*)d_in[29];
    const float* We  = (const float*)d_in[30];
    const float* be  = (const float*)d_in[31];
    const float* sln_g = (const float*)d_in[32];
    const float* sln_b = (const float*)d_in[33];
    const float* Wo  = (const float*)d_in[34];
    const float* bo  = (const float*)d_in[35];

    float* ws = (float*)d_ws;
    float* stats1   = ws + F_STATS1;
    float* stats2   = ws + F_STATS2;
    float* key_add  = ws + F_KEYADD;
    float* val_mul  = ws + F_VALMUL;
    float* cs_m     = ws + F_SILU;         // 8192
    float* cs_inv   = cs_m + Bc * Dc;      // 8192
    float* eo       = ws + F_EO;
    bf16*  attT     = (bf16*)(ws + F_ATT); // 2MB bf16 in 4MB slot
    bf16* wb = (bf16*)(ws + F_END);
    bf16* norm_x16 = wb + B_NORMX;
    bf16* q16      = wb + B_Q;
    bf16* kT16     = wb + B_KT;
    bf16* vT16     = wb + B_VT;
    bf16* nxf16    = wb + B_NXF;
    short* WtQ  = (short*)(wb + B_WQ);     // WtQ/WtKM/WtVM contiguous = QKVM B-operand
    short* WtKM = (short*)(wb + B_WKM);
    short* WtVM = (short*)(wb + B_WVM);
    short* WtKT = (short*)(wb + B_WKT);    // WtKT/WtVT contiguous = text B-operand
    short* WtVT = (short*)(wb + B_WVT);
    short* WtKR = (short*)(wb + B_WKR);
    short* WtVR = (short*)(wb + B_WVR);
    short* WtO  = (short*)(wb + B_WO);
    float* att_part = (float*)(wb + B_NORMX);  // overlays norm_x16 (dead by then)
    bf16* y16 = wb + B_NORMX;                  // written after att_part consumed
    bf16* s16 = q16;                           // q dead after y_gemm
    float* eo_part = (float*)(wb + B_VT);      // overlays vT16 (dead after att_gemm)
    bf16* ren1 = (bf16*)d_out;                 // 32MB scratch, dead before final out
    bf16* ren2 = q16;                          // consumed by gemm_retr2 before qkvm2 writes q16

    float* out = (float*)d_out;

    // 1. LayerNorms + stats
    ln_rows<bf16><<<dim3(Bc * Tc), dim3(256), 0, stream>>>(x, ln_g, ln_b, norm_x16, Dc);
    ln_rows<bf16><<<dim3(Bc * NTc), dim3(256), 0, stream>>>(xf, tln_g, tln_b, nxf16, LTc);
    ln_stats_both<<<dim3(Bc * KRc), dim3(256), 0, stream>>>(re_motion, re_text, stats1, stats2);

    // 2. Masks + vT pad zero-fill
    prep_masks<<<dim3((Bc * Nc + 255) / 256), dim3(256), 0, stream>>>(
        cond_type, src_mask, re_mask, key_add, val_mul);
    zero_tail<<<dim3((Bc * Dc + 255) / 256), dim3(256), 0, stream>>>(vT16);

    // 3. All weight transposes in one launch
    transpose_all<<<dim3(32, 272), dim3(256), 0, stream>>>(
        Wq, Wkt, Wvt, Wkm, Wvm, Wkr, Wvr, Wo,
        WtQ, WtKT, WtVT, WtKM, WtVM, WtKR, WtVR, WtO);

    // 4. Materialize normalized retrieval operands (once, bf16)
    materialize_ren<<<dim3(Bc * KRc), dim3(256), 0, stream>>>(
        re_motion, re_text, stats1, stats2, rn1_g, rn1_b, rn2_g, rn2_b, ren1, ren2);

    // 5. Fused text key+value GEMM (128^2, M=77)
    gemm_text<<<dim3(16, 1, Bc), dim3(256), 0, stream>>>(
        (const short*)nxf16, WtKT, bkt, bvt, key_add, val_mul, kT16, vT16);

    // 6. Fused retrieval GEMMs, 256^2 2-phase. Must precede qkvm2 (ren2 = q16 region).
    gemm_retr2<<<dim3(4, 4, 16), dim3(512), 0, stream>>>(
        (const short*)ren1, (const short*)ren2, WtKR, WtVR, bkr, bvr,
        key_add, val_mul, kT16, vT16);

    // 7. Fused Q + KM + VM, 256^2 2-phase
    gemm_qkvm2<<<dim3(12, 32), dim3(512), 0, stream>>>(
        (const short*)norm_x16, WtQ, bq, bkm, bvm, key_add, val_mul,
        q16, kT16, vT16);

    // 8. Softmaxes
    softmax_head<<<dim3(Bc * Tc * Hc / 4), dim3(256), 0, stream>>>(q16);
    ksm_rows<<<dim3(Bc * Dc / 4), dim3(256), 0, stream>>>(kT16, cs_m, cs_inv);

    // 9. att = p^T v (MFMA, C^T store), reduce -> bf16 attT[bh][l][d]
    att_gemm<<<dim3(Bc * Hc, ATT_SPLIT), dim3(256), 0, stream>>>(kT16, vT16, cs_m, att_part);
    reduce_att_t<<<dim3((64 * 16384 + 255) / 256), dim3(256), 0, stream>>>(att_part, cs_inv, attT);

    // 10. y = q @ att (MFMA)
    y_gemm<<<dim3(Tc / 128, Bc * Hc), dim3(256), 0, stream>>>(q16, attT, y16);

    // 11. eo = silu(emb) @ We + be
    eo_partial<<<dim3(8, 32), dim3(256), 0, stream>>>(emb, We, eo_part);
    eo_reduce<<<dim3(64), dim3(256), 0, stream>>>(eo_part, be, eo);

    // 12. FiLM + silu
    film_kernel<<<dim3(Bc * Tc), dim3(256), 0, stream>>>(y16, eo, sln_g, sln_b, s16);

    // 13. out = x + s @ Wo + bo  (256^2 2-phase; overwrites ren1 scratch fully)
    gemm_bt2<float><<<dim3(4, 32), dim3(512), 0, stream>>>(
        (const short*)s16, 1024, WtO, 1024, bo, x, 1024, out, 1024, 1024);
}

// Round 6
// 636.799 us; speedup vs baseline: 1.6449x; 1.6449x over previous
//
#include <hip/hip_runtime.h>
#include <hip/hip_bf16.h>
#include <math.h>

using bf16 = __hip_bfloat16;

typedef short s16x8 __attribute__((ext_vector_type(8)));
typedef short s16x4 __attribute__((ext_vector_type(4)));
typedef float f32x4 __attribute__((ext_vector_type(4)));

// Problem dims (fixed by setup_inputs)
constexpr int Bc = 8, Tc = 1024, Dc = 1024, Hc = 8;
constexpr int NTc = 77, LTc = 768, KRc = 1024, Nc = 2125, Ec = 2048;
constexpr float NEGC = -1000000.0f;

// Transposed K/V layout: [b][feature(1024)][token], row stride NP (16B-aligned)
constexpr int NP = 2128;  // 2125 tokens + 3 pad (zeroed in vT; guarded in kT reads)
constexpr long SKT = (long)Dc * NP;

// ---- Workspace layout ----
constexpr long F_STATS1 = 0;                    // 16,384
constexpr long F_STATS2 = F_STATS1 + 16384;     // 16,384
constexpr long F_KEYADD = F_STATS2 + 16384;     // 17,000
constexpr long F_VALMUL = F_KEYADD + 17000;     // 17,000
constexpr long F_SILU   = F_VALMUL + 17000;     // 16,384 (cs_m[8192] + cs_inv[8192])
constexpr long F_EO     = F_SILU + 16384;       // 16,384
constexpr long F_ATT    = F_EO + 16384;         // 1,048,576 (holds attT bf16 2MB)
constexpr long F_END    = F_ATT + 1048576;
// bf16 region
constexpr long KT_SZ   = (long)Bc * Dc * NP;    // 17,432,576
constexpr long B_NORMX = 0;                     // 8,388,608 (reused: att_part fp32, then y16)
constexpr long B_Q     = B_NORMX + 8388608;     // 8,388,608 (ren2 first, then q16, then s16)
constexpr long B_KT    = B_Q + 8388608;         // kT  [b][d][n]
constexpr long B_VT    = B_KT + KT_SZ;          // vT  [b][l][n] (reused: eo_part fp32 after att)
constexpr long B_NXF   = B_VT + KT_SZ;          // 473,088
// Weights: Q, KM, VM contiguous (fused QKVM B-operand = 3072 rows x 1024)
constexpr long B_WQ    = B_NXF + 473088;
constexpr long B_WKM   = B_WQ + 1048576;
constexpr long B_WVM   = B_WKM + 1048576;
constexpr long B_WKT   = B_WVM + 1048576;       // WtKT + WtVT contiguous (text B-operand)
constexpr long B_WVT   = B_WKT + 786432;
constexpr long B_WKR   = B_WVT + 786432;
constexpr long B_WVR   = B_WKR + 2097152;
constexpr long B_WO    = B_WVR + 1048576;
constexpr long B_END   = B_WO + 1048576;
constexpr size_t WS_NEED = (size_t)F_END * 4 + (size_t)B_END * 2;

__device__ __forceinline__ float b2f(bf16 v) { return __bfloat162float(v); }
__device__ __forceinline__ bf16 f2b(float v) { return __float2bfloat16(v); }
__device__ __forceinline__ short f2s(float v) {
    bf16 h = __float2bfloat16(v);
    return *reinterpret_cast<short*>(&h);
}
__device__ __forceinline__ float us2f(unsigned short u) {
    bf16 h = *reinterpret_cast<bf16*>(&u);
    return __bfloat162float(h);
}
__device__ __forceinline__ void storef(float* p, float v) { *p = v; }
__device__ __forceinline__ void storef(bf16* p, float v) { *p = __float2bfloat16(v); }

// async global->LDS, 16B per lane. LDS dest must be wave-uniform base + lane*16.
typedef __attribute__((address_space(1))) const unsigned int gu32;
typedef __attribute__((address_space(3))) unsigned int lu32;
__device__ __forceinline__ void gl_lds16(const void* g, void* l) {
    __builtin_amdgcn_global_load_lds((gu32*)g, (lu32*)l, 16, 0, 0);
}

__device__ __forceinline__ float2 block_sum2(float s, float s2) {
    #pragma unroll
    for (int off = 32; off > 0; off >>= 1) {
        s  += __shfl_down(s, off, 64);
        s2 += __shfl_down(s2, off, 64);
    }
    __shared__ float sh[4], sh2[4];
    int w = threadIdx.x >> 6, lane = threadIdx.x & 63;
    if (lane == 0) { sh[w] = s; sh2[w] = s2; }
    __syncthreads();
    s = sh[0] + sh[1] + sh[2] + sh[3];
    s2 = sh2[0] + sh2[1] + sh2[2] + sh2[3];
    return make_float2(s, s2);
}

// Row LayerNorm: one block (256 thr) per row
template <typename TO>
__global__ __launch_bounds__(256) void ln_rows(const float* __restrict__ in,
                                               const float* __restrict__ g,
                                               const float* __restrict__ b,
                                               TO* __restrict__ out, int C) {
    long row = blockIdx.x;
    const float* x = in + row * (long)C;
    TO* o = out + row * (long)C;
    float s = 0.f, s2 = 0.f;
    for (int c = threadIdx.x; c < C; c += 256) { float v = x[c]; s += v; s2 += v * v; }
    float2 r = block_sum2(s, s2);
    float mean = r.x / C;
    float var = r.y / C - mean * mean;
    float inv = rsqrtf(var + 1e-5f);
    for (int c = threadIdx.x; c < C; c += 256)
        storef(&o[c], (x[c] - mean) * inv * g[c] + b[c]);
}

// Both retrieval LN stats in one pass over re_motion
__global__ __launch_bounds__(256) void ln_stats_both(const float* __restrict__ motion,
                                                     const float* __restrict__ text,
                                                     float* __restrict__ stats1,
                                                     float* __restrict__ stats2) {
    long row = blockIdx.x;  // b*1024 + k*512 + r
    const float* m = motion + row * 1024;
    const float* tx = text + (row >> 9) * 1024;
    float s = 0.f, s2 = 0.f;
    for (int c = threadIdx.x; c < 1024; c += 256) { float v = m[c]; s += v; s2 += v * v; }
    float2 rm = block_sum2(s, s2);
    __syncthreads();
    float st = 0.f, st2 = 0.f;
    for (int c = threadIdx.x; c < 1024; c += 256) { float v = tx[c]; st += v; st2 += v * v; }
    float2 rt = block_sum2(st, st2);
    if (threadIdx.x == 0) {
        float mean2 = rm.x / 1024.f;
        float var2 = rm.y / 1024.f - mean2 * mean2;
        stats2[2 * row] = mean2;
        stats2[2 * row + 1] = rsqrtf(var2 + 1e-5f);
        float mean1 = (rm.x + rt.x) / 2048.f;
        float var1 = (rm.y + rt.y) / 2048.f - mean1 * mean1;
        stats1[2 * row] = mean1;
        stats1[2 * row + 1] = rsqrtf(var1 + 1e-5f);
    }
}

// Materialize normalized retrieval operands as bf16 (once):
// ren1[row][0:1024] = LN1(motion), ren1[row][1024:2048] = LN1(text); ren2 = LN2(motion)
__device__ __forceinline__ s16x4 pack4(float4 v, float mean, float rstd, float4 g, float4 b) {
    s16x4 o;
    o[0] = f2s((v.x - mean) * rstd * g.x + b.x);
    o[1] = f2s((v.y - mean) * rstd * g.y + b.y);
    o[2] = f2s((v.z - mean) * rstd * g.z + b.z);
    o[3] = f2s((v.w - mean) * rstd * g.w + b.w);
    return o;
}
__global__ __launch_bounds__(256) void materialize_ren(
    const float* __restrict__ motion, const float* __restrict__ text,
    const float* __restrict__ stats1, const float* __restrict__ stats2,
    const float* __restrict__ g1, const float* __restrict__ b1,
    const float* __restrict__ g2, const float* __restrict__ b2,
    bf16* __restrict__ ren1, bf16* __restrict__ ren2) {
    long row = blockIdx.x;  // b*1024 + kr
    int c = threadIdx.x * 4;
    const float* mrow = motion + row * 1024;
    const float* trow = text + (row >> 9) * 1024;
    float m1 = stats1[2 * row], r1 = stats1[2 * row + 1];
    float m2 = stats2[2 * row], r2 = stats2[2 * row + 1];
    float4 mv = *(const float4*)(mrow + c);
    float4 tv = *(const float4*)(trow + c);
    float4 g1m = *(const float4*)(g1 + c),        b1m = *(const float4*)(b1 + c);
    float4 g1t = *(const float4*)(g1 + 1024 + c), b1t = *(const float4*)(b1 + 1024 + c);
    float4 g2m = *(const float4*)(g2 + c),        b2m = *(const float4*)(b2 + c);
    *(s16x4*)((short*)ren1 + row * 2048 + c)        = pack4(mv, m1, r1, g1m, b1m);
    *(s16x4*)((short*)ren1 + row * 2048 + 1024 + c) = pack4(tv, m1, r1, g1t, b1t);
    *(s16x4*)((short*)ren2 + row * 1024 + c)        = pack4(mv, m2, r2, g2m, b2m);
}

// Per-(b, n) key additive mask and value multiplicative mask
__global__ __launch_bounds__(256) void prep_masks(const int* __restrict__ cond_type,
                                                  const float* __restrict__ src_mask,
                                                  const float* __restrict__ re_mask,
                                                  float* __restrict__ key_add,
                                                  float* __restrict__ val_mul) {
    int idx = blockIdx.x * 256 + threadIdx.x;
    if (idx >= Bc * Nc) return;
    int b = idx / Nc, n = idx % Nc;
    int ct = cond_type[b];
    float text_ct = ((ct % 10) > 0) ? 1.f : 0.f;
    float retr_ct = ((ct / 10) > 0) ? 1.f : 0.f;
    float add, mul;
    if (n < NTc) {
        add = (1.f - text_ct) * NEGC; mul = text_ct;
    } else if (n < NTc + KRc) {
        float rm = re_mask[b * KRc + (n - NTc)];
        add = (1.f - retr_ct) * NEGC + (1.f - rm) * NEGC;
        mul = retr_ct * rm;
    } else {
        float sm = src_mask[b * Tc + (n - NTc - KRc)];
        add = (1.f - sm) * NEGC; mul = sm;
    }
    key_add[idx] = add;
    val_mul[idx] = mul;
}

// Zero the 3 pad columns of vT (keeps MFMA tail reads finite; kT pad is guarded)
__global__ __launch_bounds__(256) void zero_tail(bf16* __restrict__ vT) {
    int row = blockIdx.x * 256 + threadIdx.x;
    if (row >= Bc * Dc) return;
    bf16* p = vT + (long)row * NP + Nc;
    p[0] = f2b(0.f); p[1] = f2b(0.f); p[2] = f2b(0.f);
}

// All 8 weight transposes in ONE launch: W[K][1024] fp32 -> Wt[1024][K] bf16
__global__ __launch_bounds__(256) void transpose_all(
    const float* __restrict__ Wq,  const float* __restrict__ Wkt,
    const float* __restrict__ Wvt, const float* __restrict__ Wkm,
    const float* __restrict__ Wvm, const float* __restrict__ Wkr,
    const float* __restrict__ Wvr, const float* __restrict__ Wo,
    short* __restrict__ WtQ,  short* __restrict__ WtKT,
    short* __restrict__ WtVT, short* __restrict__ WtKM,
    short* __restrict__ WtVM, short* __restrict__ WtKR,
    short* __restrict__ WtVR, short* __restrict__ WtO) {
    __shared__ float t[32][33];
    int sy = blockIdx.y;
    const float* W; short* Wt; int K; int ky;
    if (sy < 32)       { W = Wq;  Wt = WtQ;  K = 1024; ky = sy; }
    else if (sy < 56)  { W = Wkt; Wt = WtKT; K = 768;  ky = sy - 32; }
    else if (sy < 80)  { W = Wvt; Wt = WtVT; K = 768;  ky = sy - 56; }
    else if (sy < 112) { W = Wkm; Wt = WtKM; K = 1024; ky = sy - 80; }
    else if (sy < 144) { W = Wvm; Wt = WtVM; K = 1024; ky = sy - 112; }
    else if (sy < 208) { W = Wkr; Wt = WtKR; K = 2048; ky = sy - 144; }
    else if (sy < 240) { W = Wvr; Wt = WtVR; K = 1024; ky = sy - 208; }
    else               { W = Wo;  Wt = WtO;  K = 1024; ky = sy - 240; }
    int n0 = blockIdx.x * 32, k0 = ky * 32;
    int tx = threadIdx.x & 31, ty = threadIdx.x >> 5;
    #pragma unroll
    for (int i = 0; i < 4; ++i)
        t[ty + i * 8][tx] = W[(long)(k0 + ty + i * 8) * 1024 + n0 + tx];
    __syncthreads();
    #pragma unroll
    for (int i = 0; i < 4; ++i)
        Wt[(long)(n0 + ty + i * 8) * K + k0 + tx] = f2s(t[tx][ty + i * 8]);
}

// ======================= 128^2 MFMA GEMM template pieces ====================
// NOTE (R4/R5 post-mortem): 512-thread 256^2 template spilled acc to scratch
// (hipcc caps 128 VGPR/wave at 8 waves/WG) -> 1 GB scratch writes. Stay 256-thr.
constexpr int LDK = 64;

// ===== MEGA: qkvm (1536) + retrK (512) + text (128) in ONE 2176-block launch =====
// jid [0,512): retr-K  (A=ren1, K=2048, TR +key_add)        [XCD-swizzled]
// jid [512,2048): qkvm (A=norm_x, K=1024, 3 sections)       [XCD-swizzled]
// jid [2048,2176): text (A=nxf per b, K=768, M=77, 2 sect)
__global__ __launch_bounds__(256) void gemm_mega(
    const short* __restrict__ norm_x, const short* __restrict__ ren1,
    const short* __restrict__ nxf,
    const short* __restrict__ WtQKVM, const short* __restrict__ WtKR,
    const short* __restrict__ WtTXT,
    const float* __restrict__ bq, const float* __restrict__ bkm,
    const float* __restrict__ bvm, const float* __restrict__ bkr,
    const float* __restrict__ bkt, const float* __restrict__ bvt,
    const float* __restrict__ key_add, const float* __restrict__ val_mul,
    bf16* __restrict__ q16, bf16* __restrict__ kT, bf16* __restrict__ vT) {
    int jid = blockIdx.x;
    int sect, tm, tn, K, M, lda, bb = 0;
    const short* A; const short* Bt;
    if (jid < 512) {
        sect = 0;
        int s = (jid & 7) * 64 + (jid >> 3);    // XCD swizzle (512 % 8 == 0)
        bb = s >> 6; int r = s & 63;
        tm = (r >> 3) * 128; tn = (r & 7) * 128;
        A = ren1 + (long)bb * KRc * 2048; lda = 2048; K = 2048; M = 1024;
        Bt = WtKR;
    } else if (jid < 2048) {
        sect = 1;
        int l = jid - 512;
        int s = (l & 7) * 192 + (l >> 3);       // XCD swizzle (1536 % 8 == 0)
        tn = (s % 24) * 128; tm = (s / 24) * 128;
        A = norm_x; lda = 1024; K = 1024; M = 8192;
        Bt = WtQKVM;
    } else {
        sect = 2;
        int l = jid - 2048;
        bb = l >> 4; tn = (l & 15) * 128; tm = 0;
        A = nxf + (long)bb * NTc * LTc; lda = 768; K = 768; M = 77;
        Bt = WtTXT;
    }
    const int ldb = lda;  // all B operands have ldb == K == lda's K-extent
    const bool swap_ops = !(sect == 1 && tn < 1024);

    __shared__ __align__(16) short As[128 * LDK];
    __shared__ __align__(16) short Bs[128 * LDK];

    int tid = threadIdx.x;
    int lane = tid & 63, wid = tid >> 6;
    int wi = wid >> 1, wj = wid & 1;
    int l16 = lane & 15, quad = lane >> 4;

    f32x4 acc[4][4];
    #pragma unroll
    for (int i = 0; i < 4; ++i)
        #pragma unroll
        for (int j = 0; j < 4; ++j)
            acc[i][j] = (f32x4){0.f, 0.f, 0.f, 0.f};

    auto issue = [&](int k0) {
        #pragma unroll
        for (int p = 0; p < 4; ++p) {
            int e = p * 256 + tid;
            int row = e >> 3, c8 = e & 7;
            int gm = tm + row;
            if (gm >= M) gm = M - 1;  // clamp: garbage rows never stored
            gl_lds16(A + (long)gm * lda + k0 + c8 * 8, &As[row * LDK + c8 * 8]);
            gl_lds16(Bt + (long)(tn + row) * ldb + k0 + c8 * 8, &Bs[row * LDK + c8 * 8]);
        }
    };

    issue(0);
    int kt = 0;
    while (true) {
        __syncthreads();
        #pragma unroll
        for (int kk = 0; kk < 2; ++kk) {
            s16x8 af[4], bfr[4];
            #pragma unroll
            for (int i = 0; i < 4; ++i)
                af[i] = *(const s16x8*)&As[(wi * 64 + i * 16 + l16) * LDK + kk * 32 + quad * 8];
            #pragma unroll
            for (int j = 0; j < 4; ++j)
                bfr[j] = *(const s16x8*)&Bs[(wj * 64 + j * 16 + l16) * LDK + kk * 32 + quad * 8];
            if (swap_ops) {
                #pragma unroll
                for (int i = 0; i < 4; ++i)
                    #pragma unroll
                    for (int j = 0; j < 4; ++j)
                        acc[i][j] = __builtin_amdgcn_mfma_f32_16x16x32_bf16(bfr[j], af[i], acc[i][j], 0, 0, 0);
            } else {
                #pragma unroll
                for (int i = 0; i < 4; ++i)
                    #pragma unroll
                    for (int j = 0; j < 4; ++j)
                        acc[i][j] = __builtin_amdgcn_mfma_f32_16x16x32_bf16(af[i], bfr[j], acc[i][j], 0, 0, 0);
            }
        }
        int nxt = kt + 64;
        if (nxt >= K) break;
        __syncthreads();
        issue(nxt);
        kt = nxt;
    }

    if (sect == 1 && tn < 1024) {
        // Q: plain [token][feature] store
        #pragma unroll
        for (int i = 0; i < 4; ++i) {
            #pragma unroll
            for (int r = 0; r < 4; ++r) {
                int gm = tm + wi * 64 + i * 16 + quad * 4 + r;
                #pragma unroll
                for (int j = 0; j < 4; ++j) {
                    int gn = tn + wj * 64 + j * 16 + l16;
                    q16[(long)gm * Dc + gn] = f2b(acc[i][j][r] + bq[gn]);
                }
            }
        }
    } else if (sect == 1) {
        // KM / VM: TR store with per-(b,tok) mask, b = gm>>10
        int sec = tn >> 10, fn0 = tn & 1023;
        const float* bias = (sec == 1) ? bkm : bvm;
        bf16* C = (sec == 1) ? kT : vT;
        #pragma unroll
        for (int j = 0; j < 4; ++j) {
            #pragma unroll
            for (int r = 0; r < 4; ++r) {
                int feat = fn0 + wj * 64 + j * 16 + quad * 4 + r;
                float bf_ = bias[feat];
                #pragma unroll
                for (int i = 0; i < 4; ++i) {
                    int gm = tm + wi * 64 + i * 16 + l16;
                    int b = gm >> 10, tok = gm & 1023;
                    int mi = b * Nc + NTc + KRc + tok;
                    float v = acc[i][j][r] + bf_;
                    if (sec == 1) v += key_add[mi];
                    else          v *= val_mul[mi];
                    C[(long)b * SKT + (long)feat * NP + NTc + KRc + tok] = f2b(v);
                }
            }
        }
    } else if (sect == 0) {
        // retr-K: TR store + key_add
        const float* rmask = key_add + bb * Nc + NTc;
        bf16* C = kT + (long)bb * SKT + NTc;
        #pragma unroll
        for (int j = 0; j < 4; ++j) {
            #pragma unroll
            for (int r = 0; r < 4; ++r) {
                int feat = tn + wj * 64 + j * 16 + quad * 4 + r;
                float bf_ = bkr[feat];
                #pragma unroll
                for (int i = 0; i < 4; ++i) {
                    int tok = tm + wi * 64 + i * 16 + l16;
                    C[(long)feat * NP + tok] = f2b(acc[i][j][r] + bf_ + rmask[tok]);
                }
            }
        }
    } else {
        // text: sec 0 -> kT (+add), sec 1 -> vT (*mul); tok < 77
        int sec = tn >> 10, fn0 = tn & 1023;
        const float* bias = sec ? bvt : bkt;
        const float* rmask = (sec ? val_mul : key_add) + bb * Nc;
        bf16* C = (sec ? vT : kT) + (long)bb * SKT;
        #pragma unroll
        for (int j = 0; j < 4; ++j) {
            #pragma unroll
            for (int r = 0; r < 4; ++r) {
                int feat = fn0 + wj * 64 + j * 16 + quad * 4 + r;
                float bf_ = bias[feat];
                #pragma unroll
                for (int i = 0; i < 4; ++i) {
                    int tok = wi * 64 + i * 16 + l16;
                    if (tok >= NTc) continue;
                    float v = acc[i][j][r] + bf_;
                    if (sec) v *= rmask[tok];
                    else     v += rmask[tok];
                    C[(long)feat * NP + tok] = f2b(v);
                }
            }
        }
    }
}

// ===== value_retr GEMM (separate: reads ren2 which aliases q16 region) =====
// 1D grid of 512, XCD-swizzled.
__global__ __launch_bounds__(256) void gemm_vr(
    const short* __restrict__ ren2, const short* __restrict__ WtVR,
    const float* __restrict__ bvr, const float* __restrict__ val_mul,
    bf16* __restrict__ vT) {
    int s = (blockIdx.x & 7) * 64 + (blockIdx.x >> 3);
    int b = s >> 6; int r = s & 63;
    const int tm = (r >> 3) * 128;
    const int tn = (r & 7) * 128;
    const short* A = ren2 + (long)b * KRc * 1024;
    const float* rmask = val_mul + b * Nc + NTc;
    bf16* C = vT + (long)b * SKT + NTc;

    __shared__ __align__(16) short As[128 * LDK];
    __shared__ __align__(16) short Bs[128 * LDK];

    int tid = threadIdx.x;
    int lane = tid & 63, wid = tid >> 6;
    int wi = wid >> 1, wj = wid & 1;
    int l16 = lane & 15, quad = lane >> 4;

    f32x4 acc[4][4];
    #pragma unroll
    for (int i = 0; i < 4; ++i)
        #pragma unroll
        for (int j = 0; j < 4; ++j)
            acc[i][j] = (f32x4){0.f, 0.f, 0.f, 0.f};

    auto issue = [&](int k0) {
        #pragma unroll
        for (int p = 0; p < 4; ++p) {
            int e = p * 256 + tid;
            int row = e >> 3, c8 = e & 7;
            gl_lds16(A + (long)(tm + row) * 1024 + k0 + c8 * 8, &As[row * LDK + c8 * 8]);
            gl_lds16(WtVR + (long)(tn + row) * 1024 + k0 + c8 * 8, &Bs[row * LDK + c8 * 8]);
        }
    };

    issue(0);
    int kt = 0;
    while (true) {
        __syncthreads();
        #pragma unroll
        for (int kk = 0; kk < 2; ++kk) {
            s16x8 af[4], bfr[4];
            #pragma unroll
            for (int i = 0; i < 4; ++i)
                af[i] = *(const s16x8*)&As[(wi * 64 + i * 16 + l16) * LDK + kk * 32 + quad * 8];
            #pragma unroll
            for (int j = 0; j < 4; ++j)
                bfr[j] = *(const s16x8*)&Bs[(wj * 64 + j * 16 + l16) * LDK + kk * 32 + quad * 8];
            #pragma unroll
            for (int i = 0; i < 4; ++i)
                #pragma unroll
                for (int j = 0; j < 4; ++j)
                    acc[i][j] = __builtin_amdgcn_mfma_f32_16x16x32_bf16(bfr[j], af[i], acc[i][j], 0, 0, 0);
        }
        int nxt = kt + 64;
        if (nxt >= 1024) break;
        __syncthreads();
        issue(nxt);
        kt = nxt;
    }

    #pragma unroll
    for (int j = 0; j < 4; ++j) {
        #pragma unroll
        for (int r2 = 0; r2 < 4; ++r2) {
            int feat = tn + wj * 64 + j * 16 + quad * 4 + r2;
            float bf_ = bvr[feat];
            #pragma unroll
            for (int i = 0; i < 4; ++i) {
                int tok = tm + wi * 64 + i * 16 + l16;
                C[(long)feat * NP + tok] = f2b((acc[i][j][r2] + bf_) * rmask[tok]);
            }
        }
    }
}

// ===== generic 128^2 GEMM (final out only), XCD-swizzled =====
template <typename TC>
__global__ __launch_bounds__(256) void gemm_bt(
    const short* __restrict__ A, int lda,
    const short* __restrict__ Bt, int ldb,
    const float* __restrict__ bias,
    const float* __restrict__ addC, int ldac,
    TC* __restrict__ C, int ldc, int K) {
    int nx = gridDim.x;
    int nwg = nx * gridDim.y;
    int lin = blockIdx.y * nx + blockIdx.x;
    int bx = blockIdx.x, by = blockIdx.y;
    if ((nwg & 7) == 0) {
        int chunk = nwg >> 3;
        int swz = (lin & 7) * chunk + (lin >> 3);
        bx = swz % nx; by = swz / nx;
    }
    const int tm = by * 128;
    const int tn = bx * 128;

    __shared__ __align__(16) short As[128 * LDK];
    __shared__ __align__(16) short Bs[128 * LDK];

    int tid = threadIdx.x;
    int lane = tid & 63, wid = tid >> 6;
    int wi = wid >> 1, wj = wid & 1;
    int l16 = lane & 15, quad = lane >> 4;

    f32x4 acc[4][4];
    #pragma unroll
    for (int i = 0; i < 4; ++i)
        #pragma unroll
        for (int j = 0; j < 4; ++j)
            acc[i][j] = (f32x4){0.f, 0.f, 0.f, 0.f};

    auto issue = [&](int k0) {
        #pragma unroll
        for (int p = 0; p < 4; ++p) {
            int e = p * 256 + tid;
            int row = e >> 3, c8 = e & 7;
            gl_lds16(A + (long)(tm + row) * lda + k0 + c8 * 8, &As[row * LDK + c8 * 8]);
            gl_lds16(Bt + (long)(tn + row) * ldb + k0 + c8 * 8, &Bs[row * LDK + c8 * 8]);
        }
    };

    issue(0);
    int kt = 0;
    while (true) {
        __syncthreads();
        #pragma unroll
        for (int kk = 0; kk < 2; ++kk) {
            s16x8 af[4], bfr[4];
            #pragma unroll
            for (int i = 0; i < 4; ++i)
                af[i] = *(const s16x8*)&As[(wi * 64 + i * 16 + l16) * LDK + kk * 32 + quad * 8];
            #pragma unroll
            for (int j = 0; j < 4; ++j)
                bfr[j] = *(const s16x8*)&Bs[(wj * 64 + j * 16 + l16) * LDK + kk * 32 + quad * 8];
            #pragma unroll
            for (int i = 0; i < 4; ++i)
                #pragma unroll
                for (int j = 0; j < 4; ++j)
                    acc[i][j] = __builtin_amdgcn_mfma_f32_16x16x32_bf16(af[i], bfr[j], acc[i][j], 0, 0, 0);
        }
        int nxt = kt + 64;
        if (nxt >= K) break;
        __syncthreads();
        issue(nxt);
        kt = nxt;
    }

    #pragma unroll
    for (int i = 0; i < 4; ++i) {
        #pragma unroll
        for (int r = 0; r < 4; ++r) {
            int gm = tm + wi * 64 + i * 16 + quad * 4 + r;
            #pragma unroll
            for (int j = 0; j < 4; ++j) {
                int gn = tn + wj * 64 + j * 16 + l16;
                float v = acc[i][j][r] + bias[gn];
                if (addC) v += addC[(long)gm * ldac + gn];
                storef(&C[(long)gm * ldc + gn], v);
            }
        }
    }
}

// eo split-K
__global__ __launch_bounds__(256) void eo_partial(const float* __restrict__ emb,
                                                  const float* __restrict__ We,
                                                  float* __restrict__ part) {
    int nb = blockIdx.x;
    int ks = blockIdx.y;
    int n = nb * 256 + threadIdx.x;
    int k0 = ks * 64;
    __shared__ float a_s[8][64];
    for (int idx = threadIdx.x; idx < 512; idx += 256) {
        int b = idx >> 6, kk = idx & 63;
        float v = emb[b * 2048 + k0 + kk];
        a_s[b][kk] = v / (1.f + expf(-v));
    }
    __syncthreads();
    float acc[8] = {};
    for (int kk = 0; kk < 64; ++kk) {
        float w = We[(long)(k0 + kk) * 2048 + n];
        #pragma unroll
        for (int b = 0; b < 8; ++b) acc[b] = fmaf(a_s[b][kk], w, acc[b]);
    }
    #pragma unroll
    for (int b = 0; b < 8; ++b) part[((long)ks * 8 + b) * 2048 + n] = acc[b];
}

__global__ __launch_bounds__(256) void eo_reduce(const float* __restrict__ part,
                                                 const float* __restrict__ be,
                                                 float* __restrict__ eo) {
    int idx = blockIdx.x * 256 + threadIdx.x;
    int n = idx & 2047, b = idx >> 11;
    float s = be[n];
    #pragma unroll 8
    for (int ks = 0; ks < 32; ++ks) s += part[((long)ks * 8 + b) * 2048 + n];
    eo[idx] = s;
}

// q softmax over head dim (128): one wave per row, 2 elems/lane.
__global__ __launch_bounds__(256) void softmax_head(bf16* __restrict__ q) {
    long row = (long)blockIdx.x * 4 + (threadIdx.x >> 6);
    int lane = threadIdx.x & 63;
    bf16* p = q + row * 128 + lane * 2;
    float v0 = b2f(p[0]), v1 = b2f(p[1]);
    float mx = fmaxf(v0, v1);
    #pragma unroll
    for (int off = 32; off > 0; off >>= 1) mx = fmaxf(mx, __shfl_xor(mx, off, 64));
    float e0 = expf(v0 - mx), e1 = expf(v1 - mx);
    float s = e0 + e1;
    #pragma unroll
    for (int off = 32; off > 0; off >>= 1) s += __shfl_xor(s, off, 64);
    float inv = 1.f / s;
    p[0] = f2b(e0 * inv);
    p[1] = f2b(e1 * inv);
}

// key softmax column stats over tokens — ROW reduction on kT[b][d][n].
__global__ __launch_bounds__(256) void ksm_rows(const bf16* __restrict__ kT,
                                                float* __restrict__ cs_m,
                                                float* __restrict__ cs_inv) {
    int row = blockIdx.x * 4 + (threadIdx.x >> 6);  // b*1024 + feature
    int lane = threadIdx.x & 63;
    const s16x8* p8 = (const s16x8*)(kT + (long)row * NP);
    float m = -3.0e38f;
    for (int c = lane; c < NP / 8; c += 64) {
        s16x8 raw = p8[c];
        int n0 = c * 8;
        #pragma unroll
        for (int j = 0; j < 8; ++j)
            if (n0 + j < Nc) m = fmaxf(m, us2f((unsigned short)raw[j]));
    }
    #pragma unroll
    for (int off = 32; off > 0; off >>= 1) m = fmaxf(m, __shfl_xor(m, off, 64));
    float s = 0.f;
    for (int c = lane; c < NP / 8; c += 64) {
        s16x8 raw = p8[c];
        int n0 = c * 8;
        #pragma unroll
        for (int j = 0; j < 8; ++j)
            if (n0 + j < Nc) s += __expf(us2f((unsigned short)raw[j]) - m);
    }
    #pragma unroll
    for (int off = 32; off > 0; off >>= 1) s += __shfl_xor(s, off, 64);
    if (lane == 0) { cs_m[row] = m; cs_inv[row] = 1.f / s; }
}

// att_part[split][bh][l][d] = sum_{n in split} exp(kT[bd][n]-m_d) * vT[bl][n]  (C^T store)
constexpr int ATT_SPLIT = 4;
__global__ __launch_bounds__(256) void att_gemm(const bf16* __restrict__ kTb,
                                                const bf16* __restrict__ vTb,
                                                const float* __restrict__ cs_m,
                                                float* __restrict__ att_part) {
    int bh = blockIdx.x;
    int split = blockIdx.y;
    int b = bh >> 3, h = bh & 7;
    const short* A  = (const short*)kTb + ((long)b * 1024 + h * 128) * NP;
    const short* Bt = (const short*)vTb + ((long)b * 1024 + h * 128) * NP;
    float* ap = att_part + ((long)split * 64 + bh) * 16384;

    __shared__ __align__(16) short As[128 * LDK];
    __shared__ __align__(16) short Bs[128 * LDK];
    __shared__ float ms[128];

    int tid = threadIdx.x;
    if (tid < 128) ms[tid] = cs_m[(long)b * 1024 + h * 128 + tid];

    int lane = tid & 63, wid = tid >> 6;
    int wi = wid >> 1, wj = wid & 1;
    int l16 = lane & 15, quad = lane >> 4;

    f32x4 acc[4][4];
    #pragma unroll
    for (int i = 0; i < 4; ++i)
        #pragma unroll
        for (int j = 0; j < 4; ++j)
            acc[i][j] = (f32x4){0.f, 0.f, 0.f, 0.f};

    uint4 pa[4];
    auto computeA = [&](int k0) {
        #pragma unroll
        for (int p = 0; p < 4; ++p) {
            int e = p * 256 + tid;
            int row = e >> 3, c8 = e & 7;
            int n0 = k0 + c8 * 8;
            union { short s[8]; uint4 u; } pk;
            if (n0 >= Nc) {
                pk.u = (uint4){0u, 0u, 0u, 0u};
            } else {
                float m = ms[row];
                s16x8 raw = *(const s16x8*)(A + (long)row * NP + n0);
                #pragma unroll
                for (int j = 0; j < 8; ++j) {
                    float v = (n0 + j < Nc) ? __expf(us2f((unsigned short)raw[j]) - m) : 0.f;
                    pk.s[j] = f2s(v);
                }
            }
            pa[p] = pk.u;
        }
    };
    auto issueB = [&](int k0) {
        #pragma unroll
        for (int p = 0; p < 4; ++p) {
            int e = p * 256 + tid;
            int row = e >> 3, c8 = e & 7;
            int n0 = k0 + c8 * 8;
            if (n0 > NP - 8) n0 = NP - 8;  // clamp: A is zero there, values just must be finite
            gl_lds16(Bt + (long)row * NP + n0, &Bs[row * LDK + c8 * 8]);
        }
    };
    auto storeA = [&]() {
        #pragma unroll
        for (int p = 0; p < 4; ++p) {
            int e = p * 256 + tid;
            int row = e >> 3, c8 = e & 7;
            *(uint4*)&As[row * LDK + c8 * 8] = pa[p];
        }
    };

    // 34 K-steps total, split {9,9,8,8}
    int st = (split < 2) ? split * 9 : 18 + (split - 2) * 8;
    int cnt = (split < 2) ? 9 : 8;
    int kt = st * 64;
    int kend = kt + cnt * 64;

    __syncthreads();  // ms ready
    issueB(kt);
    computeA(kt);
    storeA();
    while (true) {
        __syncthreads();
        #pragma unroll
        for (int kk = 0; kk < 2; ++kk) {
            s16x8 af[4], bfr[4];
            #pragma unroll
            for (int i = 0; i < 4; ++i)
                af[i] = *(const s16x8*)&As[(wi * 64 + i * 16 + l16) * LDK + kk * 32 + quad * 8];
            #pragma unroll
            for (int j = 0; j < 4; ++j)
                bfr[j] = *(const s16x8*)&Bs[(wj * 64 + j * 16 + l16) * LDK + kk * 32 + quad * 8];
            #pragma unroll
            for (int i = 0; i < 4; ++i)
                #pragma unroll
                for (int j = 0; j < 4; ++j)
                    acc[i][j] = __builtin_amdgcn_mfma_f32_16x16x32_bf16(bfr[j], af[i], acc[i][j], 0, 0, 0);
        }
        int nxt = kt + 64;
        if (nxt >= kend) break;
        computeA(nxt);
        __syncthreads();
        issueB(nxt);
        storeA();
        kt = nxt;
    }

    // C^T: acc rows = value-feature l (tile j), cols = key-feature d (tile i)
    #pragma unroll
    for (int j = 0; j < 4; ++j) {
        #pragma unroll
        for (int r = 0; r < 4; ++r) {
            int l = wj * 64 + j * 16 + quad * 4 + r;
            #pragma unroll
            for (int i = 0; i < 4; ++i) {
                int d = wi * 64 + i * 16 + l16;
                ap[l * 128 + d] = acc[i][j][r];
            }
        }
    }
}

// reduce splits + apply per-d 1/sum -> bf16 attT[bh][l][d] (ready B^T operand for y)
__global__ __launch_bounds__(256) void reduce_att_t(const float* __restrict__ att_part,
                                                    const float* __restrict__ cs_inv,
                                                    bf16* __restrict__ attT) {
    long idx = (long)blockIdx.x * 256 + threadIdx.x;
    if (idx >= (long)64 * 16384) return;
    float s = 0.f;
    #pragma unroll
    for (int sp = 0; sp < ATT_SPLIT; ++sp) s += att_part[(long)sp * 64 * 16384 + idx];
    int bh = (int)(idx >> 14);
    int d = (int)(idx & 127);
    int b = bh >> 3, h = bh & 7;
    attT[idx] = f2b(s * cs_inv[b * Dc + h * 128 + d]);
}

// y[b,t,h*128+l] = sum_d q[b,t,h*128+d] * att[bh][d][l] — MFMA, K=128 single stage.
__global__ __launch_bounds__(256) void y_gemm(const bf16* __restrict__ q,
                                              const bf16* __restrict__ attT,
                                              bf16* __restrict__ y) {
    int bh = blockIdx.y;
    int b = bh >> 3, h = bh & 7;
    const short* A  = (const short*)q + (long)b * Tc * Dc + h * 128;   // row stride Dc
    const short* Bt = (const short*)attT + (long)bh * 16384;           // [l][d] stride 128
    bf16* yb = y + (long)b * Tc * Dc + h * 128;
    int tm = blockIdx.x * 128;

    __shared__ __align__(16) short As[128 * 128];
    __shared__ __align__(16) short Bs[128 * 128];
    int tid = threadIdx.x;
    #pragma unroll
    for (int p = 0; p < 8; ++p) {
        int e = p * 256 + tid;
        int row = e >> 4, c8 = e & 15;
        gl_lds16(A + (long)(tm + row) * Dc + c8 * 8, &As[row * 128 + c8 * 8]);
        gl_lds16(Bt + row * 128 + c8 * 8, &Bs[row * 128 + c8 * 8]);
    }
    int lane = tid & 63, wid = tid >> 6;
    int wi = wid >> 1, wj = wid & 1;
    int l16 = lane & 15, quad = lane >> 4;
    f32x4 acc[4][4];
    #pragma unroll
    for (int i = 0; i < 4; ++i)
        #pragma unroll
        for (int j = 0; j < 4; ++j)
            acc[i][j] = (f32x4){0.f, 0.f, 0.f, 0.f};
    __syncthreads();
    #pragma unroll
    for (int kk = 0; kk < 4; ++kk) {
        s16x8 af[4], bfr[4];
        #pragma unroll
        for (int i = 0; i < 4; ++i)
            af[i] = *(const s16x8*)&As[(wi * 64 + i * 16 + l16) * 128 + kk * 32 + quad * 8];
        #pragma unroll
        for (int j = 0; j < 4; ++j)
            bfr[j] = *(const s16x8*)&Bs[(wj * 64 + j * 16 + l16) * 128 + kk * 32 + quad * 8];
        #pragma unroll
        for (int i = 0; i < 4; ++i)
            #pragma unroll
            for (int j = 0; j < 4; ++j)
                acc[i][j] = __builtin_amdgcn_mfma_f32_16x16x32_bf16(af[i], bfr[j], acc[i][j], 0, 0, 0);
    }
    #pragma unroll
    for (int i = 0; i < 4; ++i) {
        #pragma unroll
        for (int r = 0; r < 4; ++r) {
            int gm = tm + wi * 64 + i * 16 + quad * 4 + r;
            #pragma unroll
            for (int j = 0; j < 4; ++j) {
                int gn = wj * 64 + j * 16 + l16;
                yb[(long)gm * Dc + gn] = f2b(acc[i][j][r]);
            }
        }
    }
}

// s = silu( LN(y)*(1+scale) + shift )
__global__ __launch_bounds__(256) void film_kernel(const bf16* __restrict__ y,
                                                   const float* __restrict__ eo,
                                                   const float* __restrict__ g,
                                                   const float* __restrict__ bta,
                                                   bf16* __restrict__ s) {
    long row = blockIdx.x;
    int b = (int)(row >> 10);
    const bf16* yr = y + row * Dc;
    float sum = 0.f, sum2 = 0.f;
    for (int c = threadIdx.x; c < Dc; c += 256) { float v = b2f(yr[c]); sum += v; sum2 += v * v; }
    float2 r = block_sum2(sum, sum2);
    float mean = r.x / Dc;
    float var = r.y / Dc - mean * mean;
    float inv = rsqrtf(var + 1e-5f);
    const float* sc = eo + (long)b * 2048;
    const float* sf = sc + 1024;
    bf16* so = s + row * Dc;
    for (int c = threadIdx.x; c < Dc; c += 256) {
        float v = (b2f(yr[c]) - mean) * inv * g[c] + bta[c];
        v = v * (1.f + sc[c]) + sf[c];
        so[c] = f2b(v / (1.f + expf(-v)));
    }
}

extern "C" void kernel_launch(void* const* d_in, const int* in_sizes, int n_in,
                              void* d_out, int out_size, void* d_ws, size_t ws_size,
                              hipStream_t stream) {
    if (ws_size < WS_NEED) return;

    const float* x         = (const float*)d_in[0];
    const float* xf        = (const float*)d_in[1];
    const float* emb       = (const float*)d_in[2];
    const float* src_mask  = (const float*)d_in[3];
    const int*   cond_type = (const int*)d_in[4];
    const float* re_motion = (const float*)d_in[5];
    const float* re_text   = (const float*)d_in[6];
    const float* re_mask   = (const float*)d_in[7];
    const float* ln_g  = (const float*)d_in[8];
    const float* ln_b  = (const float*)d_in[9];
    const float* tln_g = (const float*)d_in[10];
    const float* tln_b = (const float*)d_in[11];
    const float* rn1_g = (const float*)d_in[12];
    const float* rn1_b = (const float*)d_in[13];
    const float* rn2_g = (const float*)d_in[14];
    const float* rn2_b = (const float*)d_in[15];
    const float* Wq  = (const float*)d_in[16];
    const float* bq  = (const float*)d_in[17];
    const float* Wkt = (const float*)d_in[18];
    const float* bkt = (const float*)d_in[19];
    const float* Wvt = (const float*)d_in[20];
    const float* bvt = (const float*)d_in[21];
    const float* Wkm = (const float*)d_in[22];
    const float* bkm = (const float*)d_in[23];
    const float* Wvm = (const float*)d_in[24];
    const float* bvm = (const float*)d_in[25];
    const float* Wkr = (const float*)d_in[26];
    const float* bkr = (const float*)d_in[27];
    const float* Wvr = (const float*)d_in[28];
    const float* bvr = (const float*)d_in[29];
    const float* We  = (const float*)d_in[30];
    const float* be  = (const float*)d_in[31];
    const float* sln_g = (const float*)d_in[32];
    const float* sln_b = (const float*)d_in[33];
    const float* Wo  = (const float*)d_in[34];
    const float* bo  = (const float*)d_in[35];

    float* ws = (float*)d_ws;
    float* stats1   = ws + F_STATS1;
    float* stats2   = ws + F_STATS2;
    float* key_add  = ws + F_KEYADD;
    float* val_mul  = ws + F_VALMUL;
    float* cs_m     = ws + F_SILU;         // 8192
    float* cs_inv   = cs_m + Bc * Dc;      // 8192
    float* eo       = ws + F_EO;
    bf16*  attT     = (bf16*)(ws + F_ATT); // 2MB bf16 in 4MB slot
    bf16* wb = (bf16*)(ws + F_END);
    bf16* norm_x16 = wb + B_NORMX;
    bf16* q16      = wb + B_Q;
    bf16* kT16     = wb + B_KT;
    bf16* vT16     = wb + B_VT;
    bf16* nxf16    = wb + B_NXF;
    short* WtQ  = (short*)(wb + B_WQ);     // WtQ/WtKM/WtVM contiguous = QKVM B-operand
    short* WtKM = (short*)(wb + B_WKM);
    short* WtVM = (short*)(wb + B_WVM);
    short* WtKT = (short*)(wb + B_WKT);    // WtKT/WtVT contiguous = text B-operand
    short* WtVT = (short*)(wb + B_WVT);
    short* WtKR = (short*)(wb + B_WKR);
    short* WtVR = (short*)(wb + B_WVR);
    short* WtO  = (short*)(wb + B_WO);
    float* att_part = (float*)(wb + B_NORMX);  // overlays norm_x16 (dead by then)
    bf16* y16 = wb + B_NORMX;                  // written after att_part consumed
    bf16* s16 = q16;                           // q dead after y_gemm
    float* eo_part = (float*)(wb + B_VT);      // overlays vT16 (dead after att_gemm)
    bf16* ren1 = (bf16*)d_out;                 // 32MB scratch, dead before final out
    bf16* ren2 = q16;                          // consumed by gemm_vr BEFORE mega writes q16

    float* out = (float*)d_out;

    // 1. LayerNorms + stats
    ln_rows<bf16><<<dim3(Bc * Tc), dim3(256), 0, stream>>>(x, ln_g, ln_b, norm_x16, Dc);
    ln_rows<bf16><<<dim3(Bc * NTc), dim3(256), 0, stream>>>(xf, tln_g, tln_b, nxf16, LTc);
    ln_stats_both<<<dim3(Bc * KRc), dim3(256), 0, stream>>>(re_motion, re_text, stats1, stats2);

    // 2. Masks + vT pad zero-fill
    prep_masks<<<dim3((Bc * Nc + 255) / 256), dim3(256), 0, stream>>>(
        cond_type, src_mask, re_mask, key_add, val_mul);
    zero_tail<<<dim3((Bc * Dc + 255) / 256), dim3(256), 0, stream>>>(vT16);

    // 3. All weight transposes in one launch
    transpose_all<<<dim3(32, 272), dim3(256), 0, stream>>>(
        Wq, Wkt, Wvt, Wkm, Wvm, Wkr, Wvr, Wo,
        WtQ, WtKT, WtVT, WtKM, WtVM, WtKR, WtVR, WtO);

    // 4. Materialize normalized retrieval operands (once, bf16)
    materialize_ren<<<dim3(Bc * KRc), dim3(256), 0, stream>>>(
        re_motion, re_text, stats1, stats2, rn1_g, rn1_b, rn2_g, rn2_b, ren1, ren2);

    // 5. value_retr FIRST (consumes ren2 = q16 region before mega overwrites it)
    gemm_vr<<<dim3(512), dim3(256), 0, stream>>>(
        (const short*)ren2, WtVR, bvr, val_mul, vT16);

    // 6. MEGA: qkvm + retr-K + text in one 2176-block launch
    gemm_mega<<<dim3(2176), dim3(256), 0, stream>>>(
        (const short*)norm_x16, (const short*)ren1, (const short*)nxf16,
        WtQ, WtKR, WtKT,
        bq, bkm, bvm, bkr, bkt, bvt,
        key_add, val_mul, q16, kT16, vT16);

    // 7. Softmaxes
    softmax_head<<<dim3(Bc * Tc * Hc / 4), dim3(256), 0, stream>>>(q16);
    ksm_rows<<<dim3(Bc * Dc / 4), dim3(256), 0, stream>>>(kT16, cs_m, cs_inv);

    // 8. att = p^T v (MFMA, C^T store), reduce -> bf16 attT[bh][l][d]
    att_gemm<<<dim3(Bc * Hc, ATT_SPLIT), dim3(256), 0, stream>>>(kT16, vT16, cs_m, att_part);
    reduce_att_t<<<dim3((64 * 16384 + 255) / 256), dim3(256), 0, stream>>>(att_part, cs_inv, attT);

    // 9. y = q @ att (MFMA)
    y_gemm<<<dim3(Tc / 128, Bc * Hc), dim3(256), 0, stream>>>(q16, attT, y16);

    // 10. eo = silu(emb) @ We + be
    eo_partial<<<dim3(8, 32), dim3(256), 0, stream>>>(emb, We, eo_part);
    eo_reduce<<<dim3(64), dim3(256), 0, stream>>>(eo_part, be, eo);

    // 11. FiLM + silu
    film_kernel<<<dim3(Bc * Tc), dim3(256), 0, stream>>>(y16, eo, sln_g, sln_b, s16);

    // 12. out = x + s @ Wo + bo  (128^2 + XCD swizzle; overwrites ren1 scratch)
    gemm_bt<float><<<dim3(8, 64), dim3(256), 0, stream>>>(
        (const short*)s16, 1024, WtO, 1024, bo, x, 1024, out, 1024, 1024);
}

// Round 7
// 583.160 us; speedup vs baseline: 1.7962x; 1.0920x over previous
//
#include <hip/hip_runtime.h>
#include <hip/hip_bf16.h>
#include <math.h>

using bf16 = __hip_bfloat16;

typedef short s16x8 __attribute__((ext_vector_type(8)));
typedef short s16x4 __attribute__((ext_vector_type(4)));
typedef float f32x4 __attribute__((ext_vector_type(4)));

// Problem dims (fixed by setup_inputs)
constexpr int Bc = 8, Tc = 1024, Dc = 1024, Hc = 8;
constexpr int NTc = 77, LTc = 768, KRc = 1024, Nc = 2125, Ec = 2048;
constexpr float NEGC = -1000000.0f;

// Transposed K/V layout: [b][feature(1024)][token], row stride NP (16B-aligned)
constexpr int NP = 2128;  // 2125 tokens + 3 pad (zeroed in vT; guarded in kT reads)
constexpr long SKT = (long)Dc * NP;

// ---- Workspace layout ----
constexpr long F_STATS1 = 0;                    // (unused now, kept for layout stability)
constexpr long F_STATS2 = F_STATS1 + 16384;
constexpr long F_KEYADD = F_STATS2 + 16384;     // 17,000
constexpr long F_VALMUL = F_KEYADD + 17000;     // 17,000
constexpr long F_SILU   = F_VALMUL + 17000;     // 16,384 (cs_m[8192] + cs_inv[8192])
constexpr long F_EO     = F_SILU + 16384;       // 16,384
constexpr long F_ATT    = F_EO + 16384;         // 1,048,576 (holds attT bf16 2MB)
constexpr long F_END    = F_ATT + 1048576;
// bf16 region
constexpr long KT_SZ   = (long)Bc * Dc * NP;    // 17,432,576
constexpr long B_NORMX = 0;                     // 8,388,608 (reused: y16 later)
constexpr long B_Q     = B_NORMX + 8388608;     // 8,388,608 (ren2 fallback, q16, s16)
constexpr long B_KT    = B_Q + 8388608;         // kT  [b][d][n]
constexpr long B_VT    = B_KT + KT_SZ;          // vT  [b][l][n] (reused: eo_part fp32 after att)
constexpr long B_NXF   = B_VT + KT_SZ;          // 473,088
// Weights: Q, KM, VM contiguous (fused QKVM B-operand = 3072 rows x 1024)
constexpr long B_WQ    = B_NXF + 473088;
constexpr long B_WKM   = B_WQ + 1048576;
constexpr long B_WVM   = B_WKM + 1048576;
constexpr long B_WKT   = B_WVM + 1048576;       // WtKT + WtVT contiguous (text B-operand)
constexpr long B_WVT   = B_WKT + 786432;
constexpr long B_WKR   = B_WVT + 786432;
constexpr long B_WVR   = B_WKR + 2097152;
constexpr long B_WO    = B_WVR + 1048576;
constexpr long B_END   = B_WO + 1048576;
constexpr long B_REN2  = B_END;                 // optional 16MB ren2 (big-ws path)
constexpr long REN2_SZ = 8388608;
constexpr size_t WS_NEED = (size_t)F_END * 4 + (size_t)B_END * 2;
constexpr size_t WS_BIG  = (size_t)F_END * 4 + (size_t)(B_END + REN2_SZ) * 2;

__device__ __forceinline__ float b2f(bf16 v) { return __bfloat162float(v); }
__device__ __forceinline__ bf16 f2b(float v) { return __float2bfloat16(v); }
__device__ __forceinline__ short f2s(float v) {
    bf16 h = __float2bfloat16(v);
    return *reinterpret_cast<short*>(&h);
}
__device__ __forceinline__ float us2f(unsigned short u) {
    bf16 h = *reinterpret_cast<bf16*>(&u);
    return __bfloat162float(h);
}
__device__ __forceinline__ void storef(float* p, float v) { *p = v; }
__device__ __forceinline__ void storef(bf16* p, float v) { *p = __float2bfloat16(v); }

// async global->LDS, 16B per lane. LDS dest must be wave-uniform base + lane*16.
typedef __attribute__((address_space(1))) const unsigned int gu32;
typedef __attribute__((address_space(3))) unsigned int lu32;
__device__ __forceinline__ void gl_lds16(const void* g, void* l) {
    __builtin_amdgcn_global_load_lds((gu32*)g, (lu32*)l, 16, 0, 0);
}

__device__ __forceinline__ float2 block_sum2(float s, float s2) {
    #pragma unroll
    for (int off = 32; off > 0; off >>= 1) {
        s  += __shfl_down(s, off, 64);
        s2 += __shfl_down(s2, off, 64);
    }
    __shared__ float sh[4], sh2[4];
    int w = threadIdx.x >> 6, lane = threadIdx.x & 63;
    if (lane == 0) { sh[w] = s; sh2[w] = s2; }
    __syncthreads();
    s = sh[0] + sh[1] + sh[2] + sh[3];
    s2 = sh2[0] + sh2[1] + sh2[2] + sh2[3];
    return make_float2(s, s2);
}

// Row LayerNorm: one block (256 thr) per row
template <typename TO>
__global__ __launch_bounds__(256) void ln_rows(const float* __restrict__ in,
                                               const float* __restrict__ g,
                                               const float* __restrict__ b,
                                               TO* __restrict__ out, int C) {
    long row = blockIdx.x;
    const float* x = in + row * (long)C;
    TO* o = out + row * (long)C;
    float s = 0.f, s2 = 0.f;
    for (int c = threadIdx.x; c < C; c += 256) { float v = x[c]; s += v; s2 += v * v; }
    float2 r = block_sum2(s, s2);
    float mean = r.x / C;
    float var = r.y / C - mean * mean;
    float inv = rsqrtf(var + 1e-5f);
    for (int c = threadIdx.x; c < C; c += 256)
        storef(&o[c], (x[c] - mean) * inv * g[c] + b[c]);
}

__device__ __forceinline__ s16x4 pack4(float4 v, float mean, float rstd, float4 g, float4 b) {
    s16x4 o;
    o[0] = f2s((v.x - mean) * rstd * g.x + b.x);
    o[1] = f2s((v.y - mean) * rstd * g.y + b.y);
    o[2] = f2s((v.z - mean) * rstd * g.z + b.z);
    o[3] = f2s((v.w - mean) * rstd * g.w + b.w);
    return o;
}

// Fused: retrieval LN stats (both) + materialize ren1/ren2 bf16 — one pass, no stats RT.
__global__ __launch_bounds__(256) void ln_mat(
    const float* __restrict__ motion, const float* __restrict__ text,
    const float* __restrict__ g1, const float* __restrict__ b1,
    const float* __restrict__ g2, const float* __restrict__ b2,
    bf16* __restrict__ ren1, bf16* __restrict__ ren2) {
    long row = blockIdx.x;  // b*1024 + kr
    int c = threadIdx.x * 4;
    const float* mrow = motion + row * 1024;
    const float* trow = text + (row >> 9) * 1024;
    float4 mv = *(const float4*)(mrow + c);
    float4 tv = *(const float4*)(trow + c);
    float sm = mv.x + mv.y + mv.z + mv.w;
    float sm2 = mv.x * mv.x + mv.y * mv.y + mv.z * mv.z + mv.w * mv.w;
    float2 rm = block_sum2(sm, sm2);
    __syncthreads();
    float st = tv.x + tv.y + tv.z + tv.w;
    float st2 = tv.x * tv.x + tv.y * tv.y + tv.z * tv.z + tv.w * tv.w;
    float2 rt = block_sum2(st, st2);
    float mean2 = rm.x / 1024.f;
    float var2 = rm.y / 1024.f - mean2 * mean2;
    float r2 = rsqrtf(var2 + 1e-5f);
    float mean1 = (rm.x + rt.x) / 2048.f;
    float var1 = (rm.y + rt.y) / 2048.f - mean1 * mean1;
    float r1 = rsqrtf(var1 + 1e-5f);
    float4 g1m = *(const float4*)(g1 + c),        b1m = *(const float4*)(b1 + c);
    float4 g1t = *(const float4*)(g1 + 1024 + c), b1t = *(const float4*)(b1 + 1024 + c);
    float4 g2m = *(const float4*)(g2 + c),        b2m = *(const float4*)(b2 + c);
    *(s16x4*)((short*)ren1 + row * 2048 + c)        = pack4(mv, mean1, r1, g1m, b1m);
    *(s16x4*)((short*)ren1 + row * 2048 + 1024 + c) = pack4(tv, mean1, r1, g1t, b1t);
    *(s16x4*)((short*)ren2 + row * 1024 + c)        = pack4(mv, mean2, r2, g2m, b2m);
}

// Per-(b, n) key/value masks + vT pad zero-fill, one launch (grid 67+32)
__global__ __launch_bounds__(256) void prep_zero(const int* __restrict__ cond_type,
                                                 const float* __restrict__ src_mask,
                                                 const float* __restrict__ re_mask,
                                                 float* __restrict__ key_add,
                                                 float* __restrict__ val_mul,
                                                 bf16* __restrict__ vT) {
    int bid = blockIdx.x;
    if (bid < 67) {
        int idx = bid * 256 + threadIdx.x;
        if (idx >= Bc * Nc) return;
        int b = idx / Nc, n = idx % Nc;
        int ct = cond_type[b];
        float text_ct = ((ct % 10) > 0) ? 1.f : 0.f;
        float retr_ct = ((ct / 10) > 0) ? 1.f : 0.f;
        float add, mul;
        if (n < NTc) {
            add = (1.f - text_ct) * NEGC; mul = text_ct;
        } else if (n < NTc + KRc) {
            float rm = re_mask[b * KRc + (n - NTc)];
            add = (1.f - retr_ct) * NEGC + (1.f - rm) * NEGC;
            mul = retr_ct * rm;
        } else {
            float sm = src_mask[b * Tc + (n - NTc - KRc)];
            add = (1.f - sm) * NEGC; mul = sm;
        }
        key_add[idx] = add;
        val_mul[idx] = mul;
    } else {
        int row = (bid - 67) * 256 + threadIdx.x;
        if (row >= Bc * Dc) return;
        bf16* p = vT + (long)row * NP + Nc;
        p[0] = f2b(0.f); p[1] = f2b(0.f); p[2] = f2b(0.f);
    }
}

// All 8 weight transposes in ONE launch: W[K][1024] fp32 -> Wt[1024][K] bf16
__global__ __launch_bounds__(256) void transpose_all(
    const float* __restrict__ Wq,  const float* __restrict__ Wkt,
    const float* __restrict__ Wvt, const float* __restrict__ Wkm,
    const float* __restrict__ Wvm, const float* __restrict__ Wkr,
    const float* __restrict__ Wvr, const float* __restrict__ Wo,
    short* __restrict__ WtQ,  short* __restrict__ WtKT,
    short* __restrict__ WtVT, short* __restrict__ WtKM,
    short* __restrict__ WtVM, short* __restrict__ WtKR,
    short* __restrict__ WtVR, short* __restrict__ WtO) {
    __shared__ float t[32][33];
    int sy = blockIdx.y;
    const float* W; short* Wt; int K; int ky;
    if (sy < 32)       { W = Wq;  Wt = WtQ;  K = 1024; ky = sy; }
    else if (sy < 56)  { W = Wkt; Wt = WtKT; K = 768;  ky = sy - 32; }
    else if (sy < 80)  { W = Wvt; Wt = WtVT; K = 768;  ky = sy - 56; }
    else if (sy < 112) { W = Wkm; Wt = WtKM; K = 1024; ky = sy - 80; }
    else if (sy < 144) { W = Wvm; Wt = WtVM; K = 1024; ky = sy - 112; }
    else if (sy < 208) { W = Wkr; Wt = WtKR; K = 2048; ky = sy - 144; }
    else if (sy < 240) { W = Wvr; Wt = WtVR; K = 1024; ky = sy - 208; }
    else               { W = Wo;  Wt = WtO;  K = 1024; ky = sy - 240; }
    int n0 = blockIdx.x * 32, k0 = ky * 32;
    int tx = threadIdx.x & 31, ty = threadIdx.x >> 5;
    #pragma unroll
    for (int i = 0; i < 4; ++i)
        t[ty + i * 8][tx] = W[(long)(k0 + ty + i * 8) * 1024 + n0 + tx];
    __syncthreads();
    #pragma unroll
    for (int i = 0; i < 4; ++i)
        Wt[(long)(n0 + ty + i * 8) * K + k0 + tx] = f2s(t[tx][ty + i * 8]);
}

// ======================= 128^2 MFMA GEMM template pieces ====================
// NOTE (R4/R5 post-mortem): 512-thread workgroups pin VGPR_Count=128 on this
// toolchain -> deep accumulators spill to scratch (1 GB/dispatch). Stay 256-thr.
constexpr int LDK = 64;

// ===== MEGA: retrK (512) + qkvm (1536) + text (128) [+ VR (512) big-ws] =====
// jid [0,512): retr-K  (A=ren1, K=2048, TR +key_add)        [XCD-swizzled]
// jid [512,2048): qkvm (A=norm_x, K=1024, 3 sections)       [XCD-swizzled]
// jid [2048,2176): text (A=nxf per b, K=768, M=77, 2 sect)
// jid [2176,2688): VR   (A=ren2, K=1024, TR *val_mul)       [XCD-swizzled]
__global__ __launch_bounds__(256) void gemm_mega(
    const short* __restrict__ norm_x, const short* __restrict__ ren1,
    const short* __restrict__ ren2, const short* __restrict__ nxf,
    const short* __restrict__ WtQKVM, const short* __restrict__ WtKR,
    const short* __restrict__ WtVR, const short* __restrict__ WtTXT,
    const float* __restrict__ bq, const float* __restrict__ bkm,
    const float* __restrict__ bvm, const float* __restrict__ bkr,
    const float* __restrict__ bvr,
    const float* __restrict__ bkt, const float* __restrict__ bvt,
    const float* __restrict__ key_add, const float* __restrict__ val_mul,
    bf16* __restrict__ q16, bf16* __restrict__ kT, bf16* __restrict__ vT) {
    int jid = blockIdx.x;
    int sect, tm, tn, K, M, lda, bb = 0;
    const short* A; const short* Bt;
    if (jid < 512) {
        sect = 0;
        int s = (jid & 7) * 64 + (jid >> 3);    // XCD swizzle (512 % 8 == 0)
        bb = s >> 6; int r = s & 63;
        tm = (r >> 3) * 128; tn = (r & 7) * 128;
        A = ren1 + (long)bb * KRc * 2048; lda = 2048; K = 2048; M = 1024;
        Bt = WtKR;
    } else if (jid < 2048) {
        sect = 1;
        int l = jid - 512;
        int s = (l & 7) * 192 + (l >> 3);       // XCD swizzle (1536 % 8 == 0)
        tn = (s % 24) * 128; tm = (s / 24) * 128;
        A = norm_x; lda = 1024; K = 1024; M = 8192;
        Bt = WtQKVM;
    } else if (jid < 2176) {
        sect = 2;
        int l = jid - 2048;
        bb = l >> 4; tn = (l & 15) * 128; tm = 0;
        A = nxf + (long)bb * NTc * LTc; lda = 768; K = 768; M = 77;
        Bt = WtTXT;
    } else {
        sect = 3;
        int l = jid - 2176;
        int s = (l & 7) * 64 + (l >> 3);        // XCD swizzle (512 % 8 == 0)
        bb = s >> 6; int r = s & 63;
        tm = (r >> 3) * 128; tn = (r & 7) * 128;
        A = ren2 + (long)bb * KRc * 1024; lda = 1024; K = 1024; M = 1024;
        Bt = WtVR;
    }
    const int ldb = lda;  // all B operands have ldb == lda's K-extent
    const bool swap_ops = !(sect == 1 && tn < 1024);

    __shared__ __align__(16) short As[128 * LDK];
    __shared__ __align__(16) short Bs[128 * LDK];

    int tid = threadIdx.x;
    int lane = tid & 63, wid = tid >> 6;
    int wi = wid >> 1, wj = wid & 1;
    int l16 = lane & 15, quad = lane >> 4;

    f32x4 acc[4][4];
    #pragma unroll
    for (int i = 0; i < 4; ++i)
        #pragma unroll
        for (int j = 0; j < 4; ++j)
            acc[i][j] = (f32x4){0.f, 0.f, 0.f, 0.f};

    auto issue = [&](int k0) {
        #pragma unroll
        for (int p = 0; p < 4; ++p) {
            int e = p * 256 + tid;
            int row = e >> 3, c8 = e & 7;
            int gm = tm + row;
            if (gm >= M) gm = M - 1;  // clamp: garbage rows never stored
            gl_lds16(A + (long)gm * lda + k0 + c8 * 8, &As[row * LDK + c8 * 8]);
            gl_lds16(Bt + (long)(tn + row) * ldb + k0 + c8 * 8, &Bs[row * LDK + c8 * 8]);
        }
    };

    issue(0);
    int kt = 0;
    while (true) {
        __syncthreads();
        #pragma unroll
        for (int kk = 0; kk < 2; ++kk) {
            s16x8 af[4], bfr[4];
            #pragma unroll
            for (int i = 0; i < 4; ++i)
                af[i] = *(const s16x8*)&As[(wi * 64 + i * 16 + l16) * LDK + kk * 32 + quad * 8];
            #pragma unroll
            for (int j = 0; j < 4; ++j)
                bfr[j] = *(const s16x8*)&Bs[(wj * 64 + j * 16 + l16) * LDK + kk * 32 + quad * 8];
            if (swap_ops) {
                #pragma unroll
                for (int i = 0; i < 4; ++i)
                    #pragma unroll
                    for (int j = 0; j < 4; ++j)
                        acc[i][j] = __builtin_amdgcn_mfma_f32_16x16x32_bf16(bfr[j], af[i], acc[i][j], 0, 0, 0);
            } else {
                #pragma unroll
                for (int i = 0; i < 4; ++i)
                    #pragma unroll
                    for (int j = 0; j < 4; ++j)
                        acc[i][j] = __builtin_amdgcn_mfma_f32_16x16x32_bf16(af[i], bfr[j], acc[i][j], 0, 0, 0);
            }
        }
        int nxt = kt + 64;
        if (nxt >= K) break;
        __syncthreads();
        issue(nxt);
        kt = nxt;
    }

    if (sect == 1 && tn < 1024) {
        // Q: plain [token][feature] store
        #pragma unroll
        for (int i = 0; i < 4; ++i) {
            #pragma unroll
            for (int r = 0; r < 4; ++r) {
                int gm = tm + wi * 64 + i * 16 + quad * 4 + r;
                #pragma unroll
                for (int j = 0; j < 4; ++j) {
                    int gn = tn + wj * 64 + j * 16 + l16;
                    q16[(long)gm * Dc + gn] = f2b(acc[i][j][r] + bq[gn]);
                }
            }
        }
    } else if (sect == 1) {
        // KM / VM: TR store with per-(b,tok) mask, b = gm>>10
        int sec = tn >> 10, fn0 = tn & 1023;
        const float* bias = (sec == 1) ? bkm : bvm;
        bf16* C = (sec == 1) ? kT : vT;
        #pragma unroll
        for (int j = 0; j < 4; ++j) {
            #pragma unroll
            for (int r = 0; r < 4; ++r) {
                int feat = fn0 + wj * 64 + j * 16 + quad * 4 + r;
                float bf_ = bias[feat];
                #pragma unroll
                for (int i = 0; i < 4; ++i) {
                    int gm = tm + wi * 64 + i * 16 + l16;
                    int b = gm >> 10, tok = gm & 1023;
                    int mi = b * Nc + NTc + KRc + tok;
                    float v = acc[i][j][r] + bf_;
                    if (sec == 1) v += key_add[mi];
                    else          v *= val_mul[mi];
                    C[(long)b * SKT + (long)feat * NP + NTc + KRc + tok] = f2b(v);
                }
            }
        }
    } else if (sect == 0) {
        // retr-K: TR store + key_add
        const float* rmask = key_add + bb * Nc + NTc;
        bf16* C = kT + (long)bb * SKT + NTc;
        #pragma unroll
        for (int j = 0; j < 4; ++j) {
            #pragma unroll
            for (int r = 0; r < 4; ++r) {
                int feat = tn + wj * 64 + j * 16 + quad * 4 + r;
                float bf_ = bkr[feat];
                #pragma unroll
                for (int i = 0; i < 4; ++i) {
                    int tok = tm + wi * 64 + i * 16 + l16;
                    C[(long)feat * NP + tok] = f2b(acc[i][j][r] + bf_ + rmask[tok]);
                }
            }
        }
    } else if (sect == 3) {
        // value-retr: TR store * val_mul
        const float* rmask = val_mul + bb * Nc + NTc;
        bf16* C = vT + (long)bb * SKT + NTc;
        #pragma unroll
        for (int j = 0; j < 4; ++j) {
            #pragma unroll
            for (int r = 0; r < 4; ++r) {
                int feat = tn + wj * 64 + j * 16 + quad * 4 + r;
                float bf_ = bvr[feat];
                #pragma unroll
                for (int i = 0; i < 4; ++i) {
                    int tok = tm + wi * 64 + i * 16 + l16;
                    C[(long)feat * NP + tok] = f2b((acc[i][j][r] + bf_) * rmask[tok]);
                }
            }
        }
    } else {
        // text: sec 0 -> kT (+add), sec 1 -> vT (*mul); tok < 77
        int sec = tn >> 10, fn0 = tn & 1023;
        const float* bias = sec ? bvt : bkt;
        const float* rmask = (sec ? val_mul : key_add) + bb * Nc;
        bf16* C = (sec ? vT : kT) + (long)bb * SKT;
        #pragma unroll
        for (int j = 0; j < 4; ++j) {
            #pragma unroll
            for (int r = 0; r < 4; ++r) {
                int feat = fn0 + wj * 64 + j * 16 + quad * 4 + r;
                float bf_ = bias[feat];
                #pragma unroll
                for (int i = 0; i < 4; ++i) {
                    int tok = wi * 64 + i * 16 + l16;
                    if (tok >= NTc) continue;
                    float v = acc[i][j][r] + bf_;
                    if (sec) v *= rmask[tok];
                    else     v += rmask[tok];
                    C[(long)feat * NP + tok] = f2b(v);
                }
            }
        }
    }
}

// ===== value_retr GEMM (fallback path only: ren2 aliases q16 region) =====
__global__ __launch_bounds__(256) void gemm_vr(
    const short* __restrict__ ren2, const short* __restrict__ WtVR,
    const float* __restrict__ bvr, const float* __restrict__ val_mul,
    bf16* __restrict__ vT) {
    int s = (blockIdx.x & 7) * 64 + (blockIdx.x >> 3);
    int b = s >> 6; int r = s & 63;
    const int tm = (r >> 3) * 128;
    const int tn = (r & 7) * 128;
    const short* A = ren2 + (long)b * KRc * 1024;
    const float* rmask = val_mul + b * Nc + NTc;
    bf16* C = vT + (long)b * SKT + NTc;

    __shared__ __align__(16) short As[128 * LDK];
    __shared__ __align__(16) short Bs[128 * LDK];

    int tid = threadIdx.x;
    int lane = tid & 63, wid = tid >> 6;
    int wi = wid >> 1, wj = wid & 1;
    int l16 = lane & 15, quad = lane >> 4;

    f32x4 acc[4][4];
    #pragma unroll
    for (int i = 0; i < 4; ++i)
        #pragma unroll
        for (int j = 0; j < 4; ++j)
            acc[i][j] = (f32x4){0.f, 0.f, 0.f, 0.f};

    auto issue = [&](int k0) {
        #pragma unroll
        for (int p = 0; p < 4; ++p) {
            int e = p * 256 + tid;
            int row = e >> 3, c8 = e & 7;
            gl_lds16(A + (long)(tm + row) * 1024 + k0 + c8 * 8, &As[row * LDK + c8 * 8]);
            gl_lds16(WtVR + (long)(tn + row) * 1024 + k0 + c8 * 8, &Bs[row * LDK + c8 * 8]);
        }
    };

    issue(0);
    int kt = 0;
    while (true) {
        __syncthreads();
        #pragma unroll
        for (int kk = 0; kk < 2; ++kk) {
            s16x8 af[4], bfr[4];
            #pragma unroll
            for (int i = 0; i < 4; ++i)
                af[i] = *(const s16x8*)&As[(wi * 64 + i * 16 + l16) * LDK + kk * 32 + quad * 8];
            #pragma unroll
            for (int j = 0; j < 4; ++j)
                bfr[j] = *(const s16x8*)&Bs[(wj * 64 + j * 16 + l16) * LDK + kk * 32 + quad * 8];
            #pragma unroll
            for (int i = 0; i < 4; ++i)
                #pragma unroll
                for (int j = 0; j < 4; ++j)
                    acc[i][j] = __builtin_amdgcn_mfma_f32_16x16x32_bf16(bfr[j], af[i], acc[i][j], 0, 0, 0);
        }
        int nxt = kt + 64;
        if (nxt >= 1024) break;
        __syncthreads();
        issue(nxt);
        kt = nxt;
    }

    #pragma unroll
    for (int j = 0; j < 4; ++j) {
        #pragma unroll
        for (int r2 = 0; r2 < 4; ++r2) {
            int feat = tn + wj * 64 + j * 16 + quad * 4 + r2;
            float bf_ = bvr[feat];
            #pragma unroll
            for (int i = 0; i < 4; ++i) {
                int tok = tm + wi * 64 + i * 16 + l16;
                C[(long)feat * NP + tok] = f2b((acc[i][j][r2] + bf_) * rmask[tok]);
            }
        }
    }
}

// ===== out GEMM: 128(M)x64(N) tile, grid 1024 (4 blocks/CU), XCD-swizzled =====
// out = s16 @ WtO^T + bo + x.  Waves 2Mx2N, per-wave 64x32 (acc[4][2]).
__global__ __launch_bounds__(256) void gemm_out(
    const short* __restrict__ A, const short* __restrict__ Bt,
    const float* __restrict__ bias, const float* __restrict__ addC,
    float* __restrict__ C) {
    int s = (blockIdx.x & 7) * 128 + (blockIdx.x >> 3);  // 1024 % 8 == 0
    const int tm = (s >> 4) * 128;
    const int tn = (s & 15) * 64;

    __shared__ __align__(16) short As[128 * LDK];
    __shared__ __align__(16) short Bs[64 * LDK];

    int tid = threadIdx.x;
    int lane = tid & 63, wid = tid >> 6;
    int wi = wid >> 1, wj = wid & 1;
    int l16 = lane & 15, quad = lane >> 4;

    f32x4 acc[4][2];
    #pragma unroll
    for (int i = 0; i < 4; ++i)
        #pragma unroll
        for (int j = 0; j < 2; ++j)
            acc[i][j] = (f32x4){0.f, 0.f, 0.f, 0.f};

    auto issue = [&](int k0) {
        #pragma unroll
        for (int p = 0; p < 4; ++p) {
            int e = p * 256 + tid;
            int row = e >> 3, c8 = e & 7;
            gl_lds16(A + (long)(tm + row) * 1024 + k0 + c8 * 8, &As[row * LDK + c8 * 8]);
        }
        #pragma unroll
        for (int p = 0; p < 2; ++p) {
            int e = p * 256 + tid;
            int row = e >> 3, c8 = e & 7;
            gl_lds16(Bt + (long)(tn + row) * 1024 + k0 + c8 * 8, &Bs[row * LDK + c8 * 8]);
        }
    };

    issue(0);
    int kt = 0;
    while (true) {
        __syncthreads();
        #pragma unroll
        for (int kk = 0; kk < 2; ++kk) {
            s16x8 af[4], bfr[2];
            #pragma unroll
            for (int i = 0; i < 4; ++i)
                af[i] = *(const s16x8*)&As[(wi * 64 + i * 16 + l16) * LDK + kk * 32 + quad * 8];
            #pragma unroll
            for (int j = 0; j < 2; ++j)
                bfr[j] = *(const s16x8*)&Bs[(wj * 32 + j * 16 + l16) * LDK + kk * 32 + quad * 8];
            #pragma unroll
            for (int i = 0; i < 4; ++i)
                #pragma unroll
                for (int j = 0; j < 2; ++j)
                    acc[i][j] = __builtin_amdgcn_mfma_f32_16x16x32_bf16(af[i], bfr[j], acc[i][j], 0, 0, 0);
        }
        int nxt = kt + 64;
        if (nxt >= 1024) break;
        __syncthreads();
        issue(nxt);
        kt = nxt;
    }

    #pragma unroll
    for (int i = 0; i < 4; ++i) {
        #pragma unroll
        for (int r = 0; r < 4; ++r) {
            int gm = tm + wi * 64 + i * 16 + quad * 4 + r;
            #pragma unroll
            for (int j = 0; j < 2; ++j) {
                int gn = tn + wj * 32 + j * 16 + l16;
                C[(long)gm * 1024 + gn] = acc[i][j][r] + bias[gn] + addC[(long)gm * 1024 + gn];
            }
        }
    }
}

// eo split-K
__global__ __launch_bounds__(256) void eo_partial(const float* __restrict__ emb,
                                                  const float* __restrict__ We,
                                                  float* __restrict__ part) {
    int nb = blockIdx.x;
    int ks = blockIdx.y;
    int n = nb * 256 + threadIdx.x;
    int k0 = ks * 64;
    __shared__ float a_s[8][64];
    for (int idx = threadIdx.x; idx < 512; idx += 256) {
        int b = idx >> 6, kk = idx & 63;
        float v = emb[b * 2048 + k0 + kk];
        a_s[b][kk] = v / (1.f + expf(-v));
    }
    __syncthreads();
    float acc[8] = {};
    for (int kk = 0; kk < 64; ++kk) {
        float w = We[(long)(k0 + kk) * 2048 + n];
        #pragma unroll
        for (int b = 0; b < 8; ++b) acc[b] = fmaf(a_s[b][kk], w, acc[b]);
    }
    #pragma unroll
    for (int b = 0; b < 8; ++b) part[((long)ks * 8 + b) * 2048 + n] = acc[b];
}

__global__ __launch_bounds__(256) void eo_reduce(const float* __restrict__ part,
                                                 const float* __restrict__ be,
                                                 float* __restrict__ eo) {
    int idx = blockIdx.x * 256 + threadIdx.x;
    int n = idx & 2047, b = idx >> 11;
    float s = be[n];
    #pragma unroll 8
    for (int ks = 0; ks < 32; ++ks) s += part[((long)ks * 8 + b) * 2048 + n];
    eo[idx] = s;
}

// q softmax over head dim (128): one wave per row, 2 elems/lane.
__global__ __launch_bounds__(256) void softmax_head(bf16* __restrict__ q) {
    long row = (long)blockIdx.x * 4 + (threadIdx.x >> 6);
    int lane = threadIdx.x & 63;
    bf16* p = q + row * 128 + lane * 2;
    float v0 = b2f(p[0]), v1 = b2f(p[1]);
    float mx = fmaxf(v0, v1);
    #pragma unroll
    for (int off = 32; off > 0; off >>= 1) mx = fmaxf(mx, __shfl_xor(mx, off, 64));
    float e0 = expf(v0 - mx), e1 = expf(v1 - mx);
    float s = e0 + e1;
    #pragma unroll
    for (int off = 32; off > 0; off >>= 1) s += __shfl_xor(s, off, 64);
    float inv = 1.f / s;
    p[0] = f2b(e0 * inv);
    p[1] = f2b(e1 * inv);
}

// key softmax column stats over tokens — ROW reduction on kT[b][d][n].
__global__ __launch_bounds__(256) void ksm_rows(const bf16* __restrict__ kT,
                                                float* __restrict__ cs_m,
                                                float* __restrict__ cs_inv) {
    int row = blockIdx.x * 4 + (threadIdx.x >> 6);  // b*1024 + feature
    int lane = threadIdx.x & 63;
    const s16x8* p8 = (const s16x8*)(kT + (long)row * NP);
    float m = -3.0e38f;
    for (int c = lane; c < NP / 8; c += 64) {
        s16x8 raw = p8[c];
        int n0 = c * 8;
        #pragma unroll
        for (int j = 0; j < 8; ++j)
            if (n0 + j < Nc) m = fmaxf(m, us2f((unsigned short)raw[j]));
    }
    #pragma unroll
    for (int off = 32; off > 0; off >>= 1) m = fmaxf(m, __shfl_xor(m, off, 64));
    float s = 0.f;
    for (int c = lane; c < NP / 8; c += 64) {
        s16x8 raw = p8[c];
        int n0 = c * 8;
        #pragma unroll
        for (int j = 0; j < 8; ++j)
            if (n0 + j < Nc) s += __expf(us2f((unsigned short)raw[j]) - m);
    }
    #pragma unroll
    for (int off = 32; off > 0; off >>= 1) s += __shfl_xor(s, off, 64);
    if (lane == 0) { cs_m[row] = m; cs_inv[row] = 1.f / s; }
}

// att_part[split][bh][l][d] = sum_{n in split} exp(kT[bd][n]-m_d) * vT[bl][n]  (C^T store)
// ATT_SPLIT=8 -> 512 blocks (2/CU); att_part lives in d_out (32MB, ren1 dead).
constexpr int ATT_SPLIT = 8;
__global__ __launch_bounds__(256) void att_gemm(const bf16* __restrict__ kTb,
                                                const bf16* __restrict__ vTb,
                                                const float* __restrict__ cs_m,
                                                float* __restrict__ att_part) {
    int bh = blockIdx.x;
    int split = blockIdx.y;
    int b = bh >> 3, h = bh & 7;
    const short* A  = (const short*)kTb + ((long)b * 1024 + h * 128) * NP;
    const short* Bt = (const short*)vTb + ((long)b * 1024 + h * 128) * NP;
    float* ap = att_part + ((long)split * 64 + bh) * 16384;

    __shared__ __align__(16) short As[128 * LDK];
    __shared__ __align__(16) short Bs[128 * LDK];
    __shared__ float ms[128];

    int tid = threadIdx.x;
    if (tid < 128) ms[tid] = cs_m[(long)b * 1024 + h * 128 + tid];

    int lane = tid & 63, wid = tid >> 6;
    int wi = wid >> 1, wj = wid & 1;
    int l16 = lane & 15, quad = lane >> 4;

    f32x4 acc[4][4];
    #pragma unroll
    for (int i = 0; i < 4; ++i)
        #pragma unroll
        for (int j = 0; j < 4; ++j)
            acc[i][j] = (f32x4){0.f, 0.f, 0.f, 0.f};

    uint4 pa[4];
    auto computeA = [&](int k0) {
        #pragma unroll
        for (int p = 0; p < 4; ++p) {
            int e = p * 256 + tid;
            int row = e >> 3, c8 = e & 7;
            int n0 = k0 + c8 * 8;
            union { short s[8]; uint4 u; } pk;
            if (n0 >= Nc) {
                pk.u = (uint4){0u, 0u, 0u, 0u};
            } else {
                float m = ms[row];
                s16x8 raw = *(const s16x8*)(A + (long)row * NP + n0);
                #pragma unroll
                for (int j = 0; j < 8; ++j) {
                    float v = (n0 + j < Nc) ? __expf(us2f((unsigned short)raw[j]) - m) : 0.f;
                    pk.s[j] = f2s(v);
                }
            }
            pa[p] = pk.u;
        }
    };
    auto issueB = [&](int k0) {
        #pragma unroll
        for (int p = 0; p < 4; ++p) {
            int e = p * 256 + tid;
            int row = e >> 3, c8 = e & 7;
            int n0 = k0 + c8 * 8;
            if (n0 > NP - 8) n0 = NP - 8;  // clamp: A is zero there, values just must be finite
            gl_lds16(Bt + (long)row * NP + n0, &Bs[row * LDK + c8 * 8]);
        }
    };
    auto storeA = [&]() {
        #pragma unroll
        for (int p = 0; p < 4; ++p) {
            int e = p * 256 + tid;
            int row = e >> 3, c8 = e & 7;
            *(uint4*)&As[row * LDK + c8 * 8] = pa[p];
        }
    };

    // 34 K-steps total, splits {5,5,4,4,4,4,4,4}
    int st = (split < 2) ? split * 5 : 10 + (split - 2) * 4;
    int cnt = (split < 2) ? 5 : 4;
    int kt = st * 64;
    int kend = kt + cnt * 64;

    __syncthreads();  // ms ready
    issueB(kt);
    computeA(kt);
    storeA();
    while (true) {
        __syncthreads();
        #pragma unroll
        for (int kk = 0; kk < 2; ++kk) {
            s16x8 af[4], bfr[4];
            #pragma unroll
            for (int i = 0; i < 4; ++i)
                af[i] = *(const s16x8*)&As[(wi * 64 + i * 16 + l16) * LDK + kk * 32 + quad * 8];
            #pragma unroll
            for (int j = 0; j < 4; ++j)
                bfr[j] = *(const s16x8*)&Bs[(wj * 64 + j * 16 + l16) * LDK + kk * 32 + quad * 8];
            #pragma unroll
            for (int i = 0; i < 4; ++i)
                #pragma unroll
                for (int j = 0; j < 4; ++j)
                    acc[i][j] = __builtin_amdgcn_mfma_f32_16x16x32_bf16(bfr[j], af[i], acc[i][j], 0, 0, 0);
        }
        int nxt = kt + 64;
        if (nxt >= kend) break;
        computeA(nxt);
        __syncthreads();
        issueB(nxt);
        storeA();
        kt = nxt;
    }

    // C^T: acc rows = value-feature l (tile j), cols = key-feature d (tile i)
    #pragma unroll
    for (int j = 0; j < 4; ++j) {
        #pragma unroll
        for (int r = 0; r < 4; ++r) {
            int l = wj * 64 + j * 16 + quad * 4 + r;
            #pragma unroll
            for (int i = 0; i < 4; ++i) {
                int d = wi * 64 + i * 16 + l16;
                ap[l * 128 + d] = acc[i][j][r];
            }
        }
    }
}

// reduce splits + apply per-d 1/sum -> bf16 attT[bh][l][d] (ready B^T operand for y)
__global__ __launch_bounds__(256) void reduce_att_t(const float* __restrict__ att_part,
                                                    const float* __restrict__ cs_inv,
                                                    bf16* __restrict__ attT) {
    long idx = (long)blockIdx.x * 256 + threadIdx.x;
    if (idx >= (long)64 * 16384) return;
    float s = 0.f;
    #pragma unroll
    for (int sp = 0; sp < ATT_SPLIT; ++sp) s += att_part[(long)sp * 64 * 16384 + idx];
    int bh = (int)(idx >> 14);
    int d = (int)(idx & 127);
    int b = bh >> 3, h = bh & 7;
    attT[idx] = f2b(s * cs_inv[b * Dc + h * 128 + d]);
}

// y[b,t,h*128+l] = sum_d q[b,t,h*128+d] * att[bh][d][l] — MFMA, K=128 single stage.
__global__ __launch_bounds__(256) void y_gemm(const bf16* __restrict__ q,
                                              const bf16* __restrict__ attT,
                                              bf16* __restrict__ y) {
    int bh = blockIdx.y;
    int b = bh >> 3, h = bh & 7;
    const short* A  = (const short*)q + (long)b * Tc * Dc + h * 128;   // row stride Dc
    const short* Bt = (const short*)attT + (long)bh * 16384;           // [l][d] stride 128
    bf16* yb = y + (long)b * Tc * Dc + h * 128;
    int tm = blockIdx.x * 128;

    __shared__ __align__(16) short As[128 * 128];
    __shared__ __align__(16) short Bs[128 * 128];
    int tid = threadIdx.x;
    #pragma unroll
    for (int p = 0; p < 8; ++p) {
        int e = p * 256 + tid;
        int row = e >> 4, c8 = e & 15;
        gl_lds16(A + (long)(tm + row) * Dc + c8 * 8, &As[row * 128 + c8 * 8]);
        gl_lds16(Bt + row * 128 + c8 * 8, &Bs[row * 128 + c8 * 8]);
    }
    int lane = tid & 63, wid = tid >> 6;
    int wi = wid >> 1, wj = wid & 1;
    int l16 = lane & 15, quad = lane >> 4;
    f32x4 acc[4][4];
    #pragma unroll
    for (int i = 0; i < 4; ++i)
        #pragma unroll
        for (int j = 0; j < 4; ++j)
            acc[i][j] = (f32x4){0.f, 0.f, 0.f, 0.f};
    __syncthreads();
    #pragma unroll
    for (int kk = 0; kk < 4; ++kk) {
        s16x8 af[4], bfr[4];
        #pragma unroll
        for (int i = 0; i < 4; ++i)
            af[i] = *(const s16x8*)&As[(wi * 64 + i * 16 + l16) * 128 + kk * 32 + quad * 8];
        #pragma unroll
        for (int j = 0; j < 4; ++j)
            bfr[j] = *(const s16x8*)&Bs[(wj * 64 + j * 16 + l16) * 128 + kk * 32 + quad * 8];
        #pragma unroll
        for (int i = 0; i < 4; ++i)
            #pragma unroll
            for (int j = 0; j < 4; ++j)
                acc[i][j] = __builtin_amdgcn_mfma_f32_16x16x32_bf16(af[i], bfr[j], acc[i][j], 0, 0, 0);
    }
    #pragma unroll
    for (int i = 0; i < 4; ++i) {
        #pragma unroll
        for (int r = 0; r < 4; ++r) {
            int gm = tm + wi * 64 + i * 16 + quad * 4 + r;
            #pragma unroll
            for (int j = 0; j < 4; ++j) {
                int gn = wj * 64 + j * 16 + l16;
                yb[(long)gm * Dc + gn] = f2b(acc[i][j][r]);
            }
        }
    }
}

// s = silu( LN(y)*(1+scale) + shift )
__global__ __launch_bounds__(256) void film_kernel(const bf16* __restrict__ y,
                                                   const float* __restrict__ eo,
                                                   const float* __restrict__ g,
                                                   const float* __restrict__ bta,
                                                   bf16* __restrict__ s) {
    long row = blockIdx.x;
    int b = (int)(row >> 10);
    const bf16* yr = y + row * Dc;
    float sum = 0.f, sum2 = 0.f;
    for (int c = threadIdx.x; c < Dc; c += 256) { float v = b2f(yr[c]); sum += v; sum2 += v * v; }
    float2 r = block_sum2(sum, sum2);
    float mean = r.x / Dc;
    float var = r.y / Dc - mean * mean;
    float inv = rsqrtf(var + 1e-5f);
    const float* sc = eo + (long)b * 2048;
    const float* sf = sc + 1024;
    bf16* so = s + row * Dc;
    for (int c = threadIdx.x; c < Dc; c += 256) {
        float v = (b2f(yr[c]) - mean) * inv * g[c] + bta[c];
        v = v * (1.f + sc[c]) + sf[c];
        so[c] = f2b(v / (1.f + expf(-v)));
    }
}

extern "C" void kernel_launch(void* const* d_in, const int* in_sizes, int n_in,
                              void* d_out, int out_size, void* d_ws, size_t ws_size,
                              hipStream_t stream) {
    if (ws_size < WS_NEED) return;
    const bool big = ws_size >= WS_BIG;

    const float* x         = (const float*)d_in[0];
    const float* xf        = (const float*)d_in[1];
    const float* emb       = (const float*)d_in[2];
    const float* src_mask  = (const float*)d_in[3];
    const int*   cond_type = (const int*)d_in[4];
    const float* re_motion = (const float*)d_in[5];
    const float* re_text   = (const float*)d_in[6];
    const float* re_mask   = (const float*)d_in[7];
    const float* ln_g  = (const float*)d_in[8];
    const float* ln_b  = (const float*)d_in[9];
    const float* tln_g = (const float*)d_in[10];
    const float* tln_b = (const float*)d_in[11];
    const float* rn1_g = (const float*)d_in[12];
    const float* rn1_b = (const float*)d_in[13];
    const float* rn2_g = (const float*)d_in[14];
    const float* rn2_b = (const float*)d_in[15];
    const float* Wq  = (const float*)d_in[16];
    const float* bq  = (const float*)d_in[17];
    const float* Wkt = (const float*)d_in[18];
    const float* bkt = (const float*)d_in[19];
    const float* Wvt = (const float*)d_in[20];
    const float* bvt = (const float*)d_in[21];
    const float* Wkm = (const float*)d_in[22];
    const float* bkm = (const float*)d_in[23];
    const float* Wvm = (const float*)d_in[24];
    const float* bvm = (const float*)d_in[25];
    const float* Wkr = (const float*)d_in[26];
    const float* bkr = (const float*)d_in[27];
    const float* Wvr = (const float*)d_in[28];
    const float* bvr = (const float*)d_in[29];
    const float* We  = (const float*)d_in[30];
    const float* be  = (const float*)d_in[31];
    const float* sln_g = (const float*)d_in[32];
    const float* sln_b = (const float*)d_in[33];
    const float* Wo  = (const float*)d_in[34];
    const float* bo  = (const float*)d_in[35];

    float* ws = (float*)d_ws;
    float* key_add  = ws + F_KEYADD;
    float* val_mul  = ws + F_VALMUL;
    float* cs_m     = ws + F_SILU;         // 8192
    float* cs_inv   = cs_m + Bc * Dc;      // 8192
    float* eo       = ws + F_EO;
    bf16*  attT     = (bf16*)(ws + F_ATT); // 2MB bf16 in 4MB slot
    bf16* wb = (bf16*)(ws + F_END);
    bf16* norm_x16 = wb + B_NORMX;
    bf16* q16      = wb + B_Q;
    bf16* kT16     = wb + B_KT;
    bf16* vT16     = wb + B_VT;
    bf16* nxf16    = wb + B_NXF;
    short* WtQ  = (short*)(wb + B_WQ);     // WtQ/WtKM/WtVM contiguous = QKVM B-operand
    short* WtKM = (short*)(wb + B_WKM);
    short* WtVM = (short*)(wb + B_WVM);
    short* WtKT = (short*)(wb + B_WKT);    // WtKT/WtVT contiguous = text B-operand
    short* WtVT = (short*)(wb + B_WVT);
    short* WtKR = (short*)(wb + B_WKR);
    short* WtVR = (short*)(wb + B_WVR);
    short* WtO  = (short*)(wb + B_WO);
    bf16* y16 = wb + B_NORMX;                  // norm_x16 dead after mega
    bf16* s16 = q16;                           // q dead after y_gemm
    float* eo_part = (float*)(wb + B_VT);      // overlays vT16 (dead after att_gemm)
    bf16* ren1 = (bf16*)d_out;                 // 32MB scratch, dead after mega
    float* att_part = (float*)d_out;           // 32MB, overlays ren1 (dead by att time)
    bf16* ren2 = big ? (wb + B_REN2) : q16;    // big: own region (VR folds into mega)

    float* out = (float*)d_out;

    // 1. LayerNorms + fused retrieval-LN materialize
    ln_rows<bf16><<<dim3(Bc * Tc), dim3(256), 0, stream>>>(x, ln_g, ln_b, norm_x16, Dc);
    ln_rows<bf16><<<dim3(Bc * NTc), dim3(256), 0, stream>>>(xf, tln_g, tln_b, nxf16, LTc);
    ln_mat<<<dim3(Bc * KRc), dim3(256), 0, stream>>>(
        re_motion, re_text, rn1_g, rn1_b, rn2_g, rn2_b, ren1, ren2);

    // 2. Masks + vT pad zero-fill (one launch)
    prep_zero<<<dim3(99), dim3(256), 0, stream>>>(
        cond_type, src_mask, re_mask, key_add, val_mul, vT16);

    // 3. All weight transposes in one launch
    transpose_all<<<dim3(32, 272), dim3(256), 0, stream>>>(
        Wq, Wkt, Wvt, Wkm, Wvm, Wkr, Wvr, Wo,
        WtQ, WtKT, WtVT, WtKM, WtVM, WtKR, WtVR, WtO);

    // 4. value_retr separately only when ren2 aliases q16 (fallback ws)
    if (!big)
        gemm_vr<<<dim3(512), dim3(256), 0, stream>>>(
            (const short*)ren2, WtVR, bvr, val_mul, vT16);

    // 5. MEGA: retrK + qkvm + text (+ VR when big) in one launch
    gemm_mega<<<dim3(big ? 2688 : 2176), dim3(256), 0, stream>>>(
        (const short*)norm_x16, (const short*)ren1, (const short*)ren2,
        (const short*)nxf16, WtQ, WtKR, WtVR, WtKT,
        bq, bkm, bvm, bkr, bvr, bkt, bvt,
        key_add, val_mul, q16, kT16, vT16);

    // 6. Softmaxes
    softmax_head<<<dim3(Bc * Tc * Hc / 4), dim3(256), 0, stream>>>(q16);
    ksm_rows<<<dim3(Bc * Dc / 4), dim3(256), 0, stream>>>(kT16, cs_m, cs_inv);

    // 7. att = p^T v (MFMA, C^T store, 8-way split in d_out), reduce -> bf16 attT
    att_gemm<<<dim3(Bc * Hc, ATT_SPLIT), dim3(256), 0, stream>>>(kT16, vT16, cs_m, att_part);
    reduce_att_t<<<dim3((64 * 16384 + 255) / 256), dim3(256), 0, stream>>>(att_part, cs_inv, attT);

    // 8. y = q @ att (MFMA)
    y_gemm<<<dim3(Tc / 128, Bc * Hc), dim3(256), 0, stream>>>(q16, attT, y16);

    // 9. eo = silu(emb) @ We + be
    eo_partial<<<dim3(8, 32), dim3(256), 0, stream>>>(emb, We, eo_part);
    eo_reduce<<<dim3(64), dim3(256), 0, stream>>>(eo_part, be, eo);

    // 10. FiLM + silu
    film_kernel<<<dim3(Bc * Tc), dim3(256), 0, stream>>>(y16, eo, sln_g, sln_b, s16);

    // 11. out = x + s @ Wo + bo  (128x64 tiles, 1024 blocks, XCD-swizzled)
    gemm_out<<<dim3(1024), dim3(256), 0, stream>>>(
        (const short*)s16, WtO, bo, x, out);
}

// Round 8
// 570.600 us; speedup vs baseline: 1.8357x; 1.0220x over previous
//
#include <hip/hip_runtime.h>
#include <hip/hip_bf16.h>
#include <math.h>

using bf16 = __hip_bfloat16;

typedef short s16x8 __attribute__((ext_vector_type(8)));
typedef short s16x4 __attribute__((ext_vector_type(4)));
typedef float f32x4 __attribute__((ext_vector_type(4)));

// Problem dims (fixed by setup_inputs)
constexpr int Bc = 8, Tc = 1024, Dc = 1024, Hc = 8;
constexpr int NTc = 77, LTc = 768, KRc = 1024, Nc = 2125, Ec = 2048;
constexpr float NEGC = -1000000.0f;

// Transposed K/V layout: [b][feature(1024)][token], row stride NP (16B-aligned)
constexpr int NP = 2128;  // 2125 tokens + 3 pad (zeroed in vT; guarded in kT reads)
constexpr long SKT = (long)Dc * NP;

// ---- Workspace layout ----
constexpr long F_STATS1 = 0;                    // (unused, layout stability)
constexpr long F_STATS2 = F_STATS1 + 16384;
constexpr long F_KEYADD = F_STATS2 + 16384;     // 17,000
constexpr long F_VALMUL = F_KEYADD + 17000;     // 17,000
constexpr long F_SILU   = F_VALMUL + 17000;     // 16,384 (cs_m[8192] + cs_inv[8192])
constexpr long F_EO     = F_SILU + 16384;       // 16,384
constexpr long F_ATT    = F_EO + 16384;         // 1,048,576 floats: attT bf16 (2MB) + eo_part fp32 (2MB)
constexpr long F_END    = F_ATT + 1048576;
// bf16 region
constexpr long KT_SZ   = (long)Bc * Dc * NP;    // 17,432,576
constexpr long B_NORMX = 0;                     // 8,388,608 (reused: y16 later)
constexpr long B_Q     = B_NORMX + 8388608;     // 8,388,608 (ren2 fallback, q16, s16)
constexpr long B_KT    = B_Q + 8388608;         // kT  [b][d][n]
constexpr long B_VT    = B_KT + KT_SZ;          // vT  [b][l][n]
constexpr long B_NXF   = B_VT + KT_SZ;          // 473,088
// Weights: Q, KM, VM contiguous (fused QKVM B-operand = 3072 rows x 1024)
constexpr long B_WQ    = B_NXF + 473088;
constexpr long B_WKM   = B_WQ + 1048576;
constexpr long B_WVM   = B_WKM + 1048576;
constexpr long B_WKT   = B_WVM + 1048576;       // WtKT + WtVT contiguous (text B-operand)
constexpr long B_WVT   = B_WKT + 786432;
constexpr long B_WKR   = B_WVT + 786432;
constexpr long B_WVR   = B_WKR + 2097152;
constexpr long B_WO    = B_WVR + 1048576;
constexpr long B_END   = B_WO + 1048576;
constexpr long B_REN2  = B_END;                 // optional 16MB ren2 (big-ws path)
constexpr long REN2_SZ = 8388608;
constexpr size_t WS_NEED = (size_t)F_END * 4 + (size_t)B_END * 2;
constexpr size_t WS_BIG  = (size_t)F_END * 4 + (size_t)(B_END + REN2_SZ) * 2;

__device__ __forceinline__ float b2f(bf16 v) { return __bfloat162float(v); }
__device__ __forceinline__ bf16 f2b(float v) { return __float2bfloat16(v); }
__device__ __forceinline__ short f2s(float v) {
    bf16 h = __float2bfloat16(v);
    return *reinterpret_cast<short*>(&h);
}
__device__ __forceinline__ float us2f(unsigned short u) {
    bf16 h = *reinterpret_cast<bf16*>(&u);
    return __bfloat162float(h);
}
__device__ __forceinline__ void storef(float* p, float v) { *p = v; }
__device__ __forceinline__ void storef(bf16* p, float v) { *p = __float2bfloat16(v); }

// async global->LDS, 16B per lane. LDS dest must be wave-uniform base + lane*16.
typedef __attribute__((address_space(1))) const unsigned int gu32;
typedef __attribute__((address_space(3))) unsigned int lu32;
__device__ __forceinline__ void gl_lds16(const void* g, void* l) {
    __builtin_amdgcn_global_load_lds((gu32*)g, (lu32*)l, 16, 0, 0);
}

__device__ __forceinline__ float2 block_sum2(float s, float s2) {
    #pragma unroll
    for (int off = 32; off > 0; off >>= 1) {
        s  += __shfl_down(s, off, 64);
        s2 += __shfl_down(s2, off, 64);
    }
    __shared__ float sh[4], sh2[4];
    int w = threadIdx.x >> 6, lane = threadIdx.x & 63;
    if (lane == 0) { sh[w] = s; sh2[w] = s2; }
    __syncthreads();
    s = sh[0] + sh[1] + sh[2] + sh[3];
    s2 = sh2[0] + sh2[1] + sh2[2] + sh2[3];
    return make_float2(s, s2);
}

__device__ __forceinline__ void ln_row_dev(const float* __restrict__ x,
                                           const float* __restrict__ g,
                                           const float* __restrict__ b,
                                           bf16* __restrict__ o, int C) {
    float s = 0.f, s2 = 0.f;
    for (int c = threadIdx.x; c < C; c += 256) { float v = x[c]; s += v; s2 += v * v; }
    float2 r = block_sum2(s, s2);
    float mean = r.x / C;
    float var = r.y / C - mean * mean;
    float inv = rsqrtf(var + 1e-5f);
    for (int c = threadIdx.x; c < C; c += 256)
        o[c] = f2b((x[c] - mean) * inv * g[c] + b[c]);
}

__device__ __forceinline__ s16x4 pack4(float4 v, float mean, float rstd, float4 g, float4 b) {
    s16x4 o;
    o[0] = f2s((v.x - mean) * rstd * g.x + b.x);
    o[1] = f2s((v.y - mean) * rstd * g.y + b.y);
    o[2] = f2s((v.z - mean) * rstd * g.z + b.z);
    o[3] = f2s((v.w - mean) * rstd * g.w + b.w);
    return o;
}

// ===== FUSED PRE: ln(x) [8192] + ln(xf) [616] + ln_mat [8192] + prep/zero [99] =====
__global__ __launch_bounds__(256) void fused_pre(
    const float* __restrict__ x, const float* __restrict__ ln_g,
    const float* __restrict__ ln_b, bf16* __restrict__ norm_x,
    const float* __restrict__ xf, const float* __restrict__ tln_g,
    const float* __restrict__ tln_b, bf16* __restrict__ nxf,
    const float* __restrict__ motion, const float* __restrict__ text,
    const float* __restrict__ g1, const float* __restrict__ b1,
    const float* __restrict__ g2, const float* __restrict__ b2,
    bf16* __restrict__ ren1, bf16* __restrict__ ren2,
    const int* __restrict__ cond_type, const float* __restrict__ src_mask,
    const float* __restrict__ re_mask,
    float* __restrict__ key_add, float* __restrict__ val_mul,
    bf16* __restrict__ vT) {
    int bid = blockIdx.x;
    if (bid < 8192) {
        long row = bid;
        ln_row_dev(x + row * 1024, ln_g, ln_b, norm_x + row * 1024, 1024);
    } else if (bid < 8808) {
        long row = bid - 8192;
        ln_row_dev(xf + row * 768, tln_g, tln_b, nxf + row * 768, 768);
    } else if (bid < 17000) {
        long row = bid - 8808;  // b*1024 + kr
        int c = threadIdx.x * 4;
        const float* mrow = motion + row * 1024;
        const float* trow = text + (row >> 9) * 1024;
        float4 mv = *(const float4*)(mrow + c);
        float4 tv = *(const float4*)(trow + c);
        float sm = mv.x + mv.y + mv.z + mv.w;
        float sm2 = mv.x * mv.x + mv.y * mv.y + mv.z * mv.z + mv.w * mv.w;
        float2 rm = block_sum2(sm, sm2);
        __syncthreads();
        float st = tv.x + tv.y + tv.z + tv.w;
        float st2 = tv.x * tv.x + tv.y * tv.y + tv.z * tv.z + tv.w * tv.w;
        float2 rt = block_sum2(st, st2);
        float mean2 = rm.x / 1024.f;
        float var2 = rm.y / 1024.f - mean2 * mean2;
        float r2 = rsqrtf(var2 + 1e-5f);
        float mean1 = (rm.x + rt.x) / 2048.f;
        float var1 = (rm.y + rt.y) / 2048.f - mean1 * mean1;
        float r1 = rsqrtf(var1 + 1e-5f);
        float4 g1m = *(const float4*)(g1 + c),        b1m = *(const float4*)(b1 + c);
        float4 g1t = *(const float4*)(g1 + 1024 + c), b1t = *(const float4*)(b1 + 1024 + c);
        float4 g2m = *(const float4*)(g2 + c),        b2m = *(const float4*)(b2 + c);
        *(s16x4*)((short*)ren1 + row * 2048 + c)        = pack4(mv, mean1, r1, g1m, b1m);
        *(s16x4*)((short*)ren1 + row * 2048 + 1024 + c) = pack4(tv, mean1, r1, g1t, b1t);
        *(s16x4*)((short*)ren2 + row * 1024 + c)        = pack4(mv, mean2, r2, g2m, b2m);
    } else {
        int b2i = bid - 17000;  // 0..98
        if (b2i < 67) {
            int idx = b2i * 256 + threadIdx.x;
            if (idx >= Bc * Nc) return;
            int b = idx / Nc, n = idx % Nc;
            int ct = cond_type[b];
            float text_ct = ((ct % 10) > 0) ? 1.f : 0.f;
            float retr_ct = ((ct / 10) > 0) ? 1.f : 0.f;
            float add, mul;
            if (n < NTc) {
                add = (1.f - text_ct) * NEGC; mul = text_ct;
            } else if (n < NTc + KRc) {
                float rm = re_mask[b * KRc + (n - NTc)];
                add = (1.f - retr_ct) * NEGC + (1.f - rm) * NEGC;
                mul = retr_ct * rm;
            } else {
                float sm = src_mask[b * Tc + (n - NTc - KRc)];
                add = (1.f - sm) * NEGC; mul = sm;
            }
            key_add[idx] = add;
            val_mul[idx] = mul;
        } else {
            int row = (b2i - 67) * 256 + threadIdx.x;
            if (row >= Bc * Dc) return;
            bf16* p = vT + (long)row * NP + Nc;
            p[0] = f2b(0.f); p[1] = f2b(0.f); p[2] = f2b(0.f);
        }
    }
}

// ===== FUSED W: weight transposes [8704] + eo_partial [256] =====
__global__ __launch_bounds__(256) void fused_w(
    const float* __restrict__ Wq,  const float* __restrict__ Wkt,
    const float* __restrict__ Wvt, const float* __restrict__ Wkm,
    const float* __restrict__ Wvm, const float* __restrict__ Wkr,
    const float* __restrict__ Wvr, const float* __restrict__ Wo,
    short* __restrict__ WtQ,  short* __restrict__ WtKT,
    short* __restrict__ WtVT, short* __restrict__ WtKM,
    short* __restrict__ WtVM, short* __restrict__ WtKR,
    short* __restrict__ WtVR, short* __restrict__ WtO,
    const float* __restrict__ emb, const float* __restrict__ We,
    float* __restrict__ part) {
    __shared__ float t[32][33];
    int bid = blockIdx.x;
    if (bid < 8704) {
        int sy = bid >> 5;
        int n0 = (bid & 31) * 32;
        const float* W; short* Wt; int K; int ky;
        if (sy < 32)       { W = Wq;  Wt = WtQ;  K = 1024; ky = sy; }
        else if (sy < 56)  { W = Wkt; Wt = WtKT; K = 768;  ky = sy - 32; }
        else if (sy < 80)  { W = Wvt; Wt = WtVT; K = 768;  ky = sy - 56; }
        else if (sy < 112) { W = Wkm; Wt = WtKM; K = 1024; ky = sy - 80; }
        else if (sy < 144) { W = Wvm; Wt = WtVM; K = 1024; ky = sy - 112; }
        else if (sy < 208) { W = Wkr; Wt = WtKR; K = 2048; ky = sy - 144; }
        else if (sy < 240) { W = Wvr; Wt = WtVR; K = 1024; ky = sy - 208; }
        else               { W = Wo;  Wt = WtO;  K = 1024; ky = sy - 240; }
        int k0 = ky * 32;
        int tx = threadIdx.x & 31, ty = threadIdx.x >> 5;
        #pragma unroll
        for (int i = 0; i < 4; ++i)
            t[ty + i * 8][tx] = W[(long)(k0 + ty + i * 8) * 1024 + n0 + tx];
        __syncthreads();
        #pragma unroll
        for (int i = 0; i < 4; ++i)
            Wt[(long)(n0 + ty + i * 8) * K + k0 + tx] = f2s(t[tx][ty + i * 8]);
    } else {
        int l = bid - 8704;
        int nb = l & 7, ks = l >> 3;
        int n = nb * 256 + threadIdx.x;
        int k0 = ks * 64;
        __shared__ float a_s[8][64];
        for (int idx = threadIdx.x; idx < 512; idx += 256) {
            int b = idx >> 6, kk = idx & 63;
            float v = emb[b * 2048 + k0 + kk];
            a_s[b][kk] = v / (1.f + expf(-v));
        }
        __syncthreads();
        float acc[8] = {};
        for (int kk = 0; kk < 64; ++kk) {
            float w = We[(long)(k0 + kk) * 2048 + n];
            #pragma unroll
            for (int b = 0; b < 8; ++b) acc[b] = fmaf(a_s[b][kk], w, acc[b]);
        }
        #pragma unroll
        for (int b = 0; b < 8; ++b) part[((long)ks * 8 + b) * 2048 + n] = acc[b];
    }
}

// ======================= 128^2 MFMA GEMM template pieces ====================
// NOTE (R4/R5 post-mortem): 512-thread workgroups pin VGPR_Count=128 on this
// toolchain -> deep accumulators spill to scratch (1 GB/dispatch). Stay 256-thr.
constexpr int LDK = 64;

// ===== MEGA: retrK (512) + qkvm (1536) + text (128) [+ VR (512) big-ws] =====
__global__ __launch_bounds__(256) void gemm_mega(
    const short* __restrict__ norm_x, const short* __restrict__ ren1,
    const short* __restrict__ ren2, const short* __restrict__ nxf,
    const short* __restrict__ WtQKVM, const short* __restrict__ WtKR,
    const short* __restrict__ WtVR, const short* __restrict__ WtTXT,
    const float* __restrict__ bq, const float* __restrict__ bkm,
    const float* __restrict__ bvm, const float* __restrict__ bkr,
    const float* __restrict__ bvr,
    const float* __restrict__ bkt, const float* __restrict__ bvt,
    const float* __restrict__ key_add, const float* __restrict__ val_mul,
    bf16* __restrict__ q16, bf16* __restrict__ kT, bf16* __restrict__ vT) {
    int jid = blockIdx.x;
    int sect, tm, tn, K, M, lda, bb = 0;
    const short* A; const short* Bt;
    if (jid < 512) {
        sect = 0;
        int s = (jid & 7) * 64 + (jid >> 3);    // XCD swizzle (512 % 8 == 0)
        bb = s >> 6; int r = s & 63;
        tm = (r >> 3) * 128; tn = (r & 7) * 128;
        A = ren1 + (long)bb * KRc * 2048; lda = 2048; K = 2048; M = 1024;
        Bt = WtKR;
    } else if (jid < 2048) {
        sect = 1;
        int l = jid - 512;
        int s = (l & 7) * 192 + (l >> 3);       // XCD swizzle (1536 % 8 == 0)
        tn = (s % 24) * 128; tm = (s / 24) * 128;
        A = norm_x; lda = 1024; K = 1024; M = 8192;
        Bt = WtQKVM;
    } else if (jid < 2176) {
        sect = 2;
        int l = jid - 2048;
        bb = l >> 4; tn = (l & 15) * 128; tm = 0;
        A = nxf + (long)bb * NTc * LTc; lda = 768; K = 768; M = 77;
        Bt = WtTXT;
    } else {
        sect = 3;
        int l = jid - 2176;
        int s = (l & 7) * 64 + (l >> 3);        // XCD swizzle (512 % 8 == 0)
        bb = s >> 6; int r = s & 63;
        tm = (r >> 3) * 128; tn = (r & 7) * 128;
        A = ren2 + (long)bb * KRc * 1024; lda = 1024; K = 1024; M = 1024;
        Bt = WtVR;
    }
    const int ldb = lda;  // all B operands have ldb == lda's K-extent
    const bool swap_ops = !(sect == 1 && tn < 1024);

    __shared__ __align__(16) short As[128 * LDK];
    __shared__ __align__(16) short Bs[128 * LDK];

    int tid = threadIdx.x;
    int lane = tid & 63, wid = tid >> 6;
    int wi = wid >> 1, wj = wid & 1;
    int l16 = lane & 15, quad = lane >> 4;

    f32x4 acc[4][4];
    #pragma unroll
    for (int i = 0; i < 4; ++i)
        #pragma unroll
        for (int j = 0; j < 4; ++j)
            acc[i][j] = (f32x4){0.f, 0.f, 0.f, 0.f};

    auto issue = [&](int k0) {
        #pragma unroll
        for (int p = 0; p < 4; ++p) {
            int e = p * 256 + tid;
            int row = e >> 3, c8 = e & 7;
            int gm = tm + row;
            if (gm >= M) gm = M - 1;  // clamp: garbage rows never stored
            gl_lds16(A + (long)gm * lda + k0 + c8 * 8, &As[row * LDK + c8 * 8]);
            gl_lds16(Bt + (long)(tn + row) * ldb + k0 + c8 * 8, &Bs[row * LDK + c8 * 8]);
        }
    };

    issue(0);
    int kt = 0;
    while (true) {
        __syncthreads();
        #pragma unroll
        for (int kk = 0; kk < 2; ++kk) {
            s16x8 af[4], bfr[4];
            #pragma unroll
            for (int i = 0; i < 4; ++i)
                af[i] = *(const s16x8*)&As[(wi * 64 + i * 16 + l16) * LDK + kk * 32 + quad * 8];
            #pragma unroll
            for (int j = 0; j < 4; ++j)
                bfr[j] = *(const s16x8*)&Bs[(wj * 64 + j * 16 + l16) * LDK + kk * 32 + quad * 8];
            if (swap_ops) {
                #pragma unroll
                for (int i = 0; i < 4; ++i)
                    #pragma unroll
                    for (int j = 0; j < 4; ++j)
                        acc[i][j] = __builtin_amdgcn_mfma_f32_16x16x32_bf16(bfr[j], af[i], acc[i][j], 0, 0, 0);
            } else {
                #pragma unroll
                for (int i = 0; i < 4; ++i)
                    #pragma unroll
                    for (int j = 0; j < 4; ++j)
                        acc[i][j] = __builtin_amdgcn_mfma_f32_16x16x32_bf16(af[i], bfr[j], acc[i][j], 0, 0, 0);
            }
        }
        int nxt = kt + 64;
        if (nxt >= K) break;
        __syncthreads();
        issue(nxt);
        kt = nxt;
    }

    if (sect == 1 && tn < 1024) {
        // Q: plain [token][feature] store
        #pragma unroll
        for (int i = 0; i < 4; ++i) {
            #pragma unroll
            for (int r = 0; r < 4; ++r) {
                int gm = tm + wi * 64 + i * 16 + quad * 4 + r;
                #pragma unroll
                for (int j = 0; j < 4; ++j) {
                    int gn = tn + wj * 64 + j * 16 + l16;
                    q16[(long)gm * Dc + gn] = f2b(acc[i][j][r] + bq[gn]);
                }
            }
        }
    } else if (sect == 1) {
        // KM / VM: TR store with per-(b,tok) mask, b = gm>>10
        int sec = tn >> 10, fn0 = tn & 1023;
        const float* bias = (sec == 1) ? bkm : bvm;
        bf16* C = (sec == 1) ? kT : vT;
        #pragma unroll
        for (int j = 0; j < 4; ++j) {
            #pragma unroll
            for (int r = 0; r < 4; ++r) {
                int feat = fn0 + wj * 64 + j * 16 + quad * 4 + r;
                float bf_ = bias[feat];
                #pragma unroll
                for (int i = 0; i < 4; ++i) {
                    int gm = tm + wi * 64 + i * 16 + l16;
                    int b = gm >> 10, tok = gm & 1023;
                    int mi = b * Nc + NTc + KRc + tok;
                    float v = acc[i][j][r] + bf_;
                    if (sec == 1) v += key_add[mi];
                    else          v *= val_mul[mi];
                    C[(long)b * SKT + (long)feat * NP + NTc + KRc + tok] = f2b(v);
                }
            }
        }
    } else if (sect == 0) {
        // retr-K: TR store + key_add
        const float* rmask = key_add + bb * Nc + NTc;
        bf16* C = kT + (long)bb * SKT + NTc;
        #pragma unroll
        for (int j = 0; j < 4; ++j) {
            #pragma unroll
            for (int r = 0; r < 4; ++r) {
                int feat = tn + wj * 64 + j * 16 + quad * 4 + r;
                float bf_ = bkr[feat];
                #pragma unroll
                for (int i = 0; i < 4; ++i) {
                    int tok = tm + wi * 64 + i * 16 + l16;
                    C[(long)feat * NP + tok] = f2b(acc[i][j][r] + bf_ + rmask[tok]);
                }
            }
        }
    } else if (sect == 3) {
        // value-retr: TR store * val_mul
        const float* rmask = val_mul + bb * Nc + NTc;
        bf16* C = vT + (long)bb * SKT + NTc;
        #pragma unroll
        for (int j = 0; j < 4; ++j) {
            #pragma unroll
            for (int r = 0; r < 4; ++r) {
                int feat = tn + wj * 64 + j * 16 + quad * 4 + r;
                float bf_ = bvr[feat];
                #pragma unroll
                for (int i = 0; i < 4; ++i) {
                    int tok = tm + wi * 64 + i * 16 + l16;
                    C[(long)feat * NP + tok] = f2b((acc[i][j][r] + bf_) * rmask[tok]);
                }
            }
        }
    } else {
        // text: sec 0 -> kT (+add), sec 1 -> vT (*mul); tok < 77
        int sec = tn >> 10, fn0 = tn & 1023;
        const float* bias = sec ? bvt : bkt;
        const float* rmask = (sec ? val_mul : key_add) + bb * Nc;
        bf16* C = (sec ? vT : kT) + (long)bb * SKT;
        #pragma unroll
        for (int j = 0; j < 4; ++j) {
            #pragma unroll
            for (int r = 0; r < 4; ++r) {
                int feat = fn0 + wj * 64 + j * 16 + quad * 4 + r;
                float bf_ = bias[feat];
                #pragma unroll
                for (int i = 0; i < 4; ++i) {
                    int tok = wi * 64 + i * 16 + l16;
                    if (tok >= NTc) continue;
                    float v = acc[i][j][r] + bf_;
                    if (sec) v *= rmask[tok];
                    else     v += rmask[tok];
                    C[(long)feat * NP + tok] = f2b(v);
                }
            }
        }
    }
}

// ===== value_retr GEMM (fallback path only: ren2 aliases q16 region) =====
__global__ __launch_bounds__(256) void gemm_vr(
    const short* __restrict__ ren2, const short* __restrict__ WtVR,
    const float* __restrict__ bvr, const float* __restrict__ val_mul,
    bf16* __restrict__ vT) {
    int s = (blockIdx.x & 7) * 64 + (blockIdx.x >> 3);
    int b = s >> 6; int r = s & 63;
    const int tm = (r >> 3) * 128;
    const int tn = (r & 7) * 128;
    const short* A = ren2 + (long)b * KRc * 1024;
    const float* rmask = val_mul + b * Nc + NTc;
    bf16* C = vT + (long)b * SKT + NTc;

    __shared__ __align__(16) short As[128 * LDK];
    __shared__ __align__(16) short Bs[128 * LDK];

    int tid = threadIdx.x;
    int lane = tid & 63, wid = tid >> 6;
    int wi = wid >> 1, wj = wid & 1;
    int l16 = lane & 15, quad = lane >> 4;

    f32x4 acc[4][4];
    #pragma unroll
    for (int i = 0; i < 4; ++i)
        #pragma unroll
        for (int j = 0; j < 4; ++j)
            acc[i][j] = (f32x4){0.f, 0.f, 0.f, 0.f};

    auto issue = [&](int k0) {
        #pragma unroll
        for (int p = 0; p < 4; ++p) {
            int e = p * 256 + tid;
            int row = e >> 3, c8 = e & 7;
            gl_lds16(A + (long)(tm + row) * 1024 + k0 + c8 * 8, &As[row * LDK + c8 * 8]);
            gl_lds16(WtVR + (long)(tn + row) * 1024 + k0 + c8 * 8, &Bs[row * LDK + c8 * 8]);
        }
    };

    issue(0);
    int kt = 0;
    while (true) {
        __syncthreads();
        #pragma unroll
        for (int kk = 0; kk < 2; ++kk) {
            s16x8 af[4], bfr[4];
            #pragma unroll
            for (int i = 0; i < 4; ++i)
                af[i] = *(const s16x8*)&As[(wi * 64 + i * 16 + l16) * LDK + kk * 32 + quad * 8];
            #pragma unroll
            for (int j = 0; j < 4; ++j)
                bfr[j] = *(const s16x8*)&Bs[(wj * 64 + j * 16 + l16) * LDK + kk * 32 + quad * 8];
            #pragma unroll
            for (int i = 0; i < 4; ++i)
                #pragma unroll
                for (int j = 0; j < 4; ++j)
                    acc[i][j] = __builtin_amdgcn_mfma_f32_16x16x32_bf16(bfr[j], af[i], acc[i][j], 0, 0, 0);
        }
        int nxt = kt + 64;
        if (nxt >= 1024) break;
        __syncthreads();
        issue(nxt);
        kt = nxt;
    }

    #pragma unroll
    for (int j = 0; j < 4; ++j) {
        #pragma unroll
        for (int r2 = 0; r2 < 4; ++r2) {
            int feat = tn + wj * 64 + j * 16 + quad * 4 + r2;
            float bf_ = bvr[feat];
            #pragma unroll
            for (int i = 0; i < 4; ++i) {
                int tok = tm + wi * 64 + i * 16 + l16;
                C[(long)feat * NP + tok] = f2b((acc[i][j][r2] + bf_) * rmask[tok]);
            }
        }
    }
}

// ===== out GEMM: 128(M)x64(N) tile, grid 1024 (4 blocks/CU), XCD-swizzled =====
__global__ __launch_bounds__(256) void gemm_out(
    const short* __restrict__ A, const short* __restrict__ Bt,
    const float* __restrict__ bias, const float* __restrict__ addC,
    float* __restrict__ C) {
    int s = (blockIdx.x & 7) * 128 + (blockIdx.x >> 3);  // 1024 % 8 == 0
    const int tm = (s >> 4) * 128;
    const int tn = (s & 15) * 64;

    __shared__ __align__(16) short As[128 * LDK];
    __shared__ __align__(16) short Bs[64 * LDK];

    int tid = threadIdx.x;
    int lane = tid & 63, wid = tid >> 6;
    int wi = wid >> 1, wj = wid & 1;
    int l16 = lane & 15, quad = lane >> 4;

    f32x4 acc[4][2];
    #pragma unroll
    for (int i = 0; i < 4; ++i)
        #pragma unroll
        for (int j = 0; j < 2; ++j)
            acc[i][j] = (f32x4){0.f, 0.f, 0.f, 0.f};

    auto issue = [&](int k0) {
        #pragma unroll
        for (int p = 0; p < 4; ++p) {
            int e = p * 256 + tid;
            int row = e >> 3, c8 = e & 7;
            gl_lds16(A + (long)(tm + row) * 1024 + k0 + c8 * 8, &As[row * LDK + c8 * 8]);
        }
        #pragma unroll
        for (int p = 0; p < 2; ++p) {
            int e = p * 256 + tid;
            int row = e >> 3, c8 = e & 7;
            gl_lds16(Bt + (long)(tn + row) * 1024 + k0 + c8 * 8, &Bs[row * LDK + c8 * 8]);
        }
    };

    issue(0);
    int kt = 0;
    while (true) {
        __syncthreads();
        #pragma unroll
        for (int kk = 0; kk < 2; ++kk) {
            s16x8 af[4], bfr[2];
            #pragma unroll
            for (int i = 0; i < 4; ++i)
                af[i] = *(const s16x8*)&As[(wi * 64 + i * 16 + l16) * LDK + kk * 32 + quad * 8];
            #pragma unroll
            for (int j = 0; j < 2; ++j)
                bfr[j] = *(const s16x8*)&Bs[(wj * 32 + j * 16 + l16) * LDK + kk * 32 + quad * 8];
            #pragma unroll
            for (int i = 0; i < 4; ++i)
                #pragma unroll
                for (int j = 0; j < 2; ++j)
                    acc[i][j] = __builtin_amdgcn_mfma_f32_16x16x32_bf16(af[i], bfr[j], acc[i][j], 0, 0, 0);
        }
        int nxt = kt + 64;
        if (nxt >= 1024) break;
        __syncthreads();
        issue(nxt);
        kt = nxt;
    }

    #pragma unroll
    for (int i = 0; i < 4; ++i) {
        #pragma unroll
        for (int r = 0; r < 4; ++r) {
            int gm = tm + wi * 64 + i * 16 + quad * 4 + r;
            #pragma unroll
            for (int j = 0; j < 2; ++j) {
                int gn = tn + wj * 32 + j * 16 + l16;
                C[(long)gm * 1024 + gn] = acc[i][j][r] + bias[gn] + addC[(long)gm * 1024 + gn];
            }
        }
    }
}

// ===== FUSED SM: q softmax [16384] + ksm_rows [2048] + eo_reduce [64] =====
__global__ __launch_bounds__(256) void fused_sm(
    bf16* __restrict__ q, const bf16* __restrict__ kT,
    float* __restrict__ cs_m, float* __restrict__ cs_inv,
    const float* __restrict__ part, const float* __restrict__ be,
    float* __restrict__ eo) {
    int bid = blockIdx.x;
    int lane = threadIdx.x & 63;
    if (bid < 16384) {
        long row = (long)bid * 4 + (threadIdx.x >> 6);
        bf16* p = q + row * 128 + lane * 2;
        float v0 = b2f(p[0]), v1 = b2f(p[1]);
        float mx = fmaxf(v0, v1);
        #pragma unroll
        for (int off = 32; off > 0; off >>= 1) mx = fmaxf(mx, __shfl_xor(mx, off, 64));
        float e0 = expf(v0 - mx), e1 = expf(v1 - mx);
        float s = e0 + e1;
        #pragma unroll
        for (int off = 32; off > 0; off >>= 1) s += __shfl_xor(s, off, 64);
        float inv = 1.f / s;
        p[0] = f2b(e0 * inv);
        p[1] = f2b(e1 * inv);
    } else if (bid < 18432) {
        int row = (bid - 16384) * 4 + (threadIdx.x >> 6);  // b*1024 + feature
        const s16x8* p8 = (const s16x8*)(kT + (long)row * NP);
        float m = -3.0e38f;
        for (int c = lane; c < NP / 8; c += 64) {
            s16x8 raw = p8[c];
            int n0 = c * 8;
            #pragma unroll
            for (int j = 0; j < 8; ++j)
                if (n0 + j < Nc) m = fmaxf(m, us2f((unsigned short)raw[j]));
        }
        #pragma unroll
        for (int off = 32; off > 0; off >>= 1) m = fmaxf(m, __shfl_xor(m, off, 64));
        float s = 0.f;
        for (int c = lane; c < NP / 8; c += 64) {
            s16x8 raw = p8[c];
            int n0 = c * 8;
            #pragma unroll
            for (int j = 0; j < 8; ++j)
                if (n0 + j < Nc) s += __expf(us2f((unsigned short)raw[j]) - m);
        }
        #pragma unroll
        for (int off = 32; off > 0; off >>= 1) s += __shfl_xor(s, off, 64);
        if (lane == 0) { cs_m[row] = m; cs_inv[row] = 1.f / s; }
    } else {
        int idx = (bid - 18432) * 256 + threadIdx.x;
        int n = idx & 2047, b = idx >> 11;
        float s = be[n];
        #pragma unroll 8
        for (int ks = 0; ks < 32; ++ks) s += part[((long)ks * 8 + b) * 2048 + n];
        eo[idx] = s;
    }
}

// att_part[split][bh][l][d] = sum_{n in split} exp(kT[bd][n]-m_d) * vT[bl][n]  (C^T store)
// ATT_SPLIT=8 -> 512 blocks (2/CU); att_part lives in d_out (32MB, ren1 dead).
constexpr int ATT_SPLIT = 8;
__global__ __launch_bounds__(256) void att_gemm(const bf16* __restrict__ kTb,
                                                const bf16* __restrict__ vTb,
                                                const float* __restrict__ cs_m,
                                                float* __restrict__ att_part) {
    int bh = blockIdx.x;
    int split = blockIdx.y;
    int b = bh >> 3, h = bh & 7;
    const short* A  = (const short*)kTb + ((long)b * 1024 + h * 128) * NP;
    const short* Bt = (const short*)vTb + ((long)b * 1024 + h * 128) * NP;
    float* ap = att_part + ((long)split * 64 + bh) * 16384;

    __shared__ __align__(16) short As[128 * LDK];
    __shared__ __align__(16) short Bs[128 * LDK];
    __shared__ float ms[128];

    int tid = threadIdx.x;
    if (tid < 128) ms[tid] = cs_m[(long)b * 1024 + h * 128 + tid];

    int lane = tid & 63, wid = tid >> 6;
    int wi = wid >> 1, wj = wid & 1;
    int l16 = lane & 15, quad = lane >> 4;

    f32x4 acc[4][4];
    #pragma unroll
    for (int i = 0; i < 4; ++i)
        #pragma unroll
        for (int j = 0; j < 4; ++j)
            acc[i][j] = (f32x4){0.f, 0.f, 0.f, 0.f};

    uint4 pa[4];
    auto computeA = [&](int k0) {
        #pragma unroll
        for (int p = 0; p < 4; ++p) {
            int e = p * 256 + tid;
            int row = e >> 3, c8 = e & 7;
            int n0 = k0 + c8 * 8;
            union { short s[8]; uint4 u; } pk;
            if (n0 >= Nc) {
                pk.u = (uint4){0u, 0u, 0u, 0u};
            } else {
                float m = ms[row];
                s16x8 raw = *(const s16x8*)(A + (long)row * NP + n0);
                #pragma unroll
                for (int j = 0; j < 8; ++j) {
                    float v = (n0 + j < Nc) ? __expf(us2f((unsigned short)raw[j]) - m) : 0.f;
                    pk.s[j] = f2s(v);
                }
            }
            pa[p] = pk.u;
        }
    };
    auto issueB = [&](int k0) {
        #pragma unroll
        for (int p = 0; p < 4; ++p) {
            int e = p * 256 + tid;
            int row = e >> 3, c8 = e & 7;
            int n0 = k0 + c8 * 8;
            if (n0 > NP - 8) n0 = NP - 8;  // clamp: A is zero there, values just must be finite
            gl_lds16(Bt + (long)row * NP + n0, &Bs[row * LDK + c8 * 8]);
        }
    };
    auto storeA = [&]() {
        #pragma unroll
        for (int p = 0; p < 4; ++p) {
            int e = p * 256 + tid;
            int row = e >> 3, c8 = e & 7;
            *(uint4*)&As[row * LDK + c8 * 8] = pa[p];
        }
    };

    // 34 K-steps total, splits {5,5,4,4,4,4,4,4}
    int st = (split < 2) ? split * 5 : 10 + (split - 2) * 4;
    int cnt = (split < 2) ? 5 : 4;
    int kt = st * 64;
    int kend = kt + cnt * 64;

    __syncthreads();  // ms ready
    issueB(kt);
    computeA(kt);
    storeA();
    while (true) {
        __syncthreads();
        #pragma unroll
        for (int kk = 0; kk < 2; ++kk) {
            s16x8 af[4], bfr[4];
            #pragma unroll
            for (int i = 0; i < 4; ++i)
                af[i] = *(const s16x8*)&As[(wi * 64 + i * 16 + l16) * LDK + kk * 32 + quad * 8];
            #pragma unroll
            for (int j = 0; j < 4; ++j)
                bfr[j] = *(const s16x8*)&Bs[(wj * 64 + j * 16 + l16) * LDK + kk * 32 + quad * 8];
            #pragma unroll
            for (int i = 0; i < 4; ++i)
                #pragma unroll
                for (int j = 0; j < 4; ++j)
                    acc[i][j] = __builtin_amdgcn_mfma_f32_16x16x32_bf16(bfr[j], af[i], acc[i][j], 0, 0, 0);
        }
        int nxt = kt + 64;
        if (nxt >= kend) break;
        computeA(nxt);
        __syncthreads();
        issueB(nxt);
        storeA();
        kt = nxt;
    }

    // C^T: acc rows = value-feature l (tile j), cols = key-feature d (tile i)
    #pragma unroll
    for (int j = 0; j < 4; ++j) {
        #pragma unroll
        for (int r = 0; r < 4; ++r) {
            int l = wj * 64 + j * 16 + quad * 4 + r;
            #pragma unroll
            for (int i = 0; i < 4; ++i) {
                int d = wi * 64 + i * 16 + l16;
                ap[l * 128 + d] = acc[i][j][r];
            }
        }
    }
}

// reduce splits + apply per-d 1/sum -> bf16 attT[bh][l][d] (ready B^T operand for y)
__global__ __launch_bounds__(256) void reduce_att_t(const float* __restrict__ att_part,
                                                    const float* __restrict__ cs_inv,
                                                    bf16* __restrict__ attT) {
    long idx = (long)blockIdx.x * 256 + threadIdx.x;
    if (idx >= (long)64 * 16384) return;
    float s = 0.f;
    #pragma unroll
    for (int sp = 0; sp < ATT_SPLIT; ++sp) s += att_part[(long)sp * 64 * 16384 + idx];
    int bh = (int)(idx >> 14);
    int d = (int)(idx & 127);
    int b = bh >> 3, h = bh & 7;
    attT[idx] = f2b(s * cs_inv[b * Dc + h * 128 + d]);
}

// y[b,t,h*128+l] = sum_d q[b,t,h*128+d] * att[bh][d][l] — MFMA, K=128 single stage.
__global__ __launch_bounds__(256) void y_gemm(const bf16* __restrict__ q,
                                              const bf16* __restrict__ attT,
                                              bf16* __restrict__ y) {
    int bh = blockIdx.y;
    int b = bh >> 3, h = bh & 7;
    const short* A  = (const short*)q + (long)b * Tc * Dc + h * 128;   // row stride Dc
    const short* Bt = (const short*)attT + (long)bh * 16384;           // [l][d] stride 128
    bf16* yb = y + (long)b * Tc * Dc + h * 128;
    int tm = blockIdx.x * 128;

    __shared__ __align__(16) short As[128 * 128];
    __shared__ __align__(16) short Bs[128 * 128];
    int tid = threadIdx.x;
    #pragma unroll
    for (int p = 0; p < 8; ++p) {
        int e = p * 256 + tid;
        int row = e >> 4, c8 = e & 15;
        gl_lds16(A + (long)(tm + row) * Dc + c8 * 8, &As[row * 128 + c8 * 8]);
        gl_lds16(Bt + row * 128 + c8 * 8, &Bs[row * 128 + c8 * 8]);
    }
    int lane = tid & 63, wid = tid >> 6;
    int wi = wid >> 1, wj = wid & 1;
    int l16 = lane & 15, quad = lane >> 4;
    f32x4 acc[4][4];
    #pragma unroll
    for (int i = 0; i < 4; ++i)
        #pragma unroll
        for (int j = 0; j < 4; ++j)
            acc[i][j] = (f32x4){0.f, 0.f, 0.f, 0.f};
    __syncthreads();
    #pragma unroll
    for (int kk = 0; kk < 4; ++kk) {
        s16x8 af[4], bfr[4];
        #pragma unroll
        for (int i = 0; i < 4; ++i)
            af[i] = *(const s16x8*)&As[(wi * 64 + i * 16 + l16) * 128 + kk * 32 + quad * 8];
        #pragma unroll
        for (int j = 0; j < 4; ++j)
            bfr[j] = *(const s16x8*)&Bs[(wj * 64 + j * 16 + l16) * 128 + kk * 32 + quad * 8];
        #pragma unroll
        for (int i = 0; i < 4; ++i)
            #pragma unroll
            for (int j = 0; j < 4; ++j)
                acc[i][j] = __builtin_amdgcn_mfma_f32_16x16x32_bf16(af[i], bfr[j], acc[i][j], 0, 0, 0);
    }
    #pragma unroll
    for (int i = 0; i < 4; ++i) {
        #pragma unroll
        for (int r = 0; r < 4; ++r) {
            int gm = tm + wi * 64 + i * 16 + quad * 4 + r;
            #pragma unroll
            for (int j = 0; j < 4; ++j) {
                int gn = wj * 64 + j * 16 + l16;
                yb[(long)gm * Dc + gn] = f2b(acc[i][j][r]);
            }
        }
    }
}

// s = silu( LN(y)*(1+scale) + shift )
__global__ __launch_bounds__(256) void film_kernel(const bf16* __restrict__ y,
                                                   const float* __restrict__ eo,
                                                   const float* __restrict__ g,
                                                   const float* __restrict__ bta,
                                                   bf16* __restrict__ s) {
    long row = blockIdx.x;
    int b = (int)(row >> 10);
    const bf16* yr = y + row * Dc;
    float sum = 0.f, sum2 = 0.f;
    for (int c = threadIdx.x; c < Dc; c += 256) { float v = b2f(yr[c]); sum += v; sum2 += v * v; }
    float2 r = block_sum2(sum, sum2);
    float mean = r.x / Dc;
    float var = r.y / Dc - mean * mean;
    float inv = rsqrtf(var + 1e-5f);
    const float* sc = eo + (long)b * 2048;
    const float* sf = sc + 1024;
    bf16* so = s + row * Dc;
    for (int c = threadIdx.x; c < Dc; c += 256) {
        float v = (b2f(yr[c]) - mean) * inv * g[c] + bta[c];
        v = v * (1.f + sc[c]) + sf[c];
        so[c] = f2b(v / (1.f + expf(-v)));
    }
}

extern "C" void kernel_launch(void* const* d_in, const int* in_sizes, int n_in,
                              void* d_out, int out_size, void* d_ws, size_t ws_size,
                              hipStream_t stream) {
    if (ws_size < WS_NEED) return;
    const bool big = ws_size >= WS_BIG;

    const float* x         = (const float*)d_in[0];
    const float* xf        = (const float*)d_in[1];
    const float* emb       = (const float*)d_in[2];
    const float* src_mask  = (const float*)d_in[3];
    const int*   cond_type = (const int*)d_in[4];
    const float* re_motion = (const float*)d_in[5];
    const float* re_text   = (const float*)d_in[6];
    const float* re_mask   = (const float*)d_in[7];
    const float* ln_g  = (const float*)d_in[8];
    const float* ln_b  = (const float*)d_in[9];
    const float* tln_g = (const float*)d_in[10];
    const float* tln_b = (const float*)d_in[11];
    const float* rn1_g = (const float*)d_in[12];
    const float* rn1_b = (const float*)d_in[13];
    const float* rn2_g = (const float*)d_in[14];
    const float* rn2_b = (const float*)d_in[15];
    const float* Wq  = (const float*)d_in[16];
    const float* bq  = (const float*)d_in[17];
    const float* Wkt = (const float*)d_in[18];
    const float* bkt = (const float*)d_in[19];
    const float* Wvt = (const float*)d_in[20];
    const float* bvt = (const float*)d_in[21];
    const float* Wkm = (const float*)d_in[22];
    const float* bkm = (const float*)d_in[23];
    const float* Wvm = (const float*)d_in[24];
    const float* bvm = (const float*)d_in[25];
    const float* Wkr = (const float*)d_in[26];
    const float* bkr = (const float*)d_in[27];
    const float* Wvr = (const float*)d_in[28];
    const float* bvr = (const float*)d_in[29];
    const float* We  = (const float*)d_in[30];
    const float* be  = (const float*)d_in[31];
    const float* sln_g = (const float*)d_in[32];
    const float* sln_b = (const float*)d_in[33];
    const float* Wo  = (const float*)d_in[34];
    const float* bo  = (const float*)d_in[35];

    float* ws = (float*)d_ws;
    float* key_add  = ws + F_KEYADD;
    float* val_mul  = ws + F_VALMUL;
    float* cs_m     = ws + F_SILU;         // 8192
    float* cs_inv   = cs_m + Bc * Dc;      // 8192
    float* eo       = ws + F_EO;
    bf16*  attT     = (bf16*)(ws + F_ATT);       // first 2MB of slot
    float* eo_part  = ws + F_ATT + 524288;       // second 2MB of slot (disjoint)
    bf16* wb = (bf16*)(ws + F_END);
    bf16* norm_x16 = wb + B_NORMX;
    bf16* q16      = wb + B_Q;
    bf16* kT16     = wb + B_KT;
    bf16* vT16     = wb + B_VT;
    bf16* nxf16    = wb + B_NXF;
    short* WtQ  = (short*)(wb + B_WQ);     // WtQ/WtKM/WtVM contiguous = QKVM B-operand
    short* WtKM = (short*)(wb + B_WKM);
    short* WtVM = (short*)(wb + B_WVM);
    short* WtKT = (short*)(wb + B_WKT);    // WtKT/WtVT contiguous = text B-operand
    short* WtVT = (short*)(wb + B_WVT);
    short* WtKR = (short*)(wb + B_WKR);
    short* WtVR = (short*)(wb + B_WVR);
    short* WtO  = (short*)(wb + B_WO);
    bf16* y16 = wb + B_NORMX;                  // norm_x16 dead after mega
    bf16* s16 = q16;                           // q dead after y_gemm
    bf16* ren1 = (bf16*)d_out;                 // 32MB scratch, dead after mega
    float* att_part = (float*)d_out;           // 32MB, overlays ren1 (dead by att time)
    bf16* ren2 = big ? (wb + B_REN2) : q16;    // big: own region (VR folds into mega)

    float* out = (float*)d_out;

    // 1. FUSED PRE: ln(x) + ln(xf) + retrieval-LN materialize + masks/zero  [17099 blocks]
    fused_pre<<<dim3(17099), dim3(256), 0, stream>>>(
        x, ln_g, ln_b, norm_x16, xf, tln_g, tln_b, nxf16,
        re_motion, re_text, rn1_g, rn1_b, rn2_g, rn2_b, ren1, ren2,
        cond_type, src_mask, re_mask, key_add, val_mul, vT16);

    // 2. FUSED W: all weight transposes + eo split-K partial  [8960 blocks]
    fused_w<<<dim3(8960), dim3(256), 0, stream>>>(
        Wq, Wkt, Wvt, Wkm, Wvm, Wkr, Wvr, Wo,
        WtQ, WtKT, WtVT, WtKM, WtVM, WtKR, WtVR, WtO,
        emb, We, eo_part);

    // 3. value_retr separately only when ren2 aliases q16 (fallback ws)
    if (!big)
        gemm_vr<<<dim3(512), dim3(256), 0, stream>>>(
            (const short*)ren2, WtVR, bvr, val_mul, vT16);

    // 4. MEGA: retrK + qkvm + text (+ VR when big) in one launch
    gemm_mega<<<dim3(big ? 2688 : 2176), dim3(256), 0, stream>>>(
        (const short*)norm_x16, (const short*)ren1, (const short*)ren2,
        (const short*)nxf16, WtQ, WtKR, WtVR, WtKT,
        bq, bkm, bvm, bkr, bvr, bkt, bvt,
        key_add, val_mul, q16, kT16, vT16);

    // 5. FUSED SM: q softmax + key column stats + eo reduce  [18496 blocks]
    fused_sm<<<dim3(18496), dim3(256), 0, stream>>>(
        q16, kT16, cs_m, cs_inv, eo_part, be, eo);

    // 6. att = p^T v (MFMA, C^T store, 8-way split in d_out), reduce -> bf16 attT
    att_gemm<<<dim3(Bc * Hc, ATT_SPLIT), dim3(256), 0, stream>>>(kT16, vT16, cs_m, att_part);
    reduce_att_t<<<dim3((64 * 16384 + 255) / 256), dim3(256), 0, stream>>>(att_part, cs_inv, attT);

    // 7. y = q @ att (MFMA)
    y_gemm<<<dim3(Tc / 128, Bc * Hc), dim3(256), 0, stream>>>(q16, attT, y16);

    // 8. FiLM + silu
    film_kernel<<<dim3(Bc * Tc), dim3(256), 0, stream>>>(y16, eo, sln_g, sln_b, s16);

    // 9. out = x + s @ Wo + bo  (128x64 tiles, 1024 blocks, XCD-swizzled)
    gemm_out<<<dim3(1024), dim3(256), 0, stream>>>(
        (const short*)s16, WtO, bo, x, out);
}

// Round 9
// 561.588 us; speedup vs baseline: 1.8652x; 1.0160x over previous
//
#include <hip/hip_runtime.h>
#include <hip/hip_bf16.h>
#include <math.h>

using bf16 = __hip_bfloat16;

typedef short s16x8 __attribute__((ext_vector_type(8)));
typedef short s16x4 __attribute__((ext_vector_type(4)));
typedef float f32x4 __attribute__((ext_vector_type(4)));

// Problem dims (fixed by setup_inputs)
constexpr int Bc = 8, Tc = 1024, Dc = 1024, Hc = 8;
constexpr int NTc = 77, LTc = 768, KRc = 1024, Nc = 2125, Ec = 2048;
constexpr float NEGC = -1000000.0f;

// Transposed K/V layout: [b][feature(1024)][token], row stride NP (16B-aligned)
constexpr int NP = 2128;  // 2125 tokens + 3 pad (zeroed in vT; guarded in kT reads)
constexpr long SKT = (long)Dc * NP;

// ---- Workspace layout ----
constexpr long F_STATS1 = 0;                    // (unused, layout stability)
constexpr long F_STATS2 = F_STATS1 + 16384;
constexpr long F_KEYADD = F_STATS2 + 16384;     // 17,000
constexpr long F_VALMUL = F_KEYADD + 17000;     // 17,000
constexpr long F_SILU   = F_VALMUL + 17000;     // 16,384 (cs_m[8192] + cs_inv[8192])
constexpr long F_EO     = F_SILU + 16384;       // 16,384
constexpr long F_ATT    = F_EO + 16384;         // 1,048,576 floats: attT bf16 (2MB) + eo_part fp32 (2MB)
constexpr long F_END    = F_ATT + 1048576;
// bf16 region
constexpr long KT_SZ   = (long)Bc * Dc * NP;    // 17,432,576
constexpr long B_NORMX = 0;                     // 8,388,608 (reused: y16 later)
constexpr long B_Q     = B_NORMX + 8388608;     // 8,388,608 (ren2 fallback, q16, s16)
constexpr long B_KT    = B_Q + 8388608;         // kT  [b][d][n]
constexpr long B_VT    = B_KT + KT_SZ;          // vT  [b][l][n]
constexpr long B_NXF   = B_VT + KT_SZ;          // 473,088
// Weights: Q, KM, VM contiguous (fused QKVM B-operand = 3072 rows x 1024)
constexpr long B_WQ    = B_NXF + 473088;
constexpr long B_WKM   = B_WQ + 1048576;
constexpr long B_WVM   = B_WKM + 1048576;
constexpr long B_WKT   = B_WVM + 1048576;       // WtKT + WtVT contiguous (text B-operand)
constexpr long B_WVT   = B_WKT + 786432;
constexpr long B_WKR   = B_WVT + 786432;
constexpr long B_WVR   = B_WKR + 2097152;
constexpr long B_WO    = B_WVR + 1048576;
constexpr long B_END   = B_WO + 1048576;
constexpr long B_REN2  = B_END;                 // optional 16MB ren2 (big-ws path)
constexpr long REN2_SZ = 8388608;
constexpr size_t WS_NEED = (size_t)F_END * 4 + (size_t)B_END * 2;
constexpr size_t WS_BIG  = (size_t)F_END * 4 + (size_t)(B_END + REN2_SZ) * 2;

__device__ __forceinline__ float b2f(bf16 v) { return __bfloat162float(v); }
__device__ __forceinline__ bf16 f2b(float v) { return __float2bfloat16(v); }
__device__ __forceinline__ short f2s(float v) {
    bf16 h = __float2bfloat16(v);
    return *reinterpret_cast<short*>(&h);
}
__device__ __forceinline__ float us2f(unsigned short u) {
    bf16 h = *reinterpret_cast<bf16*>(&u);
    return __bfloat162float(h);
}
__device__ __forceinline__ void storef(float* p, float v) { *p = v; }
__device__ __forceinline__ void storef(bf16* p, float v) { *p = __float2bfloat16(v); }

// async global->LDS, 16B per lane. LDS dest must be wave-uniform base + lane*16.
typedef __attribute__((address_space(1))) const unsigned int gu32;
typedef __attribute__((address_space(3))) unsigned int lu32;
__device__ __forceinline__ void gl_lds16(const void* g, void* l) {
    __builtin_amdgcn_global_load_lds((gu32*)g, (lu32*)l, 16, 0, 0);
}

__device__ __forceinline__ float2 block_sum2(float s, float s2) {
    #pragma unroll
    for (int off = 32; off > 0; off >>= 1) {
        s  += __shfl_down(s, off, 64);
        s2 += __shfl_down(s2, off, 64);
    }
    __shared__ float sh[4], sh2[4];
    int w = threadIdx.x >> 6, lane = threadIdx.x & 63;
    if (lane == 0) { sh[w] = s; sh2[w] = s2; }
    __syncthreads();
    s = sh[0] + sh[1] + sh[2] + sh[3];
    s2 = sh2[0] + sh2[1] + sh2[2] + sh2[3];
    return make_float2(s, s2);
}

// Single-pass vectorized row LN: thread owns 4 consecutive floats (float4).
__device__ __forceinline__ void ln_row_vec(const float* __restrict__ x,
                                           const float* __restrict__ g,
                                           const float* __restrict__ b,
                                           bf16* __restrict__ o, int C) {
    int c = threadIdx.x * 4;
    bool act = c < C;
    float4 v = make_float4(0.f, 0.f, 0.f, 0.f);
    if (act) v = *(const float4*)(x + c);
    float s = v.x + v.y + v.z + v.w;
    float s2 = v.x * v.x + v.y * v.y + v.z * v.z + v.w * v.w;
    float2 r = block_sum2(s, s2);
    float mean = r.x / C;
    float var = r.y / C - mean * mean;
    float inv = rsqrtf(var + 1e-5f);
    if (act) {
        float4 gv = *(const float4*)(g + c), bv = *(const float4*)(b + c);
        s16x4 ov;
        ov[0] = f2s((v.x - mean) * inv * gv.x + bv.x);
        ov[1] = f2s((v.y - mean) * inv * gv.y + bv.y);
        ov[2] = f2s((v.z - mean) * inv * gv.z + bv.z);
        ov[3] = f2s((v.w - mean) * inv * gv.w + bv.w);
        *(s16x4*)((short*)o + c) = ov;
    }
}

__device__ __forceinline__ s16x4 pack4(float4 v, float mean, float rstd, float4 g, float4 b) {
    s16x4 o;
    o[0] = f2s((v.x - mean) * rstd * g.x + b.x);
    o[1] = f2s((v.y - mean) * rstd * g.y + b.y);
    o[2] = f2s((v.z - mean) * rstd * g.z + b.z);
    o[3] = f2s((v.w - mean) * rstd * g.w + b.w);
    return o;
}

// ===== FUSED PRE: ln(x) [8192] + ln(xf) [616] + ln_mat [8192] + prep/zero [99] =====
__global__ __launch_bounds__(256) void fused_pre(
    const float* __restrict__ x, const float* __restrict__ ln_g,
    const float* __restrict__ ln_b, bf16* __restrict__ norm_x,
    const float* __restrict__ xf, const float* __restrict__ tln_g,
    const float* __restrict__ tln_b, bf16* __restrict__ nxf,
    const float* __restrict__ motion, const float* __restrict__ text,
    const float* __restrict__ g1, const float* __restrict__ b1,
    const float* __restrict__ g2, const float* __restrict__ b2,
    bf16* __restrict__ ren1, bf16* __restrict__ ren2,
    const int* __restrict__ cond_type, const float* __restrict__ src_mask,
    const float* __restrict__ re_mask,
    float* __restrict__ key_add, float* __restrict__ val_mul,
    bf16* __restrict__ vT) {
    int bid = blockIdx.x;
    if (bid < 8192) {
        long row = bid;
        ln_row_vec(x + row * 1024, ln_g, ln_b, norm_x + row * 1024, 1024);
    } else if (bid < 8808) {
        long row = bid - 8192;
        ln_row_vec(xf + row * 768, tln_g, tln_b, nxf + row * 768, 768);
    } else if (bid < 17000) {
        long row = bid - 8808;  // b*1024 + kr
        int c = threadIdx.x * 4;
        const float* mrow = motion + row * 1024;
        const float* trow = text + (row >> 9) * 1024;
        float4 mv = *(const float4*)(mrow + c);
        float4 tv = *(const float4*)(trow + c);
        float sm = mv.x + mv.y + mv.z + mv.w;
        float sm2 = mv.x * mv.x + mv.y * mv.y + mv.z * mv.z + mv.w * mv.w;
        float2 rm = block_sum2(sm, sm2);
        __syncthreads();
        float st = tv.x + tv.y + tv.z + tv.w;
        float st2 = tv.x * tv.x + tv.y * tv.y + tv.z * tv.z + tv.w * tv.w;
        float2 rt = block_sum2(st, st2);
        float mean2 = rm.x / 1024.f;
        float var2 = rm.y / 1024.f - mean2 * mean2;
        float r2 = rsqrtf(var2 + 1e-5f);
        float mean1 = (rm.x + rt.x) / 2048.f;
        float var1 = (rm.y + rt.y) / 2048.f - mean1 * mean1;
        float r1 = rsqrtf(var1 + 1e-5f);
        float4 g1m = *(const float4*)(g1 + c),        b1m = *(const float4*)(b1 + c);
        float4 g1t = *(const float4*)(g1 + 1024 + c), b1t = *(const float4*)(b1 + 1024 + c);
        float4 g2m = *(const float4*)(g2 + c),        b2m = *(const float4*)(b2 + c);
        *(s16x4*)((short*)ren1 + row * 2048 + c)        = pack4(mv, mean1, r1, g1m, b1m);
        *(s16x4*)((short*)ren1 + row * 2048 + 1024 + c) = pack4(tv, mean1, r1, g1t, b1t);
        *(s16x4*)((short*)ren2 + row * 1024 + c)        = pack4(mv, mean2, r2, g2m, b2m);
    } else {
        int b2i = bid - 17000;  // 0..98
        if (b2i < 67) {
            int idx = b2i * 256 + threadIdx.x;
            if (idx >= Bc * Nc) return;
            int b = idx / Nc, n = idx % Nc;
            int ct = cond_type[b];
            float text_ct = ((ct % 10) > 0) ? 1.f : 0.f;
            float retr_ct = ((ct / 10) > 0) ? 1.f : 0.f;
            float add, mul;
            if (n < NTc) {
                add = (1.f - text_ct) * NEGC; mul = text_ct;
            } else if (n < NTc + KRc) {
                float rm = re_mask[b * KRc + (n - NTc)];
                add = (1.f - retr_ct) * NEGC + (1.f - rm) * NEGC;
                mul = retr_ct * rm;
            } else {
                float sm = src_mask[b * Tc + (n - NTc - KRc)];
                add = (1.f - sm) * NEGC; mul = sm;
            }
            key_add[idx] = add;
            val_mul[idx] = mul;
        } else {
            int row = (b2i - 67) * 256 + threadIdx.x;
            if (row >= Bc * Dc) return;
            bf16* p = vT + (long)row * NP + Nc;
            p[0] = f2b(0.f); p[1] = f2b(0.f); p[2] = f2b(0.f);
        }
    }
}

// ===== FUSED W: weight transposes [8704] + eo_partial [256] =====
__global__ __launch_bounds__(256) void fused_w(
    const float* __restrict__ Wq,  const float* __restrict__ Wkt,
    const float* __restrict__ Wvt, const float* __restrict__ Wkm,
    const float* __restrict__ Wvm, const float* __restrict__ Wkr,
    const float* __restrict__ Wvr, const float* __restrict__ Wo,
    short* __restrict__ WtQ,  short* __restrict__ WtKT,
    short* __restrict__ WtVT, short* __restrict__ WtKM,
    short* __restrict__ WtVM, short* __restrict__ WtKR,
    short* __restrict__ WtVR, short* __restrict__ WtO,
    const float* __restrict__ emb, const float* __restrict__ We,
    float* __restrict__ part) {
    __shared__ float t[32][33];
    int bid = blockIdx.x;
    if (bid < 8704) {
        int sy = bid >> 5;
        int n0 = (bid & 31) * 32;
        const float* W; short* Wt; int K; int ky;
        if (sy < 32)       { W = Wq;  Wt = WtQ;  K = 1024; ky = sy; }
        else if (sy < 56)  { W = Wkt; Wt = WtKT; K = 768;  ky = sy - 32; }
        else if (sy < 80)  { W = Wvt; Wt = WtVT; K = 768;  ky = sy - 56; }
        else if (sy < 112) { W = Wkm; Wt = WtKM; K = 1024; ky = sy - 80; }
        else if (sy < 144) { W = Wvm; Wt = WtVM; K = 1024; ky = sy - 112; }
        else if (sy < 208) { W = Wkr; Wt = WtKR; K = 2048; ky = sy - 144; }
        else if (sy < 240) { W = Wvr; Wt = WtVR; K = 1024; ky = sy - 208; }
        else               { W = Wo;  Wt = WtO;  K = 1024; ky = sy - 240; }
        int k0 = ky * 32;
        int tx = threadIdx.x & 31, ty = threadIdx.x >> 5;
        #pragma unroll
        for (int i = 0; i < 4; ++i)
            t[ty + i * 8][tx] = W[(long)(k0 + ty + i * 8) * 1024 + n0 + tx];
        __syncthreads();
        #pragma unroll
        for (int i = 0; i < 4; ++i)
            Wt[(long)(n0 + ty + i * 8) * K + k0 + tx] = f2s(t[tx][ty + i * 8]);
    } else {
        int l = bid - 8704;
        int nb = l & 7, ks = l >> 3;
        int n = nb * 256 + threadIdx.x;
        int k0 = ks * 64;
        __shared__ float a_s[8][64];
        for (int idx = threadIdx.x; idx < 512; idx += 256) {
            int b = idx >> 6, kk = idx & 63;
            float v = emb[b * 2048 + k0 + kk];
            a_s[b][kk] = v / (1.f + expf(-v));
        }
        __syncthreads();
        float acc[8] = {};
        for (int kk = 0; kk < 64; ++kk) {
            float w = We[(long)(k0 + kk) * 2048 + n];
            #pragma unroll
            for (int b = 0; b < 8; ++b) acc[b] = fmaf(a_s[b][kk], w, acc[b]);
        }
        #pragma unroll
        for (int b = 0; b < 8; ++b) part[((long)ks * 8 + b) * 2048 + n] = acc[b];
    }
}

// ======================= 128^2 MFMA GEMM template pieces ====================
// NOTE (R4/R5 post-mortem): 512-thread workgroups pin VGPR_Count=128 on this
// toolchain -> deep accumulators spill to scratch. Stay 256-thr.
// R9: 2-phase DOUBLE-BUFFERED K-loop (one barrier per K-step) per T3 recipe;
// verified correct in R4's gemm_bt2 (it passed; only slow due to VGPR cap).
constexpr int LDK = 64;

// ===== MEGA: retrK (512) + qkvm (1536) + text (128) [+ VR (512) big-ws] =====
__global__ __launch_bounds__(256) void gemm_mega(
    const short* __restrict__ norm_x, const short* __restrict__ ren1,
    const short* __restrict__ ren2, const short* __restrict__ nxf,
    const short* __restrict__ WtQKVM, const short* __restrict__ WtKR,
    const short* __restrict__ WtVR, const short* __restrict__ WtTXT,
    const float* __restrict__ bq, const float* __restrict__ bkm,
    const float* __restrict__ bvm, const float* __restrict__ bkr,
    const float* __restrict__ bvr,
    const float* __restrict__ bkt, const float* __restrict__ bvt,
    const float* __restrict__ key_add, const float* __restrict__ val_mul,
    bf16* __restrict__ q16, bf16* __restrict__ kT, bf16* __restrict__ vT) {
    int jid = blockIdx.x;
    int sect, tm, tn, K, M, lda, bb = 0;
    const short* A; const short* Bt;
    if (jid < 512) {
        sect = 0;
        int s = (jid & 7) * 64 + (jid >> 3);    // XCD swizzle (512 % 8 == 0)
        bb = s >> 6; int r = s & 63;
        tm = (r >> 3) * 128; tn = (r & 7) * 128;
        A = ren1 + (long)bb * KRc * 2048; lda = 2048; K = 2048; M = 1024;
        Bt = WtKR;
    } else if (jid < 2048) {
        sect = 1;
        int l = jid - 512;
        int s = (l & 7) * 192 + (l >> 3);       // XCD swizzle (1536 % 8 == 0)
        tn = (s % 24) * 128; tm = (s / 24) * 128;
        A = norm_x; lda = 1024; K = 1024; M = 8192;
        Bt = WtQKVM;
    } else if (jid < 2176) {
        sect = 2;
        int l = jid - 2048;
        bb = l >> 4; tn = (l & 15) * 128; tm = 0;
        A = nxf + (long)bb * NTc * LTc; lda = 768; K = 768; M = 77;
        Bt = WtTXT;
    } else {
        sect = 3;
        int l = jid - 2176;
        int s = (l & 7) * 64 + (l >> 3);        // XCD swizzle (512 % 8 == 0)
        bb = s >> 6; int r = s & 63;
        tm = (r >> 3) * 128; tn = (r & 7) * 128;
        A = ren2 + (long)bb * KRc * 1024; lda = 1024; K = 1024; M = 1024;
        Bt = WtVR;
    }
    const int ldb = lda;  // all B operands have ldb == lda's K-extent
    const bool swap_ops = !(sect == 1 && tn < 1024);

    __shared__ __align__(16) short As[2][128 * LDK];
    __shared__ __align__(16) short Bs[2][128 * LDK];

    int tid = threadIdx.x;
    int lane = tid & 63, wid = tid >> 6;
    int wi = wid >> 1, wj = wid & 1;
    int l16 = lane & 15, quad = lane >> 4;

    f32x4 acc[4][4];
    #pragma unroll
    for (int i = 0; i < 4; ++i)
        #pragma unroll
        for (int j = 0; j < 4; ++j)
            acc[i][j] = (f32x4){0.f, 0.f, 0.f, 0.f};

    auto issue = [&](int k0, int buf) {
        #pragma unroll
        for (int p = 0; p < 4; ++p) {
            int e = p * 256 + tid;
            int row = e >> 3, c8 = e & 7;
            int gm = tm + row;
            if (gm >= M) gm = M - 1;  // clamp: garbage rows never stored
            gl_lds16(A + (long)gm * lda + k0 + c8 * 8, &As[buf][row * LDK + c8 * 8]);
            gl_lds16(Bt + (long)(tn + row) * ldb + k0 + c8 * 8, &Bs[buf][row * LDK + c8 * 8]);
        }
    };
    auto compute = [&](int buf) {
        const short* as = As[buf];
        const short* bs = Bs[buf];
        #pragma unroll
        for (int kk = 0; kk < 2; ++kk) {
            s16x8 af[4], bfr[4];
            #pragma unroll
            for (int i = 0; i < 4; ++i)
                af[i] = *(const s16x8*)&as[(wi * 64 + i * 16 + l16) * LDK + kk * 32 + quad * 8];
            #pragma unroll
            for (int j = 0; j < 4; ++j)
                bfr[j] = *(const s16x8*)&bs[(wj * 64 + j * 16 + l16) * LDK + kk * 32 + quad * 8];
            if (swap_ops) {
                #pragma unroll
                for (int i = 0; i < 4; ++i)
                    #pragma unroll
                    for (int j = 0; j < 4; ++j)
                        acc[i][j] = __builtin_amdgcn_mfma_f32_16x16x32_bf16(bfr[j], af[i], acc[i][j], 0, 0, 0);
            } else {
                #pragma unroll
                for (int i = 0; i < 4; ++i)
                    #pragma unroll
                    for (int j = 0; j < 4; ++j)
                        acc[i][j] = __builtin_amdgcn_mfma_f32_16x16x32_bf16(af[i], bfr[j], acc[i][j], 0, 0, 0);
            }
        }
    };

    issue(0, 0);
    __syncthreads();
    int cur = 0, kt = 0;
    while (true) {
        int nxt = kt + 64;
        if (nxt < K) issue(nxt, cur ^ 1);
        compute(cur);
        if (nxt >= K) break;
        __syncthreads();
        cur ^= 1;
        kt = nxt;
    }

    if (sect == 1 && tn < 1024) {
        // Q: plain [token][feature] store
        #pragma unroll
        for (int i = 0; i < 4; ++i) {
            #pragma unroll
            for (int r = 0; r < 4; ++r) {
                int gm = tm + wi * 64 + i * 16 + quad * 4 + r;
                #pragma unroll
                for (int j = 0; j < 4; ++j) {
                    int gn = tn + wj * 64 + j * 16 + l16;
                    q16[(long)gm * Dc + gn] = f2b(acc[i][j][r] + bq[gn]);
                }
            }
        }
    } else if (sect == 1) {
        // KM / VM: TR store with per-(b,tok) mask, b = gm>>10
        int sec = tn >> 10, fn0 = tn & 1023;
        const float* bias = (sec == 1) ? bkm : bvm;
        bf16* C = (sec == 1) ? kT : vT;
        #pragma unroll
        for (int j = 0; j < 4; ++j) {
            #pragma unroll
            for (int r = 0; r < 4; ++r) {
                int feat = fn0 + wj * 64 + j * 16 + quad * 4 + r;
                float bf_ = bias[feat];
                #pragma unroll
                for (int i = 0; i < 4; ++i) {
                    int gm = tm + wi * 64 + i * 16 + l16;
                    int b = gm >> 10, tok = gm & 1023;
                    int mi = b * Nc + NTc + KRc + tok;
                    float v = acc[i][j][r] + bf_;
                    if (sec == 1) v += key_add[mi];
                    else          v *= val_mul[mi];
                    C[(long)b * SKT + (long)feat * NP + NTc + KRc + tok] = f2b(v);
                }
            }
        }
    } else if (sect == 0) {
        // retr-K: TR store + key_add
        const float* rmask = key_add + bb * Nc + NTc;
        bf16* C = kT + (long)bb * SKT + NTc;
        #pragma unroll
        for (int j = 0; j < 4; ++j) {
            #pragma unroll
            for (int r = 0; r < 4; ++r) {
                int feat = tn + wj * 64 + j * 16 + quad * 4 + r;
                float bf_ = bkr[feat];
                #pragma unroll
                for (int i = 0; i < 4; ++i) {
                    int tok = tm + wi * 64 + i * 16 + l16;
                    C[(long)feat * NP + tok] = f2b(acc[i][j][r] + bf_ + rmask[tok]);
                }
            }
        }
    } else if (sect == 3) {
        // value-retr: TR store * val_mul
        const float* rmask = val_mul + bb * Nc + NTc;
        bf16* C = vT + (long)bb * SKT + NTc;
        #pragma unroll
        for (int j = 0; j < 4; ++j) {
            #pragma unroll
            for (int r = 0; r < 4; ++r) {
                int feat = tn + wj * 64 + j * 16 + quad * 4 + r;
                float bf_ = bvr[feat];
                #pragma unroll
                for (int i = 0; i < 4; ++i) {
                    int tok = tm + wi * 64 + i * 16 + l16;
                    C[(long)feat * NP + tok] = f2b((acc[i][j][r] + bf_) * rmask[tok]);
                }
            }
        }
    } else {
        // text: sec 0 -> kT (+add), sec 1 -> vT (*mul); tok < 77
        int sec = tn >> 10, fn0 = tn & 1023;
        const float* bias = sec ? bvt : bkt;
        const float* rmask = (sec ? val_mul : key_add) + bb * Nc;
        bf16* C = (sec ? vT : kT) + (long)bb * SKT;
        #pragma unroll
        for (int j = 0; j < 4; ++j) {
            #pragma unroll
            for (int r = 0; r < 4; ++r) {
                int feat = fn0 + wj * 64 + j * 16 + quad * 4 + r;
                float bf_ = bias[feat];
                #pragma unroll
                for (int i = 0; i < 4; ++i) {
                    int tok = wi * 64 + i * 16 + l16;
                    if (tok >= NTc) continue;
                    float v = acc[i][j][r] + bf_;
                    if (sec) v *= rmask[tok];
                    else     v += rmask[tok];
                    C[(long)feat * NP + tok] = f2b(v);
                }
            }
        }
    }
}

// ===== value_retr GEMM (fallback path only: ren2 aliases q16 region) =====
__global__ __launch_bounds__(256) void gemm_vr(
    const short* __restrict__ ren2, const short* __restrict__ WtVR,
    const float* __restrict__ bvr, const float* __restrict__ val_mul,
    bf16* __restrict__ vT) {
    int s = (blockIdx.x & 7) * 64 + (blockIdx.x >> 3);
    int b = s >> 6; int r = s & 63;
    const int tm = (r >> 3) * 128;
    const int tn = (r & 7) * 128;
    const short* A = ren2 + (long)b * KRc * 1024;
    const float* rmask = val_mul + b * Nc + NTc;
    bf16* C = vT + (long)b * SKT + NTc;

    __shared__ __align__(16) short As[2][128 * LDK];
    __shared__ __align__(16) short Bs[2][128 * LDK];

    int tid = threadIdx.x;
    int lane = tid & 63, wid = tid >> 6;
    int wi = wid >> 1, wj = wid & 1;
    int l16 = lane & 15, quad = lane >> 4;

    f32x4 acc[4][4];
    #pragma unroll
    for (int i = 0; i < 4; ++i)
        #pragma unroll
        for (int j = 0; j < 4; ++j)
            acc[i][j] = (f32x4){0.f, 0.f, 0.f, 0.f};

    auto issue = [&](int k0, int buf) {
        #pragma unroll
        for (int p = 0; p < 4; ++p) {
            int e = p * 256 + tid;
            int row = e >> 3, c8 = e & 7;
            gl_lds16(A + (long)(tm + row) * 1024 + k0 + c8 * 8, &As[buf][row * LDK + c8 * 8]);
            gl_lds16(WtVR + (long)(tn + row) * 1024 + k0 + c8 * 8, &Bs[buf][row * LDK + c8 * 8]);
        }
    };
    auto compute = [&](int buf) {
        const short* as = As[buf];
        const short* bs = Bs[buf];
        #pragma unroll
        for (int kk = 0; kk < 2; ++kk) {
            s16x8 af[4], bfr[4];
            #pragma unroll
            for (int i = 0; i < 4; ++i)
                af[i] = *(const s16x8*)&as[(wi * 64 + i * 16 + l16) * LDK + kk * 32 + quad * 8];
            #pragma unroll
            for (int j = 0; j < 4; ++j)
                bfr[j] = *(const s16x8*)&bs[(wj * 64 + j * 16 + l16) * LDK + kk * 32 + quad * 8];
            #pragma unroll
            for (int i = 0; i < 4; ++i)
                #pragma unroll
                for (int j = 0; j < 4; ++j)
                    acc[i][j] = __builtin_amdgcn_mfma_f32_16x16x32_bf16(bfr[j], af[i], acc[i][j], 0, 0, 0);
        }
    };

    issue(0, 0);
    __syncthreads();
    int cur = 0, kt = 0;
    while (true) {
        int nxt = kt + 64;
        if (nxt < 1024) issue(nxt, cur ^ 1);
        compute(cur);
        if (nxt >= 1024) break;
        __syncthreads();
        cur ^= 1;
        kt = nxt;
    }

    #pragma unroll
    for (int j = 0; j < 4; ++j) {
        #pragma unroll
        for (int r2 = 0; r2 < 4; ++r2) {
            int feat = tn + wj * 64 + j * 16 + quad * 4 + r2;
            float bf_ = bvr[feat];
            #pragma unroll
            for (int i = 0; i < 4; ++i) {
                int tok = tm + wi * 64 + i * 16 + l16;
                C[(long)feat * NP + tok] = f2b((acc[i][j][r2] + bf_) * rmask[tok]);
            }
        }
    }
}

// ===== out GEMM: 128(M)x64(N) tile, grid 1024, XCD-swizzled, 2-phase dbuf =====
__global__ __launch_bounds__(256) void gemm_out(
    const short* __restrict__ A, const short* __restrict__ Bt,
    const float* __restrict__ bias, const float* __restrict__ addC,
    float* __restrict__ C) {
    int s = (blockIdx.x & 7) * 128 + (blockIdx.x >> 3);  // 1024 % 8 == 0
    const int tm = (s >> 4) * 128;
    const int tn = (s & 15) * 64;

    __shared__ __align__(16) short As[2][128 * LDK];
    __shared__ __align__(16) short Bs[2][64 * LDK];

    int tid = threadIdx.x;
    int lane = tid & 63, wid = tid >> 6;
    int wi = wid >> 1, wj = wid & 1;
    int l16 = lane & 15, quad = lane >> 4;

    f32x4 acc[4][2];
    #pragma unroll
    for (int i = 0; i < 4; ++i)
        #pragma unroll
        for (int j = 0; j < 2; ++j)
            acc[i][j] = (f32x4){0.f, 0.f, 0.f, 0.f};

    auto issue = [&](int k0, int buf) {
        #pragma unroll
        for (int p = 0; p < 4; ++p) {
            int e = p * 256 + tid;
            int row = e >> 3, c8 = e & 7;
            gl_lds16(A + (long)(tm + row) * 1024 + k0 + c8 * 8, &As[buf][row * LDK + c8 * 8]);
        }
        #pragma unroll
        for (int p = 0; p < 2; ++p) {
            int e = p * 256 + tid;
            int row = e >> 3, c8 = e & 7;
            gl_lds16(Bt + (long)(tn + row) * 1024 + k0 + c8 * 8, &Bs[buf][row * LDK + c8 * 8]);
        }
    };
    auto compute = [&](int buf) {
        const short* as = As[buf];
        const short* bs = Bs[buf];
        #pragma unroll
        for (int kk = 0; kk < 2; ++kk) {
            s16x8 af[4], bfr[2];
            #pragma unroll
            for (int i = 0; i < 4; ++i)
                af[i] = *(const s16x8*)&as[(wi * 64 + i * 16 + l16) * LDK + kk * 32 + quad * 8];
            #pragma unroll
            for (int j = 0; j < 2; ++j)
                bfr[j] = *(const s16x8*)&bs[(wj * 32 + j * 16 + l16) * LDK + kk * 32 + quad * 8];
            #pragma unroll
            for (int i = 0; i < 4; ++i)
                #pragma unroll
                for (int j = 0; j < 2; ++j)
                    acc[i][j] = __builtin_amdgcn_mfma_f32_16x16x32_bf16(af[i], bfr[j], acc[i][j], 0, 0, 0);
        }
    };

    issue(0, 0);
    __syncthreads();
    int cur = 0, kt = 0;
    while (true) {
        int nxt = kt + 64;
        if (nxt < 1024) issue(nxt, cur ^ 1);
        compute(cur);
        if (nxt >= 1024) break;
        __syncthreads();
        cur ^= 1;
        kt = nxt;
    }

    #pragma unroll
    for (int i = 0; i < 4; ++i) {
        #pragma unroll
        for (int r = 0; r < 4; ++r) {
            int gm = tm + wi * 64 + i * 16 + quad * 4 + r;
            #pragma unroll
            for (int j = 0; j < 2; ++j) {
                int gn = tn + wj * 32 + j * 16 + l16;
                C[(long)gm * 1024 + gn] = acc[i][j][r] + bias[gn] + addC[(long)gm * 1024 + gn];
            }
        }
    }
}

// ===== FUSED SM: q softmax [16384] + ksm_rows [2048] + eo_reduce [64] =====
__global__ __launch_bounds__(256) void fused_sm(
    bf16* __restrict__ q, const bf16* __restrict__ kT,
    float* __restrict__ cs_m, float* __restrict__ cs_inv,
    const float* __restrict__ part, const float* __restrict__ be,
    float* __restrict__ eo) {
    int bid = blockIdx.x;
    int lane = threadIdx.x & 63;
    if (bid < 16384) {
        long row = (long)bid * 4 + (threadIdx.x >> 6);
        bf16* p = q + row * 128 + lane * 2;
        float v0 = b2f(p[0]), v1 = b2f(p[1]);
        float mx = fmaxf(v0, v1);
        #pragma unroll
        for (int off = 32; off > 0; off >>= 1) mx = fmaxf(mx, __shfl_xor(mx, off, 64));
        float e0 = expf(v0 - mx), e1 = expf(v1 - mx);
        float s = e0 + e1;
        #pragma unroll
        for (int off = 32; off > 0; off >>= 1) s += __shfl_xor(s, off, 64);
        float inv = 1.f / s;
        p[0] = f2b(e0 * inv);
        p[1] = f2b(e1 * inv);
    } else if (bid < 18432) {
        int row = (bid - 16384) * 4 + (threadIdx.x >> 6);  // b*1024 + feature
        const s16x8* p8 = (const s16x8*)(kT + (long)row * NP);
        float m = -3.0e38f;
        for (int c = lane; c < NP / 8; c += 64) {
            s16x8 raw = p8[c];
            int n0 = c * 8;
            #pragma unroll
            for (int j = 0; j < 8; ++j)
                if (n0 + j < Nc) m = fmaxf(m, us2f((unsigned short)raw[j]));
        }
        #pragma unroll
        for (int off = 32; off > 0; off >>= 1) m = fmaxf(m, __shfl_xor(m, off, 64));
        float s = 0.f;
        for (int c = lane; c < NP / 8; c += 64) {
            s16x8 raw = p8[c];
            int n0 = c * 8;
            #pragma unroll
            for (int j = 0; j < 8; ++j)
                if (n0 + j < Nc) s += __expf(us2f((unsigned short)raw[j]) - m);
        }
        #pragma unroll
        for (int off = 32; off > 0; off >>= 1) s += __shfl_xor(s, off, 64);
        if (lane == 0) { cs_m[row] = m; cs_inv[row] = 1.f / s; }
    } else {
        int idx = (bid - 18432) * 256 + threadIdx.x;
        int n = idx & 2047, b = idx >> 11;
        float s = be[n];
        #pragma unroll 8
        for (int ks = 0; ks < 32; ++ks) s += part[((long)ks * 8 + b) * 2048 + n];
        eo[idx] = s;
    }
}

// att_part[split][bh][l][d] = sum_{n in split} exp(kT[bd][n]-m_d) * vT[bl][n]  (C^T store)
// ATT_SPLIT=8 -> 512 blocks (2/CU); att_part lives in d_out (32MB, ren1 dead).
constexpr int ATT_SPLIT = 8;
__global__ __launch_bounds__(256) void att_gemm(const bf16* __restrict__ kTb,
                                                const bf16* __restrict__ vTb,
                                                const float* __restrict__ cs_m,
                                                float* __restrict__ att_part) {
    int bh = blockIdx.x;
    int split = blockIdx.y;
    int b = bh >> 3, h = bh & 7;
    const short* A  = (const short*)kTb + ((long)b * 1024 + h * 128) * NP;
    const short* Bt = (const short*)vTb + ((long)b * 1024 + h * 128) * NP;
    float* ap = att_part + ((long)split * 64 + bh) * 16384;

    __shared__ __align__(16) short As[128 * LDK];
    __shared__ __align__(16) short Bs[128 * LDK];
    __shared__ float ms[128];

    int tid = threadIdx.x;
    if (tid < 128) ms[tid] = cs_m[(long)b * 1024 + h * 128 + tid];

    int lane = tid & 63, wid = tid >> 6;
    int wi = wid >> 1, wj = wid & 1;
    int l16 = lane & 15, quad = lane >> 4;

    f32x4 acc[4][4];
    #pragma unroll
    for (int i = 0; i < 4; ++i)
        #pragma unroll
        for (int j = 0; j < 4; ++j)
            acc[i][j] = (f32x4){0.f, 0.f, 0.f, 0.f};

    uint4 pa[4];
    auto computeA = [&](int k0) {
        #pragma unroll
        for (int p = 0; p < 4; ++p) {
            int e = p * 256 + tid;
            int row = e >> 3, c8 = e & 7;
            int n0 = k0 + c8 * 8;
            union { short s[8]; uint4 u; } pk;
            if (n0 >= Nc) {
                pk.u = (uint4){0u, 0u, 0u, 0u};
            } else {
                float m = ms[row];
                s16x8 raw = *(const s16x8*)(A + (long)row * NP + n0);
                #pragma unroll
                for (int j = 0; j < 8; ++j) {
                    float v = (n0 + j < Nc) ? __expf(us2f((unsigned short)raw[j]) - m) : 0.f;
                    pk.s[j] = f2s(v);
                }
            }
            pa[p] = pk.u;
        }
    };
    auto issueB = [&](int k0) {
        #pragma unroll
        for (int p = 0; p < 4; ++p) {
            int e = p * 256 + tid;
            int row = e >> 3, c8 = e & 7;
            int n0 = k0 + c8 * 8;
            if (n0 > NP - 8) n0 = NP - 8;  // clamp: A is zero there, values just must be finite
            gl_lds16(Bt + (long)row * NP + n0, &Bs[row * LDK + c8 * 8]);
        }
    };
    auto storeA = [&]() {
        #pragma unroll
        for (int p = 0; p < 4; ++p) {
            int e = p * 256 + tid;
            int row = e >> 3, c8 = e & 7;
            *(uint4*)&As[row * LDK + c8 * 8] = pa[p];
        }
    };

    // 34 K-steps total, splits {5,5,4,4,4,4,4,4}
    int st = (split < 2) ? split * 5 : 10 + (split - 2) * 4;
    int cnt = (split < 2) ? 5 : 4;
    int kt = st * 64;
    int kend = kt + cnt * 64;

    __syncthreads();  // ms ready
    issueB(kt);
    computeA(kt);
    storeA();
    while (true) {
        __syncthreads();
        #pragma unroll
        for (int kk = 0; kk < 2; ++kk) {
            s16x8 af[4], bfr[4];
            #pragma unroll
            for (int i = 0; i < 4; ++i)
                af[i] = *(const s16x8*)&As[(wi * 64 + i * 16 + l16) * LDK + kk * 32 + quad * 8];
            #pragma unroll
            for (int j = 0; j < 4; ++j)
                bfr[j] = *(const s16x8*)&Bs[(wj * 64 + j * 16 + l16) * LDK + kk * 32 + quad * 8];
            #pragma unroll
            for (int i = 0; i < 4; ++i)
                #pragma unroll
                for (int j = 0; j < 4; ++j)
                    acc[i][j] = __builtin_amdgcn_mfma_f32_16x16x32_bf16(bfr[j], af[i], acc[i][j], 0, 0, 0);
        }
        int nxt = kt + 64;
        if (nxt >= kend) break;
        computeA(nxt);
        __syncthreads();
        issueB(nxt);
        storeA();
        kt = nxt;
    }

    // C^T: acc rows = value-feature l (tile j), cols = key-feature d (tile i)
    #pragma unroll
    for (int j = 0; j < 4; ++j) {
        #pragma unroll
        for (int r = 0; r < 4; ++r) {
            int l = wj * 64 + j * 16 + quad * 4 + r;
            #pragma unroll
            for (int i = 0; i < 4; ++i) {
                int d = wi * 64 + i * 16 + l16;
                ap[l * 128 + d] = acc[i][j][r];
            }
        }
    }
}

// reduce splits + apply per-d 1/sum -> bf16 attT[bh][l][d] (ready B^T operand for y)
__global__ __launch_bounds__(256) void reduce_att_t(const float* __restrict__ att_part,
                                                    const float* __restrict__ cs_inv,
                                                    bf16* __restrict__ attT) {
    long idx = (long)blockIdx.x * 256 + threadIdx.x;
    if (idx >= (long)64 * 16384) return;
    float s = 0.f;
    #pragma unroll
    for (int sp = 0; sp < ATT_SPLIT; ++sp) s += att_part[(long)sp * 64 * 16384 + idx];
    int bh = (int)(idx >> 14);
    int d = (int)(idx & 127);
    int b = bh >> 3, h = bh & 7;
    attT[idx] = f2b(s * cs_inv[b * Dc + h * 128 + d]);
}

// y[b,t,h*128+l] = sum_d q[b,t,h*128+d] * att[bh][d][l] — MFMA, K=128 single stage.
__global__ __launch_bounds__(256) void y_gemm(const bf16* __restrict__ q,
                                              const bf16* __restrict__ attT,
                                              bf16* __restrict__ y) {
    int bh = blockIdx.y;
    int b = bh >> 3, h = bh & 7;
    const short* A  = (const short*)q + (long)b * Tc * Dc + h * 128;   // row stride Dc
    const short* Bt = (const short*)attT + (long)bh * 16384;           // [l][d] stride 128
    bf16* yb = y + (long)b * Tc * Dc + h * 128;
    int tm = blockIdx.x * 128;

    __shared__ __align__(16) short As[128 * 128];
    __shared__ __align__(16) short Bs[128 * 128];
    int tid = threadIdx.x;
    #pragma unroll
    for (int p = 0; p < 8; ++p) {
        int e = p * 256 + tid;
        int row = e >> 4, c8 = e & 15;
        gl_lds16(A + (long)(tm + row) * Dc + c8 * 8, &As[row * 128 + c8 * 8]);
        gl_lds16(Bt + row * 128 + c8 * 8, &Bs[row * 128 + c8 * 8]);
    }
    int lane = tid & 63, wid = tid >> 6;
    int wi = wid >> 1, wj = wid & 1;
    int l16 = lane & 15, quad = lane >> 4;
    f32x4 acc[4][4];
    #pragma unroll
    for (int i = 0; i < 4; ++i)
        #pragma unroll
        for (int j = 0; j < 4; ++j)
            acc[i][j] = (f32x4){0.f, 0.f, 0.f, 0.f};
    __syncthreads();
    #pragma unroll
    for (int kk = 0; kk < 4; ++kk) {
        s16x8 af[4], bfr[4];
        #pragma unroll
        for (int i = 0; i < 4; ++i)
            af[i] = *(const s16x8*)&As[(wi * 64 + i * 16 + l16) * 128 + kk * 32 + quad * 8];
        #pragma unroll
        for (int j = 0; j < 4; ++j)
            bfr[j] = *(const s16x8*)&Bs[(wj * 64 + j * 16 + l16) * 128 + kk * 32 + quad * 8];
        #pragma unroll
        for (int i = 0; i < 4; ++i)
            #pragma unroll
            for (int j = 0; j < 4; ++j)
                acc[i][j] = __builtin_amdgcn_mfma_f32_16x16x32_bf16(af[i], bfr[j], acc[i][j], 0, 0, 0);
    }
    #pragma unroll
    for (int i = 0; i < 4; ++i) {
        #pragma unroll
        for (int r = 0; r < 4; ++r) {
            int gm = tm + wi * 64 + i * 16 + quad * 4 + r;
            #pragma unroll
            for (int j = 0; j < 4; ++j) {
                int gn = wj * 64 + j * 16 + l16;
                yb[(long)gm * Dc + gn] = f2b(acc[i][j][r]);
            }
        }
    }
}

// s = silu( LN(y)*(1+scale) + shift ) — single pass, s16x4-vectorized (G13)
__global__ __launch_bounds__(256) void film_kernel(const bf16* __restrict__ y,
                                                   const float* __restrict__ eo,
                                                   const float* __restrict__ g,
                                                   const float* __restrict__ bta,
                                                   bf16* __restrict__ s) {
    long row = blockIdx.x;
    int b = (int)(row >> 10);
    int c = threadIdx.x * 4;
    s16x4 raw = *(const s16x4*)((const short*)(y + row * Dc) + c);
    float v0 = us2f((unsigned short)raw[0]);
    float v1 = us2f((unsigned short)raw[1]);
    float v2 = us2f((unsigned short)raw[2]);
    float v3 = us2f((unsigned short)raw[3]);
    float sum = v0 + v1 + v2 + v3;
    float sum2 = v0 * v0 + v1 * v1 + v2 * v2 + v3 * v3;
    float2 r = block_sum2(sum, sum2);
    float mean = r.x / Dc;
    float var = r.y / Dc - mean * mean;
    float inv = rsqrtf(var + 1e-5f);
    const float* sc = eo + (long)b * 2048;
    const float* sf = sc + 1024;
    float4 gv = *(const float4*)(g + c), bv = *(const float4*)(bta + c);
    float4 scv = *(const float4*)(sc + c), sfv = *(const float4*)(sf + c);
    auto fl = [&](float v, float gg, float bb, float ss, float ff) {
        float t = (v - mean) * inv * gg + bb;
        t = t * (1.f + ss) + ff;
        return t / (1.f + expf(-t));
    };
    s16x4 o;
    o[0] = f2s(fl(v0, gv.x, bv.x, scv.x, sfv.x));
    o[1] = f2s(fl(v1, gv.y, bv.y, scv.y, sfv.y));
    o[2] = f2s(fl(v2, gv.z, bv.z, scv.z, sfv.z));
    o[3] = f2s(fl(v3, gv.w, bv.w, scv.w, sfv.w));
    *(s16x4*)((short*)(s + row * Dc) + c) = o;
}

extern "C" void kernel_launch(void* const* d_in, const int* in_sizes, int n_in,
                              void* d_out, int out_size, void* d_ws, size_t ws_size,
                              hipStream_t stream) {
    if (ws_size < WS_NEED) return;
    const bool big = ws_size >= WS_BIG;

    const float* x         = (const float*)d_in[0];
    const float* xf        = (const float*)d_in[1];
    const float* emb       = (const float*)d_in[2];
    const float* src_mask  = (const float*)d_in[3];
    const int*   cond_type = (const int*)d_in[4];
    const float* re_motion = (const float*)d_in[5];
    const float* re_text   = (const float*)d_in[6];
    const float* re_mask   = (const float*)d_in[7];
    const float* ln_g  = (const float*)d_in[8];
    const float* ln_b  = (const float*)d_in[9];
    const float* tln_g = (const float*)d_in[10];
    const float* tln_b = (const float*)d_in[11];
    const float* rn1_g = (const float*)d_in[12];
    const float* rn1_b = (const float*)d_in[13];
    const float* rn2_g = (const float*)d_in[14];
    const float* rn2_b = (const float*)d_in[15];
    const float* Wq  = (const float*)d_in[16];
    const float* bq  = (const float*)d_in[17];
    const float* Wkt = (const float*)d_in[18];
    const float* bkt = (const float*)d_in[19];
    const float* Wvt = (const float*)d_in[20];
    const float* bvt = (const float*)d_in[21];
    const float* Wkm = (const float*)d_in[22];
    const float* bkm = (const float*)d_in[23];
    const float* Wvm = (const float*)d_in[24];
    const float* bvm = (const float*)d_in[25];
    const float* Wkr = (const float*)d_in[26];
    const float* bkr = (const float*)d_in[27];
    const float* Wvr = (const float*)d_in[28];
    const float* bvr = (const float*)d_in[29];
    const float* We  = (const float*)d_in[30];
    const float* be  = (const float*)d_in[31];
    const float* sln_g = (const float*)d_in[32];
    const float* sln_b = (const float*)d_in[33];
    const float* Wo  = (const float*)d_in[34];
    const float* bo  = (const float*)d_in[35];

    float* ws = (float*)d_ws;
    float* key_add  = ws + F_KEYADD;
    float* val_mul  = ws + F_VALMUL;
    float* cs_m     = ws + F_SILU;         // 8192
    float* cs_inv   = cs_m + Bc * Dc;      // 8192
    float* eo       = ws + F_EO;
    bf16*  attT     = (bf16*)(ws + F_ATT);       // first 2MB of slot
    float* eo_part  = ws + F_ATT + 524288;       // second 2MB of slot (disjoint)
    bf16* wb = (bf16*)(ws + F_END);
    bf16* norm_x16 = wb + B_NORMX;
    bf16* q16      = wb + B_Q;
    bf16* kT16     = wb + B_KT;
    bf16* vT16     = wb + B_VT;
    bf16* nxf16    = wb + B_NXF;
    short* WtQ  = (short*)(wb + B_WQ);     // WtQ/WtKM/WtVM contiguous = QKVM B-operand
    short* WtKM = (short*)(wb + B_WKM);
    short* WtVM = (short*)(wb + B_WVM);
    short* WtKT = (short*)(wb + B_WKT);    // WtKT/WtVT contiguous = text B-operand
    short* WtVT = (short*)(wb + B_WVT);
    short* WtKR = (short*)(wb + B_WKR);
    short* WtVR = (short*)(wb + B_WVR);
    short* WtO  = (short*)(wb + B_WO);
    bf16* y16 = wb + B_NORMX;                  // norm_x16 dead after mega
    bf16* s16 = q16;                           // q dead after y_gemm
    bf16* ren1 = (bf16*)d_out;                 // 32MB scratch, dead after mega
    float* att_part = (float*)d_out;           // 32MB, overlays ren1 (dead by att time)
    bf16* ren2 = big ? (wb + B_REN2) : q16;    // big: own region (VR folds into mega)

    float* out = (float*)d_out;

    // 1. FUSED PRE: ln(x) + ln(xf) + retrieval-LN materialize + masks/zero  [17099 blocks]
    fused_pre<<<dim3(17099), dim3(256), 0, stream>>>(
        x, ln_g, ln_b, norm_x16, xf, tln_g, tln_b, nxf16,
        re_motion, re_text, rn1_g, rn1_b, rn2_g, rn2_b, ren1, ren2,
        cond_type, src_mask, re_mask, key_add, val_mul, vT16);

    // 2. FUSED W: all weight transposes + eo split-K partial  [8960 blocks]
    fused_w<<<dim3(8960), dim3(256), 0, stream>>>(
        Wq, Wkt, Wvt, Wkm, Wvm, Wkr, Wvr, Wo,
        WtQ, WtKT, WtVT, WtKM, WtVM, WtKR, WtVR, WtO,
        emb, We, eo_part);

    // 3. value_retr separately only when ren2 aliases q16 (fallback ws)
    if (!big)
        gemm_vr<<<dim3(512), dim3(256), 0, stream>>>(
            (const short*)ren2, WtVR, bvr, val_mul, vT16);

    // 4. MEGA: retrK + qkvm + text (+ VR when big), 2-phase dbuf K-loop
    gemm_mega<<<dim3(big ? 2688 : 2176), dim3(256), 0, stream>>>(
        (const short*)norm_x16, (const short*)ren1, (const short*)ren2,
        (const short*)nxf16, WtQ, WtKR, WtVR, WtKT,
        bq, bkm, bvm, bkr, bvr, bkt, bvt,
        key_add, val_mul, q16, kT16, vT16);

    // 5. FUSED SM: q softmax + key column stats + eo reduce  [18496 blocks]
    fused_sm<<<dim3(18496), dim3(256), 0, stream>>>(
        q16, kT16, cs_m, cs_inv, eo_part, be, eo);

    // 6. att = p^T v (MFMA, C^T store, 8-way split in d_out), reduce -> bf16 attT
    att_gemm<<<dim3(Bc * Hc, ATT_SPLIT), dim3(256), 0, stream>>>(kT16, vT16, cs_m, att_part);
    reduce_att_t<<<dim3((64 * 16384 + 255) / 256), dim3(256), 0, stream>>>(att_part, cs_inv, attT);

    // 7. y = q @ att (MFMA)
    y_gemm<<<dim3(Tc / 128, Bc * Hc), dim3(256), 0, stream>>>(q16, attT, y16);

    // 8. FiLM + silu (single-pass vectorized)
    film_kernel<<<dim3(Bc * Tc), dim3(256), 0, stream>>>(y16, eo, sln_g, sln_b, s16);

    // 9. out = x + s @ Wo + bo  (128x64 tiles, 1024 blocks, XCD-swizzled, 2-phase)
    gemm_out<<<dim3(1024), dim3(256), 0, stream>>>(
        (const short*)s16, WtO, bo, x, out);
}